// Round 2
// baseline (1793.016 us; speedup 1.0000x reference)
//
#include <hip/hip_runtime.h>
#include <math.h>

constexpr int TT = 12;
constexpr int NN = 325;
constexpr int MM = 975;   // 3*NN
constexpr int DD = 64;
constexpr long ROWS_ALL = 96L * MM;      // 93,600
constexpr long SZ = ROWS_ALL * DD;       // 5,990,400 floats per big buffer
constexpr int SLD = 328;                 // S row stride: 325 cols + 2 diag + pad
constexpr long MASKF = 26624;            // floats reserved for normalized mask
constexpr float BN_EPS_ = 1e-5f;
constexpr float LN_EPS_ = 1e-5f;

// ------------- mask dtype sniff + normalize to uint8 0/1 ------------------
// bool may arrive as u8 (1B) or int32/float32 (4B). For 0/1 values stored in
// 4-byte elems, every byte at offset%4==1 is zero; for bernoulli u8 data the
// chance all 256 such bytes are zero is 2^-256.
__global__ __launch_bounds__(256) void k_maskprep(const unsigned char* __restrict__ raw,
                                                  unsigned char* __restrict__ outm) {
  bool is_u8 = false;
  for (int i = 0; i < 256; ++i) {
    if (raw[4 * i + 1]) { is_u8 = true; break; }
  }
  int idx = blockIdx.x * 256 + threadIdx.x;
  if (idx >= NN * NN) return;
  unsigned char v;
  if (is_u8) v = (raw[idx] != 0);
  else       v = (((const int*)raw)[idx] != 0);   // covers int32 and f32 0/1.0
  outm[idx] = v;
}

// ---------------- stX gather: [B,T,N,D] -> [BT, 3N, D] -------------------
__global__ __launch_bounds__(256) void k_stx(const float* __restrict__ x,
                                             float* __restrict__ stX) {
  int idx = blockIdx.x * 256 + threadIdx.x;     // exact: 23,400 blocks
  int d = idx & 63;
  int m = (idx >> 6) % MM;
  int bt = idx / (MM * DD);
  int b = bt / TT, t = bt - b * TT;
  int w = m / NN, n = m - w * NN;
  int st = t + w - 1;
  st = st < 0 ? 0 : (st > TT - 1 ? TT - 1 : st);
  stX[idx] = x[(((b * TT + st) * NN + n) << 6) + d];
}

// ---------------- QKV projections: out[r,o] = sum_d stX[r,d]*W[o,d] ------
__global__ __launch_bounds__(256) void k_qkv(const float* __restrict__ stX,
                                             const float* __restrict__ Wq,
                                             const float* __restrict__ Wk,
                                             const float* __restrict__ Wv,
                                             float* __restrict__ qo,
                                             float* __restrict__ ko,
                                             float* __restrict__ vo) {
  __shared__ float wl[64][65];                 // [d][o]
  const float* W = blockIdx.y == 0 ? Wq : (blockIdx.y == 1 ? Wk : Wv);
  float* out = blockIdx.y == 0 ? qo : (blockIdx.y == 1 ? ko : vo);
  int tid = threadIdx.x;
  for (int u = 0; u < 16; ++u) {
    int f = tid + 256 * u;                     // f = o*64+d
    wl[f & 63][f >> 6] = W[f];
  }
  __syncthreads();
  int lane = tid & 63;
  int wv = __builtin_amdgcn_readfirstlane(tid >> 6);
  long rowbase = (long)blockIdx.x * 208;       // 450*208 = 93,600 exact
  for (int g = 0; g < 13; ++g) {
    long r0 = rowbase + wv * 4 + 16 * g;
    const float* A0 = stX + (r0 + 0) * DD;
    const float* A1 = stX + (r0 + 1) * DD;
    const float* A2 = stX + (r0 + 2) * DD;
    const float* A3 = stX + (r0 + 3) * DD;
    float a0 = 0.f, a1 = 0.f, a2 = 0.f, a3 = 0.f;
#pragma unroll 8
    for (int d = 0; d < 64; ++d) {
      float wv_ = wl[d][lane];
      a0 += A0[d] * wv_; a1 += A1[d] * wv_; a2 += A2[d] * wv_; a3 += A3[d] * wv_;
    }
    out[(r0 + 0) * DD + lane] = a0;
    out[(r0 + 1) * DD + lane] = a1;
    out[(r0 + 2) * DD + lane] = a2;
    out[(r0 + 3) * DD + lane] = a3;
  }
}

// ---------------- block-diagonal scores: S[n,j] = q_row . k_col ----------
__global__ __launch_bounds__(256) void k_scores(const float* __restrict__ q,
                                                const float* __restrict__ km,
                                                float* __restrict__ S,
                                                int bt_base) {
  __shared__ float kl[64][65];                 // [j_local][d]
  int btw = blockIdx.x;
  int btl = btw / 3, w = btw - btl * 3;
  long bt = bt_base + btl;
  int ct = blockIdx.y;                         // col tile 0..5
  int tid = threadIdx.x;
  long kb = (bt * MM + (long)w * NN) * DD;
  for (int u = 0; u < 16; ++u) {
    int f = tid + 256 * u;
    int j = f >> 6, d = f & 63;
    int jg = ct * 64 + j;
    kl[j][d] = (jg < NN) ? km[kb + (long)jg * DD + d] : 0.f;
  }
  __syncthreads();
  int lane = tid & 63;
  int wv = __builtin_amdgcn_readfirstlane(tid >> 6);
  int jg = ct * 64 + lane;
  long qb = (bt * MM + (long)w * NN) * DD;
  long sb = (long)(btl * 3 + w) * NN * SLD;
  for (int g = 0; g < 21; ++g) {
    int r0 = wv * 4 + 16 * g;
    if (r0 >= NN) break;
    int rc1 = min(r0 + 1, NN - 1), rc2 = min(r0 + 2, NN - 1), rc3 = min(r0 + 3, NN - 1);
    const float* Q0 = q + qb + (long)r0 * DD;
    const float* Q1 = q + qb + (long)rc1 * DD;
    const float* Q2 = q + qb + (long)rc2 * DD;
    const float* Q3 = q + qb + (long)rc3 * DD;
    float a0 = 0.f, a1 = 0.f, a2 = 0.f, a3 = 0.f;
#pragma unroll 8
    for (int d = 0; d < 64; ++d) {
      float kv = kl[lane][d];
      a0 += Q0[d] * kv; a1 += Q1[d] * kv; a2 += Q2[d] * kv; a3 += Q3[d] * kv;
    }
    if (jg < NN) {
      if (r0 + 0 < NN) S[sb + (long)(r0 + 0) * SLD + jg] = a0;
      if (r0 + 1 < NN) S[sb + (long)(r0 + 1) * SLD + jg] = a1;
      if (r0 + 2 < NN) S[sb + (long)(r0 + 2) * SLD + jg] = a2;
      if (r0 + 3 < NN) S[sb + (long)(r0 + 3) * SLD + jg] = a3;
    }
  }
}

// ---------------- masked softmax (+ cross-window diagonal terms) ---------
__global__ __launch_bounds__(256) void k_softmax(const float* __restrict__ q,
                                                 const float* __restrict__ km,
                                                 const unsigned char* __restrict__ mask,
                                                 float* __restrict__ S,
                                                 int bt_base, int nrows) {
  int wv = __builtin_amdgcn_readfirstlane((int)(threadIdx.x >> 6));
  int lane = threadIdx.x & 63;
  int row = blockIdx.x * 4 + wv;
  if (row >= nrows) return;
  int btl = row / MM;
  int rem = row - btl * MM;
  int w = rem / NN;
  int n = rem - w * NN;
  long bt = bt_base + btl;
  long sb = ((long)(btl * 3 + w) * NN + n) * SLD;
  float s0 = -INFINITY, s1 = -INFINITY, s2 = -INFINITY,
        s3 = -INFINITY, s4 = -INFINITY, s5 = -INFINITY;
  const unsigned char* mrow = mask + (long)n * NN;
  {
    int j;
    j = lane;        if (!mrow[j]) s0 = S[sb + j];
    j = lane + 64;   if (!mrow[j]) s1 = S[sb + j];
    j = lane + 128;  if (!mrow[j]) s2 = S[sb + j];
    j = lane + 192;  if (!mrow[j]) s3 = S[sb + j];
    j = lane + 256;  if (!mrow[j]) s4 = S[sb + j];
    j = lane + 320;  if (j < NN && !mrow[j]) s5 = S[sb + j];
  }
  float mx = fmaxf(fmaxf(fmaxf(s0, s1), fmaxf(s2, s3)), fmaxf(s4, s5));
  for (int m = 1; m < 64; m <<= 1) mx = fmaxf(mx, __shfl_xor(mx, m));
  // diagonal partner scores
  long qb = (bt * MM + (long)w * NN + n) * DD;
  int pA = (w == 1) ? n : NN + n;              // global m-index of partner A
  float qd = q[qb + lane];
  float da = qd * km[(bt * MM + pA) * DD + lane];
  for (int m = 1; m < 64; m <<= 1) da += __shfl_xor(da, m);
  float db = 0.f;
  if (w == 1) {
    float t = qd * km[(bt * MM + 2 * NN + n) * DD + lane];
    for (int m = 1; m < 64; m <<= 1) t += __shfl_xor(t, m);
    db = t;
  }
  float gm = fmaxf(mx, da);
  if (w == 1) gm = fmaxf(gm, db);
  float p0 = s0 > -1e37f ? __expf(s0 - gm) : 0.f;
  float p1 = s1 > -1e37f ? __expf(s1 - gm) : 0.f;
  float p2 = s2 > -1e37f ? __expf(s2 - gm) : 0.f;
  float p3 = s3 > -1e37f ? __expf(s3 - gm) : 0.f;
  float p4 = s4 > -1e37f ? __expf(s4 - gm) : 0.f;
  float p5 = s5 > -1e37f ? __expf(s5 - gm) : 0.f;
  float sum = p0 + p1 + p2 + p3 + p4 + p5;
  for (int m = 1; m < 64; m <<= 1) sum += __shfl_xor(sum, m);
  float ea = __expf(da - gm);
  float eb = (w == 1) ? __expf(db - gm) : 0.f;
  sum += ea + eb;
  float inv = 1.f / sum;
  S[sb + lane]       = p0 * inv;
  S[sb + lane + 64]  = p1 * inv;
  S[sb + lane + 128] = p2 * inv;
  S[sb + lane + 192] = p3 * inv;
  S[sb + lane + 256] = p4 * inv;
  if (lane + 320 < NN) S[sb + lane + 320] = p5 * inv;
  if (lane == 0) { S[sb + NN] = ea * inv; S[sb + NN + 1] = eb * inv; }
}

// ---------------- PV: sem = P * V (+ diagonal partner contributions) -----
__global__ __launch_bounds__(256) void k_pv(const float* __restrict__ S,
                                            const float* __restrict__ vm,
                                            float* __restrict__ sem,
                                            int bt_base) {
  __shared__ float bl[128][64];
  int btw = blockIdx.x;
  int btl = btw / 3, w = btw - btl * 3;
  long bt = bt_base + btl;
  int rt = blockIdx.y;                         // row tile (112 rows)
  int tid = threadIdx.x, lane = tid & 63;
  int wv = __builtin_amdgcn_readfirstlane(tid >> 6);
  long vb = (bt * MM + (long)w * NN) * DD;
  long sb = (long)(btl * 3 + w) * NN * SLD;
  float acc[7][4];
#pragma unroll
  for (int g = 0; g < 7; ++g)
#pragma unroll
    for (int ri = 0; ri < 4; ++ri) acc[g][ri] = 0.f;
  for (int ch = 0; ch < 3; ++ch) {
    int jbase = ch * 128;
    int jlen = NN - jbase; if (jlen > 128) jlen = 128;
    __syncthreads();
    for (int u = 0; u < 32; ++u) {
      int f = tid + 256 * u;
      int j = f >> 6, d = f & 63;
      bl[j][d] = (j < jlen) ? vm[vb + (long)(jbase + j) * DD + d] : 0.f;
    }
    __syncthreads();
#pragma unroll 4
    for (int j = 0; j < jlen; ++j) {
      float bv = bl[j][lane];
      int jg = jbase + j;
#pragma unroll
      for (int g = 0; g < 7; ++g) {
        int r = rt * 112 + wv * 4 + 16 * g;
#pragma unroll
        for (int ri = 0; ri < 4; ++ri) {
          int rc = min(r + ri, NN - 1);
          acc[g][ri] += S[sb + (long)rc * SLD + jg] * bv;
        }
      }
    }
  }
#pragma unroll
  for (int g = 0; g < 7; ++g) {
#pragma unroll
    for (int ri = 0; ri < 4; ++ri) {
      int r = rt * 112 + wv * 4 + 16 * g + ri;
      int rc = min(r, NN - 1);
      float pA = S[sb + (long)rc * SLD + NN];
      int partA = (w == 1) ? rc : NN + rc;
      float val = acc[g][ri] + pA * vm[(bt * MM + partA) * DD + lane];
      if (w == 1) {
        float pB = S[sb + (long)rc * SLD + NN + 1];
        val += pB * vm[(bt * MM + 2 * NN + rc) * DD + lane];
      }
      if (r < NN) sem[(bt * MM + (long)w * NN + r) * DD + lane] = val;
    }
  }
}

// ---------------- xs1 = L * stX (block-sparse) ---------------------------
__global__ __launch_bounds__(256) void k_xs1(const float* __restrict__ gso,
                                             const float* __restrict__ stX,
                                             const float* __restrict__ pt12,
                                             const float* __restrict__ pt21,
                                             const float* __restrict__ pt23,
                                             const float* __restrict__ pt32,
                                             float* __restrict__ xs1) {
  __shared__ float bl[128][64];
  int btw = blockIdx.x;
  int bt = btw / 3, w = btw - bt * 3;
  int b = bt / TT;
  int rt = blockIdx.y;
  int tid = threadIdx.x, lane = tid & 63;
  int wv = __builtin_amdgcn_readfirstlane(tid >> 6);
  const float* A = gso + (long)b * NN * NN;
  long bb = ((long)bt * MM + (long)w * NN) * DD;
  float acc[7][4];
#pragma unroll
  for (int g = 0; g < 7; ++g)
#pragma unroll
    for (int ri = 0; ri < 4; ++ri) acc[g][ri] = 0.f;
  for (int ch = 0; ch < 3; ++ch) {
    int jbase = ch * 128;
    int jlen = NN - jbase; if (jlen > 128) jlen = 128;
    __syncthreads();
    for (int u = 0; u < 32; ++u) {
      int f = tid + 256 * u;
      int j = f >> 6, d = f & 63;
      bl[j][d] = (j < jlen) ? stX[bb + (long)(jbase + j) * DD + d] : 0.f;
    }
    __syncthreads();
#pragma unroll 4
    for (int j = 0; j < jlen; ++j) {
      float bv = bl[j][lane];
      int jg = jbase + j;
#pragma unroll
      for (int g = 0; g < 7; ++g) {
        int r = rt * 112 + wv * 4 + 16 * g;
#pragma unroll
        for (int ri = 0; ri < 4; ++ri) {
          int rc = min(r + ri, NN - 1);
          acc[g][ri] += A[rc * NN + jg] * bv;
        }
      }
    }
  }
  long btM = (long)bt * MM;
#pragma unroll
  for (int g = 0; g < 7; ++g) {
#pragma unroll
    for (int ri = 0; ri < 4; ++ri) {
      int r = rt * 112 + wv * 4 + 16 * g + ri;
      int rc = min(r, NN - 1);
      float val = acc[g][ri];
      if (w == 0) {
        val += pt21[rc] * stX[(btM + NN + rc) * DD + lane];
      } else if (w == 1) {
        val += pt12[rc] * stX[(btM + rc) * DD + lane]
             + pt32[rc] * stX[(btM + 2 * NN + rc) * DD + lane];
      } else {
        val += pt23[rc] * stX[(btM + NN + rc) * DD + lane];
      }
      if (r < NN) xs1[(btM + (long)w * NN + r) * DD + lane] = val;
    }
  }
}

// -------- t2 = 2*(L*xs1)[middle] - stX[middle] ---------------------------
__global__ __launch_bounds__(256) void k_t2(const float* __restrict__ gso,
                                            const float* __restrict__ xs1,
                                            const float* __restrict__ stX,
                                            const float* __restrict__ pt12,
                                            const float* __restrict__ pt32,
                                            float* __restrict__ t2o) {
  __shared__ float bl[128][64];
  int bt = blockIdx.x;
  int b = bt / TT;
  int rt = blockIdx.y;
  int tid = threadIdx.x, lane = tid & 63;
  int wv = __builtin_amdgcn_readfirstlane(tid >> 6);
  const float* A = gso + (long)b * NN * NN;
  long btM = (long)bt * MM;
  long mb = (btM + NN) * DD;                   // xs1 middle block base
  float acc[7][4];
#pragma unroll
  for (int g = 0; g < 7; ++g)
#pragma unroll
    for (int ri = 0; ri < 4; ++ri) acc[g][ri] = 0.f;
  for (int ch = 0; ch < 3; ++ch) {
    int jbase = ch * 128;
    int jlen = NN - jbase; if (jlen > 128) jlen = 128;
    __syncthreads();
    for (int u = 0; u < 32; ++u) {
      int f = tid + 256 * u;
      int j = f >> 6, d = f & 63;
      bl[j][d] = (j < jlen) ? xs1[mb + (long)(jbase + j) * DD + d] : 0.f;
    }
    __syncthreads();
#pragma unroll 4
    for (int j = 0; j < jlen; ++j) {
      float bv = bl[j][lane];
      int jg = jbase + j;
#pragma unroll
      for (int g = 0; g < 7; ++g) {
        int r = rt * 112 + wv * 4 + 16 * g;
#pragma unroll
        for (int ri = 0; ri < 4; ++ri) {
          int rc = min(r + ri, NN - 1);
          acc[g][ri] += A[rc * NN + jg] * bv;
        }
      }
    }
  }
#pragma unroll
  for (int g = 0; g < 7; ++g) {
#pragma unroll
    for (int ri = 0; ri < 4; ++ri) {
      int r = rt * 112 + wv * 4 + 16 * g + ri;
      int rc = min(r, NN - 1);
      float val = 2.f * (pt12[rc] * xs1[(btM + rc) * DD + lane]
                         + acc[g][ri]
                         + pt32[rc] * xs1[(btM + 2 * NN + rc) * DD + lane])
                  - stX[(btM + NN + rc) * DD + lane];
      if (r < NN) t2o[((long)bt * NN + r) * DD + lane] = val;
    }
  }
}

// -------- cheb combine (middle rows) + LayerNorm -------------------------
__global__ __launch_bounds__(256) void k_cheb(const float* __restrict__ stX,
                                              const float* __restrict__ xs1,
                                              const float* __restrict__ t2o,
                                              const float* __restrict__ cw,
                                              const float* __restrict__ lng,
                                              const float* __restrict__ lnb,
                                              float* __restrict__ gcn) {
  __shared__ float cl[3 * 64 * 64];
  int tid = threadIdx.x;
  for (int u = 0; u < 48; ++u) cl[tid + 256 * u] = cw[tid + 256 * u];
  __syncthreads();
  int lane = tid & 63;
  int wv = __builtin_amdgcn_readfirstlane(tid >> 6);
  float g_ = lng[lane], b_ = lnb[lane];
  for (int pp = 0; pp < 8; ++pp) {
    int row0 = blockIdx.x * 64 + wv * 16 + pp * 2;
    if (row0 >= 96 * NN) break;
    int row1 = min(row0 + 1, 96 * NN - 1);
    int bt0 = row0 / NN, n0 = row0 - bt0 * NN;
    int bt1 = row1 / NN, n1 = row1 - bt1 * NN;
    const float* a00 = stX + ((long)bt0 * MM + NN + n0) * DD;
    const float* a01 = xs1 + ((long)bt0 * MM + NN + n0) * DD;
    const float* a02 = t2o + (long)row0 * DD;
    const float* a10 = stX + ((long)bt1 * MM + NN + n1) * DD;
    const float* a11 = xs1 + ((long)bt1 * MM + NN + n1) * DD;
    const float* a12 = t2o + (long)row1 * DD;
    float h0 = 0.f, h1 = 0.f;
#pragma unroll
    for (int kk = 0; kk < 3; ++kk) {
      const float* A0 = kk == 0 ? a00 : (kk == 1 ? a01 : a02);
      const float* A1 = kk == 0 ? a10 : (kk == 1 ? a11 : a12);
#pragma unroll 8
      for (int i = 0; i < 64; ++i) {
        float c = cl[(kk * 64 + i) * 64 + lane];
        h0 += A0[i] * c;
        h1 += A1[i] * c;
      }
    }
    // LayerNorm over the 64 lanes
    float s0 = h0, s1 = h1;
    for (int m = 1; m < 64; m <<= 1) { s0 += __shfl_xor(s0, m); s1 += __shfl_xor(s1, m); }
    float mu0 = s0 * (1.f / 64.f), mu1 = s1 * (1.f / 64.f);
    float d0 = h0 - mu0, d1 = h1 - mu1;
    float q0 = d0 * d0, q1 = d1 * d1;
    for (int m = 1; m < 64; m <<= 1) { q0 += __shfl_xor(q0, m); q1 += __shfl_xor(q1, m); }
    float var0 = q0 * (1.f / 64.f), var1 = q1 * (1.f / 64.f);
    gcn[(long)row0 * DD + lane] = d0 * rsqrtf(var0 + LN_EPS_) * g_ + b_;
    if (row0 + 1 < 96 * NN)
      gcn[(long)(row0 + 1) * DD + lane] = d1 * rsqrtf(var1 + LN_EPS_) * g_ + b_;
  }
}

// -------- attn layout-scramble gather ------------------------------------
__global__ __launch_bounds__(256) void k_gather(const float* __restrict__ sem,
                                                float* __restrict__ attn) {
  int idx = blockIdx.x * 256 + threadIdx.x;    // exact 7800 blocks
  int d = idx & 63;
  int n = (idx >> 6) % NN;
  int bt = idx / (NN * DD);
  int f = (NN + n) * DD + d;
  int mm = f % MM, ii = f / MM;
  attn[idx] = sem[((long)bt * MM + mm) * DD + ii];
}

// -------- mean over (t,n) per (b,d) --------------------------------------
__global__ __launch_bounds__(256) void k_mean(const float* __restrict__ attn,
                                              const float* __restrict__ gcn,
                                              float* __restrict__ mbd) {
  __shared__ float red[4][64];
  int bt = blockIdx.x;
  int b = bt / TT;
  int d = threadIdx.x & 63, g = threadIdx.x >> 6;
  float s = 0.f;
  for (int n = g; n < NN; n += 4) {
    long o = ((long)bt * NN + n) * DD + d;
    s += attn[o] + gcn[o];
  }
  red[g][d] = s;
  __syncthreads();
  if (threadIdx.x < 64) {
    float v = red[0][d] + red[1][d] + red[2][d] + red[3][d];
    atomicAdd(&mbd[b * 64 + d], v);
  }
}

// -------- global AFF branch ----------------------------------------------
__global__ __launch_bounds__(64) void k_glob(const float* __restrict__ mbd,
                                             const float* __restrict__ w1,
                                             const float* __restrict__ b1,
                                             const float* __restrict__ g1,
                                             const float* __restrict__ be1,
                                             const float* __restrict__ w2,
                                             const float* __restrict__ b2,
                                             const float* __restrict__ g2,
                                             const float* __restrict__ be2,
                                             float* __restrict__ xg) {
  __shared__ float ml[64];
  __shared__ float zg[16];
  int b = blockIdx.x, d = threadIdx.x;
  ml[d] = mbd[b * 64 + d] * (1.f / 3900.f);
  __syncthreads();
  float rb = rsqrtf(1.f + BN_EPS_);
  if (d < 16) {
    float a = b1[d];
    for (int i = 0; i < 64; ++i) a += w1[d * 64 + i] * ml[i];
    a = a * (g1[d] * rb) + be1[d];
    zg[d] = a > 0.f ? a : 0.f;
  }
  __syncthreads();
  float a = b2[d];
  for (int i = 0; i < 16; ++i) a += w2[d * 16 + i] * zg[i];
  xg[b * 64 + d] = a * (g2[d] * rb) + be2[d];
}

// -------- final: local AFF branch + sigmoid fuse -------------------------
__global__ __launch_bounds__(256) void k_final(const float* __restrict__ attn,
                                               const float* __restrict__ gcn,
                                               const float* __restrict__ xg,
                                               const float* __restrict__ w1,
                                               const float* __restrict__ b1,
                                               const float* __restrict__ g1,
                                               const float* __restrict__ be1,
                                               const float* __restrict__ w2,
                                               const float* __restrict__ b2,
                                               const float* __restrict__ g2,
                                               const float* __restrict__ be2,
                                               float* __restrict__ out) {
  __shared__ float w1l[16][65];
  __shared__ float w2l[64][17];
  __shared__ float xal[4][64];
  __shared__ float zll[4][16];
  int tid = threadIdx.x;
  for (int u = 0; u < 4; ++u) {
    int f = tid + 256 * u;
    w1l[f >> 6][f & 63] = w1[f];               // [o][c]
    w2l[f >> 4][f & 15] = w2[f];               // [d][i]
  }
  int lane = tid & 63, wv = tid >> 6;
  long row = (long)blockIdx.x * 4 + wv;        // exact: 7800*4 = 31,200
  int bt = (int)(row / NN);
  int b = bt / TT;
  long o = row * DD + lane;
  float a = attn[o], r = gcn[o];
  float xa = a + r;
  xal[wv][lane] = xa;
  __syncthreads();
  float rb = rsqrtf(1.f + BN_EPS_);
  if (lane < 16) {
    float acc = b1[lane];
#pragma unroll 8
    for (int i = 0; i < 64; ++i) acc += w1l[lane][i] * xal[wv][i];
    acc = acc * (g1[lane] * rb) + be1[lane];
    zll[wv][lane] = acc > 0.f ? acc : 0.f;
  }
  __syncthreads();
  float acc = b2[lane];
#pragma unroll
  for (int i = 0; i < 16; ++i) acc += w2l[lane][i] * zll[wv][i];
  float xl = acc * (g2[lane] * rb) + be2[lane];
  float wei = 1.f / (1.f + __expf(-(xl + xg[b * 64 + lane])));
  out[o] = 2.f * a * wei + 2.f * r * (1.f - wei);
}

extern "C" void kernel_launch(void* const* d_in, const int* in_sizes, int n_in,
                              void* d_out, int out_size, void* d_ws, size_t ws_size,
                              hipStream_t stream) {
  const float* x    = (const float*)d_in[0];
  const float* gso  = (const float*)d_in[1];
  const unsigned char* mask_raw = (const unsigned char*)d_in[2];
  const float* Wq   = (const float*)d_in[3];
  const float* Wk   = (const float*)d_in[4];
  const float* Wv   = (const float*)d_in[5];
  const float* chw  = (const float*)d_in[6];
  const float* pt12 = (const float*)d_in[7];
  const float* pt21 = (const float*)d_in[8];
  const float* pt23 = (const float*)d_in[9];
  const float* pt32 = (const float*)d_in[10];
  const float* lng  = (const float*)d_in[11];
  const float* lnb  = (const float*)d_in[12];
  const float* l_w1 = (const float*)d_in[13];
  const float* l_b1 = (const float*)d_in[14];
  const float* l_g1 = (const float*)d_in[15];
  const float* l_be1= (const float*)d_in[16];
  const float* l_w2 = (const float*)d_in[17];
  const float* l_b2 = (const float*)d_in[18];
  const float* l_g2 = (const float*)d_in[19];
  const float* l_be2= (const float*)d_in[20];
  const float* g_w1 = (const float*)d_in[21];
  const float* g_b1 = (const float*)d_in[22];
  const float* g_g1 = (const float*)d_in[23];
  const float* g_be1= (const float*)d_in[24];
  const float* g_w2 = (const float*)d_in[25];
  const float* g_b2 = (const float*)d_in[26];
  const float* g_g2 = (const float*)d_in[27];
  const float* g_be2= (const float*)d_in[28];

  unsigned char* nmask = (unsigned char*)d_ws;   // normalized mask, 105,625 B
  float* base = (float*)d_ws + MASKF;
  float* stX = base;
  float* q   = base + SZ;
  float* k   = base + 2 * SZ;
  float* v   = base + 3 * SZ;
  float* sem = base + 4 * SZ;
  float* S   = base + 5 * SZ;
  // aliases (lifetimes disjoint)
  float* xs1 = q;                              // after attention chunks done
  float* t2o = v;
  float* gcn = k;
  float* attn = k + 96L * NN * DD;
  float* mbd = k + 2 * 96L * NN * DD;
  float* xg  = mbd + 512;

  // pick attention chunk size (in bt) from available workspace
  long avail_f = (long)(ws_size / sizeof(float)) - MASKF - 5 * SZ;
  const int cands[9] = {24, 16, 12, 8, 6, 4, 3, 2, 1};
  int cbt = 1;
  for (int i = 0; i < 9; ++i) {
    long need = (long)cands[i] * 3 * NN * SLD;
    if (need <= avail_f) { cbt = cands[i]; break; }
  }

  k_maskprep<<<(NN * NN + 255) / 256, 256, 0, stream>>>(mask_raw, nmask);
  k_stx<<<23400, 256, 0, stream>>>(x, stX);
  {
    dim3 g(450, 3);
    k_qkv<<<g, 256, 0, stream>>>(stX, Wq, Wk, Wv, q, k, v);
  }
  for (int bb = 0; bb < 96; bb += cbt) {
    dim3 gs(cbt * 3, 6);
    k_scores<<<gs, 256, 0, stream>>>(q, k, S, bb);
    int nrows = cbt * MM;
    k_softmax<<<(nrows + 3) / 4, 256, 0, stream>>>(q, k, nmask, S, bb, nrows);
    dim3 gp(cbt * 3, 3);
    k_pv<<<gp, 256, 0, stream>>>(S, v, sem, bb);
  }
  {
    dim3 g(288, 3);
    k_xs1<<<g, 256, 0, stream>>>(gso, stX, pt12, pt21, pt23, pt32, xs1);
  }
  {
    dim3 g(96, 3);
    k_t2<<<g, 256, 0, stream>>>(gso, xs1, stX, pt12, pt32, t2o);
  }
  k_cheb<<<488, 256, 0, stream>>>(stX, xs1, t2o, chw, lng, lnb, gcn);
  k_gather<<<7800, 256, 0, stream>>>(sem, attn);
  hipMemsetAsync(mbd, 0, 512 * sizeof(float), stream);
  k_mean<<<96, 256, 0, stream>>>(attn, gcn, mbd);
  k_glob<<<8, 64, 0, stream>>>(mbd, g_w1, g_b1, g_g1, g_be1, g_w2, g_b2, g_g2, g_be2, xg);
  k_final<<<7800, 256, 0, stream>>>(attn, gcn, xg,
                                    l_w1, l_b1, l_g1, l_be1,
                                    l_w2, l_b2, l_g2, l_be2,
                                    (float*)d_out);
}

// Round 5
// 543.783 us; speedup vs baseline: 3.2973x; 3.2973x over previous
//
#include <hip/hip_runtime.h>
#include <math.h>

constexpr int TT = 12;
constexpr int NN = 325;
constexpr int MM = 975;   // 3*NN
constexpr int DD = 64;
constexpr long SZ = 96L * MM * DD;       // 5,990,400 floats per big buffer
constexpr int SLD = 328;                 // S row stride (f32)
constexpr int PSTR = 352;                // P row stride (fp16 shorts), zero-padded
constexpr int GSTR = 352;                // gso row stride (fp16 shorts), zero-padded
constexpr float BN_EPS_ = 1e-5f;
constexpr float LN_EPS_ = 1e-5f;

// ---- workspace float offsets (running map; all sizes in floats) ----------
constexpr long WS_NMASK = 0;                         // 105,625 B -> 26,624 f
constexpr long WS_GSOB  = WS_NMASK + 26624;          // 915,200 shorts = 457,600 f
constexpr long WS_STX   = WS_GSOB + 457600;          // SZ f
constexpr long WS_STXB  = WS_STX + SZ;               // SZ shorts = SZ/2 f
constexpr long WS_QB    = WS_STXB + SZ / 2;          // SZ shorts
constexpr long WS_KB    = WS_QB + SZ / 2;            // SZ shorts
constexpr long WS_VB    = WS_KB + SZ / 2;            // SZ shorts
constexpr long WS_SEM   = WS_VB + SZ / 2;            // SZ f
constexpr long WS_G     = WS_SEM + SZ;               // chunk region / mbd / xg
constexpr long PERBT = 319800 + 171600 + 1950;       // 493,350 f per bt of chunk

typedef _Float16 half8 __attribute__((ext_vector_type(8)));
typedef __attribute__((ext_vector_type(4))) float f32x4;

static __device__ inline unsigned short f2h(float f) {
  _Float16 h = (_Float16)f;                 // v_cvt_f16_f32, RTN
  return __builtin_bit_cast(unsigned short, h);
}
static __device__ inline float h2f(unsigned short s) {
  return (float)__builtin_bit_cast(_Float16, s);
}

// ------------- mask dtype sniff + normalize to uint8 0/1 ------------------
__global__ __launch_bounds__(256) void k_maskprep(const unsigned char* __restrict__ raw,
                                                  unsigned char* __restrict__ outm) {
  bool is_u8 = false;
  for (int i = 0; i < 256; ++i) {
    if (raw[4 * i + 1]) { is_u8 = true; break; }
  }
  int idx = blockIdx.x * 256 + threadIdx.x;
  if (idx >= NN * NN) return;
  unsigned char v;
  if (is_u8) v = (raw[idx] != 0);
  else       v = (((const int*)raw)[idx] != 0);
  outm[idx] = v;
}

// ------------- gso -> fp16, padded rows [8][325][GSTR] --------------------
__global__ __launch_bounds__(256) void k_gsoprep(const float* __restrict__ gso,
                                                 unsigned short* __restrict__ gsoB) {
  int idx = blockIdx.x * 256 + threadIdx.x;   // 3575 blocks exact (915,200)
  int b = idx / (NN * GSTR);
  int rem = idx - b * (NN * GSTR);
  int r = rem / GSTR, j = rem - r * GSTR;
  gsoB[idx] = (j < NN) ? f2h(gso[(long)b * NN * NN + r * NN + j]) : (unsigned short)0;
}

// ---------------- stX gather: [B,T,N,D] -> [BT, 3N, D] (f32 + fp16) ------
__global__ __launch_bounds__(256) void k_stx(const float* __restrict__ x,
                                             float* __restrict__ stX,
                                             unsigned short* __restrict__ stXb) {
  int idx = blockIdx.x * 256 + threadIdx.x;     // exact: 23,400 blocks
  int d = idx & 63;
  int m = (idx >> 6) % MM;
  int bt = idx / (MM * DD);
  int b = bt / TT, t = bt - b * TT;
  int w = m / NN, n = m - w * NN;
  int st = t + w - 1;
  st = st < 0 ? 0 : (st > TT - 1 ? TT - 1 : st);
  float val = x[(((b * TT + st) * NN + n) << 6) + d];
  stX[idx] = val;
  stXb[idx] = f2h(val);
}

// ---------------- QKV via MFMA: [93600x64] x [64x64] -> fp16 -------------
__global__ __launch_bounds__(256) void k_qkv_mfma(const unsigned short* __restrict__ stXb,
                                                  const float* __restrict__ Wq,
                                                  const float* __restrict__ Wk,
                                                  const float* __restrict__ Wv,
                                                  unsigned short* __restrict__ qb,
                                                  unsigned short* __restrict__ kb,
                                                  unsigned short* __restrict__ vb) {
  __shared__ alignas(16) unsigned short sX[128 * 72];
  __shared__ alignas(16) unsigned short sW[64 * 72];
  const float* W = blockIdx.y == 0 ? Wq : (blockIdx.y == 1 ? Wk : Wv);
  unsigned short* outb = blockIdx.y == 0 ? qb : (blockIdx.y == 1 ? kb : vb);
  int tid = threadIdx.x;
  long r0 = (long)blockIdx.x * 128;
  for (int u = 0; u < 4; ++u) {
    int idx = tid + 256 * u;
    int row = idx >> 3, c8 = idx & 7;
    long rg = r0 + row; if (rg > 93599) rg = 93599;
    *(uint4*)&sX[row * 72 + c8 * 8] = *(const uint4*)&stXb[rg * 64 + c8 * 8];
  }
  for (int u = 0; u < 16; ++u) {
    int f = tid + 256 * u;
    int o = f >> 6, d = f & 63;
    sW[o * 72 + d] = f2h(W[f]);
  }
  __syncthreads();
  int lane = tid & 63;
  int wv = __builtin_amdgcn_readfirstlane(tid >> 6);
  int lr = lane & 15, lg = lane >> 4;
  f32x4 zero4 = {0.f, 0.f, 0.f, 0.f};
  f32x4 acc[2][4];
#pragma unroll
  for (int rt = 0; rt < 2; ++rt)
#pragma unroll
    for (int c = 0; c < 4; ++c) acc[rt][c] = zero4;
#pragma unroll
  for (int kk = 0; kk < 2; ++kk) {
    half8 a0 = *(const half8*)&sX[(32 * wv + lr) * 72 + kk * 32 + lg * 8];
    half8 a1 = *(const half8*)&sX[(32 * wv + 16 + lr) * 72 + kk * 32 + lg * 8];
#pragma unroll
    for (int c = 0; c < 4; ++c) {
      half8 b = *(const half8*)&sW[(16 * c + lr) * 72 + kk * 32 + lg * 8];
      acc[0][c] = __builtin_amdgcn_mfma_f32_16x16x32_f16(a0, b, acc[0][c], 0, 0, 0);
      acc[1][c] = __builtin_amdgcn_mfma_f32_16x16x32_f16(a1, b, acc[1][c], 0, 0, 0);
    }
  }
  __syncthreads();
#pragma unroll
  for (int rt = 0; rt < 2; ++rt)
#pragma unroll
    for (int c = 0; c < 4; ++c)
#pragma unroll
      for (int e = 0; e < 4; ++e) {
        int row = 32 * wv + 16 * rt + lg * 4 + e;
        int col = 16 * c + lr;
        sX[row * 64 + col] = f2h(acc[rt][c][e]);
      }
  __syncthreads();
  for (int u = 0; u < 4; ++u) {
    int idx = tid + 256 * u;
    int row = idx >> 3, c8 = idx & 7;
    long rg = r0 + row;
    if (rg < 93600)
      *(uint4*)&outb[rg * 64 + c8 * 8] = *(const uint4*)&sX[row * 64 + c8 * 8];
  }
}

// ---------------- scores via MFMA: per (bt,w) [325x64]x[64x325] ----------
__global__ __launch_bounds__(256) void k_scores_mfma(const unsigned short* __restrict__ qb,
                                                     const unsigned short* __restrict__ kb,
                                                     float* __restrict__ S,
                                                     int bt_base) {
  __shared__ alignas(16) unsigned short qT[128 * 72];
  __shared__ alignas(16) unsigned short kT[128 * 72];
  int btw = blockIdx.x;
  int btl = btw / 3, w = btw - btl * 3;
  long bt = bt_base + btl;
  int rt_blk = blockIdx.y, ct_blk = blockIdx.z;
  long qbase = bt * MM + (long)w * NN;
  int tid = threadIdx.x;
  for (int u = 0; u < 4; ++u) {
    int idx = tid + 256 * u;
    int row = idx >> 3, c8 = idx & 7;
    int rq = rt_blk * 128 + row; if (rq > NN - 1) rq = NN - 1;
    *(uint4*)&qT[row * 72 + c8 * 8] = *(const uint4*)&qb[(qbase + rq) * 64 + c8 * 8];
    int rk = ct_blk * 128 + row; if (rk > NN - 1) rk = NN - 1;
    *(uint4*)&kT[row * 72 + c8 * 8] = *(const uint4*)&kb[(qbase + rk) * 64 + c8 * 8];
  }
  __syncthreads();
  int lane = tid & 63;
  int wv = __builtin_amdgcn_readfirstlane(tid >> 6);
  int lr = lane & 15, lg = lane >> 4;
  f32x4 zero4 = {0.f, 0.f, 0.f, 0.f};
  f32x4 acc[2][8];
#pragma unroll
  for (int rt = 0; rt < 2; ++rt)
#pragma unroll
    for (int ct = 0; ct < 8; ++ct) acc[rt][ct] = zero4;
#pragma unroll
  for (int kk = 0; kk < 2; ++kk) {
    half8 a0 = *(const half8*)&qT[(32 * wv + lr) * 72 + kk * 32 + lg * 8];
    half8 a1 = *(const half8*)&qT[(32 * wv + 16 + lr) * 72 + kk * 32 + lg * 8];
#pragma unroll
    for (int ct = 0; ct < 8; ++ct) {
      half8 b = *(const half8*)&kT[(16 * ct + lr) * 72 + kk * 32 + lg * 8];
      acc[0][ct] = __builtin_amdgcn_mfma_f32_16x16x32_f16(a0, b, acc[0][ct], 0, 0, 0);
      acc[1][ct] = __builtin_amdgcn_mfma_f32_16x16x32_f16(a1, b, acc[1][ct], 0, 0, 0);
    }
  }
  long sb = (long)(btl * 3 + w) * NN * SLD;
#pragma unroll
  for (int rt = 0; rt < 2; ++rt)
#pragma unroll
    for (int ct = 0; ct < 8; ++ct)
#pragma unroll
      for (int e = 0; e < 4; ++e) {
        int row = rt_blk * 128 + 32 * wv + 16 * rt + lg * 4 + e;
        int col = ct_blk * 128 + 16 * ct + lr;
        if (row < NN && col < NN) S[sb + (long)row * SLD + col] = acc[rt][ct][e];
      }
}

// ---------------- masked softmax -> P fp16 (+ diag probs) ----------------
__global__ __launch_bounds__(256) void k_softmax(const unsigned short* __restrict__ qb,
                                                 const unsigned short* __restrict__ kb,
                                                 const unsigned char* __restrict__ mask,
                                                 const float* __restrict__ S,
                                                 unsigned short* __restrict__ Pb,
                                                 float* __restrict__ pda,
                                                 float* __restrict__ pdb,
                                                 int bt_base, int nrows) {
  int wv = __builtin_amdgcn_readfirstlane((int)(threadIdx.x >> 6));
  int lane = threadIdx.x & 63;
  int row = blockIdx.x * 4 + wv;
  if (row >= nrows) return;
  int btl = row / MM;
  int rem = row - btl * MM;
  int w = rem / NN;
  int n = rem - w * NN;
  long bt = bt_base + btl;
  long sb = (long)row * SLD;   // S chunk row index == row
  float s0 = -INFINITY, s1 = -INFINITY, s2 = -INFINITY,
        s3 = -INFINITY, s4 = -INFINITY, s5 = -INFINITY;
  const unsigned char* mrow = mask + (long)n * NN;
  {
    int j;
    j = lane;        if (!mrow[j]) s0 = S[sb + j];
    j = lane + 64;   if (!mrow[j]) s1 = S[sb + j];
    j = lane + 128;  if (!mrow[j]) s2 = S[sb + j];
    j = lane + 192;  if (!mrow[j]) s3 = S[sb + j];
    j = lane + 256;  if (!mrow[j]) s4 = S[sb + j];
    j = lane + 320;  if (j < NN && !mrow[j]) s5 = S[sb + j];
  }
  float mx = fmaxf(fmaxf(fmaxf(s0, s1), fmaxf(s2, s3)), fmaxf(s4, s5));
  for (int m = 1; m < 64; m <<= 1) mx = fmaxf(mx, __shfl_xor(mx, m));
  long qoff = (bt * MM + (long)w * NN + n) * DD;
  int pA = (w == 1) ? n : NN + n;
  float qd = h2f(qb[qoff + lane]);
  float da = qd * h2f(kb[(bt * MM + pA) * DD + lane]);
  for (int m = 1; m < 64; m <<= 1) da += __shfl_xor(da, m);
  float db = 0.f;
  if (w == 1) {
    float t = qd * h2f(kb[(bt * MM + 2 * NN + n) * DD + lane]);
    for (int m = 1; m < 64; m <<= 1) t += __shfl_xor(t, m);
    db = t;
  }
  float gm = fmaxf(mx, da);
  if (w == 1) gm = fmaxf(gm, db);
  float p0 = s0 > -1e37f ? __expf(s0 - gm) : 0.f;
  float p1 = s1 > -1e37f ? __expf(s1 - gm) : 0.f;
  float p2 = s2 > -1e37f ? __expf(s2 - gm) : 0.f;
  float p3 = s3 > -1e37f ? __expf(s3 - gm) : 0.f;
  float p4 = s4 > -1e37f ? __expf(s4 - gm) : 0.f;
  float p5 = s5 > -1e37f ? __expf(s5 - gm) : 0.f;
  float sum = p0 + p1 + p2 + p3 + p4 + p5;
  for (int m = 1; m < 64; m <<= 1) sum += __shfl_xor(sum, m);
  float ea = __expf(da - gm);
  float eb = (w == 1) ? __expf(db - gm) : 0.f;
  sum += ea + eb;
  float inv = 1.f / sum;
  unsigned short* prow = Pb + (long)row * PSTR;
  prow[lane]       = f2h(p0 * inv);
  prow[lane + 64]  = f2h(p1 * inv);
  prow[lane + 128] = f2h(p2 * inv);
  prow[lane + 192] = f2h(p3 * inv);
  prow[lane + 256] = f2h(p4 * inv);
  {
    int j = lane + 320;
    if (j < NN) prow[j] = f2h(p5 * inv);
    else if (j < PSTR) prow[j] = 0;
  }
  if (lane == 0) { pda[row] = ea * inv; pdb[row] = (w == 1) ? eb * inv : 0.f; }
}

// ---------------- PV via MFMA: [325x352]x[352x64] + diag epilogue --------
__global__ __launch_bounds__(256) void k_pv_mfma(const unsigned short* __restrict__ Pb,
                                                 const float* __restrict__ pda,
                                                 const float* __restrict__ pdb,
                                                 const unsigned short* __restrict__ vb,
                                                 float* __restrict__ sem,
                                                 int bt_base) {
  __shared__ alignas(16) unsigned short Al[128 * 40];
  __shared__ alignas(16) unsigned short Bt[64 * 40];
  int btw = blockIdx.x;
  int btl = btw / 3, w = btw - btl * 3;
  long bt = bt_base + btl;
  int rt_blk = blockIdx.y;
  long prow0 = (long)(btl * 3 + w) * NN;
  long vbase = bt * MM + (long)w * NN;
  int tid = threadIdx.x;
  int lane = tid & 63;
  int wv = __builtin_amdgcn_readfirstlane(tid >> 6);
  int lr = lane & 15, lg = lane >> 4;
  f32x4 zero4 = {0.f, 0.f, 0.f, 0.f};
  f32x4 acc[2][4];
#pragma unroll
  for (int rt = 0; rt < 2; ++rt)
#pragma unroll
    for (int c = 0; c < 4; ++c) acc[rt][c] = zero4;
  for (int kb_ = 0; kb_ < 352; kb_ += 32) {
    __syncthreads();
    for (int u = 0; u < 2; ++u) {
      int idx = tid + 256 * u;
      int row = idx >> 2, c8 = idx & 3;
      int rr = rt_blk * 128 + row; if (rr > NN - 1) rr = NN - 1;
      *(uint4*)&Al[row * 40 + c8 * 8] = *(const uint4*)&Pb[(prow0 + rr) * PSTR + kb_ + c8 * 8];
    }
    for (int u = 0; u < 2; ++u) {
      int idx = tid + 256 * u;
      int k = idx >> 4, c4 = idx & 15;
      int kg = kb_ + k;
      ushort4 vv;
      if (kg < NN) vv = *(const ushort4*)&vb[(vbase + kg) * 64 + c4 * 4];
      else { vv.x = 0; vv.y = 0; vv.z = 0; vv.w = 0; }
      Bt[(4 * c4 + 0) * 40 + k] = vv.x;
      Bt[(4 * c4 + 1) * 40 + k] = vv.y;
      Bt[(4 * c4 + 2) * 40 + k] = vv.z;
      Bt[(4 * c4 + 3) * 40 + k] = vv.w;
    }
    __syncthreads();
    half8 a0 = *(const half8*)&Al[(32 * wv + lr) * 40 + lg * 8];
    half8 a1 = *(const half8*)&Al[(32 * wv + 16 + lr) * 40 + lg * 8];
#pragma unroll
    for (int c = 0; c < 4; ++c) {
      half8 b = *(const half8*)&Bt[(16 * c + lr) * 40 + lg * 8];
      acc[0][c] = __builtin_amdgcn_mfma_f32_16x16x32_f16(a0, b, acc[0][c], 0, 0, 0);
      acc[1][c] = __builtin_amdgcn_mfma_f32_16x16x32_f16(a1, b, acc[1][c], 0, 0, 0);
    }
  }
#pragma unroll
  for (int rt = 0; rt < 2; ++rt)
#pragma unroll
    for (int c = 0; c < 4; ++c)
#pragma unroll
      for (int e = 0; e < 4; ++e) {
        int n = rt_blk * 128 + 32 * wv + 16 * rt + lg * 4 + e;
        int col = 16 * c + lr;
        if (n < NN) {
          float val = acc[rt][c][e];
          int partA = (w == 1) ? n : NN + n;
          val += pda[prow0 + n] * h2f(vb[(bt * MM + partA) * 64 + col]);
          if (w == 1)
            val += pdb[prow0 + n] * h2f(vb[(bt * MM + 2 * NN + n) * 64 + col]);
          sem[(bt * MM + (long)w * NN + n) * 64 + col] = val;
        }
      }
}

// ---------------- xs1 via MFMA: gso x stX(block) + diag epilogue ---------
__global__ __launch_bounds__(256) void k_xs1_mfma(const unsigned short* __restrict__ gsoB,
                                                  const unsigned short* __restrict__ stXb,
                                                  const float* __restrict__ stX,
                                                  const float* __restrict__ pt12,
                                                  const float* __restrict__ pt21,
                                                  const float* __restrict__ pt23,
                                                  const float* __restrict__ pt32,
                                                  float* __restrict__ xs1f,
                                                  unsigned short* __restrict__ xs1b) {
  __shared__ alignas(16) unsigned short Al[128 * 40];
  __shared__ alignas(16) unsigned short Bt[64 * 40];
  int btw = blockIdx.x;
  int bt = btw / 3, w = btw - bt * 3;
  int b = bt / TT;
  int rt_blk = blockIdx.y;
  const unsigned short* A = gsoB + (long)b * NN * GSTR;
  long vbase = (long)bt * MM + (long)w * NN;
  int tid = threadIdx.x;
  int lane = tid & 63;
  int wv = __builtin_amdgcn_readfirstlane(tid >> 6);
  int lr = lane & 15, lg = lane >> 4;
  f32x4 zero4 = {0.f, 0.f, 0.f, 0.f};
  f32x4 acc[2][4];
#pragma unroll
  for (int rt = 0; rt < 2; ++rt)
#pragma unroll
    for (int c = 0; c < 4; ++c) acc[rt][c] = zero4;
  for (int kb_ = 0; kb_ < 352; kb_ += 32) {
    __syncthreads();
    for (int u = 0; u < 2; ++u) {
      int idx = tid + 256 * u;
      int row = idx >> 2, c8 = idx & 3;
      int rr = rt_blk * 128 + row; if (rr > NN - 1) rr = NN - 1;
      *(uint4*)&Al[row * 40 + c8 * 8] = *(const uint4*)&A[(long)rr * GSTR + kb_ + c8 * 8];
    }
    for (int u = 0; u < 2; ++u) {
      int idx = tid + 256 * u;
      int k = idx >> 4, c4 = idx & 15;
      int kg = kb_ + k;
      ushort4 vv;
      if (kg < NN) vv = *(const ushort4*)&stXb[(vbase + kg) * 64 + c4 * 4];
      else { vv.x = 0; vv.y = 0; vv.z = 0; vv.w = 0; }
      Bt[(4 * c4 + 0) * 40 + k] = vv.x;
      Bt[(4 * c4 + 1) * 40 + k] = vv.y;
      Bt[(4 * c4 + 2) * 40 + k] = vv.z;
      Bt[(4 * c4 + 3) * 40 + k] = vv.w;
    }
    __syncthreads();
    half8 a0 = *(const half8*)&Al[(32 * wv + lr) * 40 + lg * 8];
    half8 a1 = *(const half8*)&Al[(32 * wv + 16 + lr) * 40 + lg * 8];
#pragma unroll
    for (int c = 0; c < 4; ++c) {
      half8 b_ = *(const half8*)&Bt[(16 * c + lr) * 40 + lg * 8];
      acc[0][c] = __builtin_amdgcn_mfma_f32_16x16x32_f16(a0, b_, acc[0][c], 0, 0, 0);
      acc[1][c] = __builtin_amdgcn_mfma_f32_16x16x32_f16(a1, b_, acc[1][c], 0, 0, 0);
    }
  }
  long btM = (long)bt * MM;
#pragma unroll
  for (int rt = 0; rt < 2; ++rt)
#pragma unroll
    for (int c = 0; c < 4; ++c)
#pragma unroll
      for (int e = 0; e < 4; ++e) {
        int n = rt_blk * 128 + 32 * wv + 16 * rt + lg * 4 + e;
        int col = 16 * c + lr;
        if (n < NN) {
          float val = acc[rt][c][e];
          if (w == 0) {
            val += pt21[n] * stX[(btM + NN + n) * 64 + col];
          } else if (w == 1) {
            val += pt12[n] * stX[(btM + n) * 64 + col]
                 + pt32[n] * stX[(btM + 2 * NN + n) * 64 + col];
          } else {
            val += pt23[n] * stX[(btM + NN + n) * 64 + col];
          }
          long o = (btM + (long)w * NN + n) * 64 + col;
          xs1f[o] = val;
          xs1b[o] = f2h(val);
        }
      }
}

// ---------------- t2 via MFMA: 2*(L*xs1)[mid] - stX[mid] -----------------
__global__ __launch_bounds__(256) void k_t2_mfma(const unsigned short* __restrict__ gsoB,
                                                 const unsigned short* __restrict__ xs1b,
                                                 const float* __restrict__ xs1f,
                                                 const float* __restrict__ stX,
                                                 const float* __restrict__ pt12,
                                                 const float* __restrict__ pt32,
                                                 float* __restrict__ t2o) {
  __shared__ alignas(16) unsigned short Al[128 * 40];
  __shared__ alignas(16) unsigned short Bt[64 * 40];
  int bt = blockIdx.x;
  int b = bt / TT;
  int rt_blk = blockIdx.y;
  const unsigned short* A = gsoB + (long)b * NN * GSTR;
  long vbase = (long)bt * MM + NN;
  int tid = threadIdx.x;
  int lane = tid & 63;
  int wv = __builtin_amdgcn_readfirstlane(tid >> 6);
  int lr = lane & 15, lg = lane >> 4;
  f32x4 zero4 = {0.f, 0.f, 0.f, 0.f};
  f32x4 acc[2][4];
#pragma unroll
  for (int rt = 0; rt < 2; ++rt)
#pragma unroll
    for (int c = 0; c < 4; ++c) acc[rt][c] = zero4;
  for (int kb_ = 0; kb_ < 352; kb_ += 32) {
    __syncthreads();
    for (int u = 0; u < 2; ++u) {
      int idx = tid + 256 * u;
      int row = idx >> 2, c8 = idx & 3;
      int rr = rt_blk * 128 + row; if (rr > NN - 1) rr = NN - 1;
      *(uint4*)&Al[row * 40 + c8 * 8] = *(const uint4*)&A[(long)rr * GSTR + kb_ + c8 * 8];
    }
    for (int u = 0; u < 2; ++u) {
      int idx = tid + 256 * u;
      int k = idx >> 4, c4 = idx & 15;
      int kg = kb_ + k;
      ushort4 vv;
      if (kg < NN) vv = *(const ushort4*)&xs1b[(vbase + kg) * 64 + c4 * 4];
      else { vv.x = 0; vv.y = 0; vv.z = 0; vv.w = 0; }
      Bt[(4 * c4 + 0) * 40 + k] = vv.x;
      Bt[(4 * c4 + 1) * 40 + k] = vv.y;
      Bt[(4 * c4 + 2) * 40 + k] = vv.z;
      Bt[(4 * c4 + 3) * 40 + k] = vv.w;
    }
    __syncthreads();
    half8 a0 = *(const half8*)&Al[(32 * wv + lr) * 40 + lg * 8];
    half8 a1 = *(const half8*)&Al[(32 * wv + 16 + lr) * 40 + lg * 8];
#pragma unroll
    for (int c = 0; c < 4; ++c) {
      half8 b_ = *(const half8*)&Bt[(16 * c + lr) * 40 + lg * 8];
      acc[0][c] = __builtin_amdgcn_mfma_f32_16x16x32_f16(a0, b_, acc[0][c], 0, 0, 0);
      acc[1][c] = __builtin_amdgcn_mfma_f32_16x16x32_f16(a1, b_, acc[1][c], 0, 0, 0);
    }
  }
  long btM = (long)bt * MM;
#pragma unroll
  for (int rt = 0; rt < 2; ++rt)
#pragma unroll
    for (int c = 0; c < 4; ++c)
#pragma unroll
      for (int e = 0; e < 4; ++e) {
        int n = rt_blk * 128 + 32 * wv + 16 * rt + lg * 4 + e;
        int col = 16 * c + lr;
        if (n < NN) {
          float val = 2.f * (pt12[n] * xs1f[(btM + n) * 64 + col]
                             + acc[rt][c][e]
                             + pt32[n] * xs1f[(btM + 2 * NN + n) * 64 + col])
                      - stX[(btM + NN + n) * 64 + col];
          t2o[((long)bt * NN + n) * 64 + col] = val;
        }
      }
}

// -------- cheb combine (middle rows) + LayerNorm -------------------------
__global__ __launch_bounds__(256) void k_cheb(const float* __restrict__ stX,
                                              const float* __restrict__ xs1,
                                              const float* __restrict__ t2o,
                                              const float* __restrict__ cw,
                                              const float* __restrict__ lng,
                                              const float* __restrict__ lnb,
                                              float* __restrict__ gcn) {
  __shared__ float cl[3 * 64 * 64];
  int tid = threadIdx.x;
  for (int u = 0; u < 48; ++u) cl[tid + 256 * u] = cw[tid + 256 * u];
  __syncthreads();
  int lane = tid & 63;
  int wv = __builtin_amdgcn_readfirstlane(tid >> 6);
  float g_ = lng[lane], b_ = lnb[lane];
  for (int pp = 0; pp < 8; ++pp) {
    int row0 = blockIdx.x * 64 + wv * 16 + pp * 2;
    if (row0 >= 96 * NN) break;
    int row1 = min(row0 + 1, 96 * NN - 1);
    int bt0 = row0 / NN, n0 = row0 - bt0 * NN;
    int bt1 = row1 / NN, n1 = row1 - bt1 * NN;
    const float* a00 = stX + ((long)bt0 * MM + NN + n0) * DD;
    const float* a01 = xs1 + ((long)bt0 * MM + NN + n0) * DD;
    const float* a02 = t2o + (long)row0 * DD;
    const float* a10 = stX + ((long)bt1 * MM + NN + n1) * DD;
    const float* a11 = xs1 + ((long)bt1 * MM + NN + n1) * DD;
    const float* a12 = t2o + (long)row1 * DD;
    float h0 = 0.f, h1 = 0.f;
#pragma unroll
    for (int kk = 0; kk < 3; ++kk) {
      const float* A0 = kk == 0 ? a00 : (kk == 1 ? a01 : a02);
      const float* A1 = kk == 0 ? a10 : (kk == 1 ? a11 : a12);
#pragma unroll 8
      for (int i = 0; i < 64; ++i) {
        float c = cl[(kk * 64 + i) * 64 + lane];
        h0 += A0[i] * c;
        h1 += A1[i] * c;
      }
    }
    float s0 = h0, s1 = h1;
    for (int m = 1; m < 64; m <<= 1) { s0 += __shfl_xor(s0, m); s1 += __shfl_xor(s1, m); }
    float mu0 = s0 * (1.f / 64.f), mu1 = s1 * (1.f / 64.f);
    float d0 = h0 - mu0, d1 = h1 - mu1;
    float q0 = d0 * d0, q1 = d1 * d1;
    for (int m = 1; m < 64; m <<= 1) { q0 += __shfl_xor(q0, m); q1 += __shfl_xor(q1, m); }
    float var0 = q0 * (1.f / 64.f), var1 = q1 * (1.f / 64.f);
    gcn[(long)row0 * DD + lane] = d0 * rsqrtf(var0 + LN_EPS_) * g_ + b_;
    if (row0 + 1 < 96 * NN)
      gcn[(long)(row0 + 1) * DD + lane] = d1 * rsqrtf(var1 + LN_EPS_) * g_ + b_;
  }
}

// -------- mean over (t,n) per (b,d), inline scramble-gather --------------
__global__ __launch_bounds__(256) void k_mean(const float* __restrict__ sem,
                                              const float* __restrict__ gcn,
                                              float* __restrict__ mbd) {
  __shared__ float red[4][64];
  int bt = blockIdx.x;
  int b = bt / TT;
  int d = threadIdx.x & 63, g = threadIdx.x >> 6;
  float s = 0.f;
  for (int n = g; n < NN; n += 4) {
    int f = (NN + n) * 64 + d;
    int mm = f % MM, ii = f / MM;
    float a = sem[((long)bt * MM + mm) * 64 + ii];
    float r = gcn[((long)bt * NN + n) * 64 + d];
    s += a + r;
  }
  red[g][d] = s;
  __syncthreads();
  if (threadIdx.x < 64) {
    float v = red[0][d] + red[1][d] + red[2][d] + red[3][d];
    atomicAdd(&mbd[b * 64 + d], v);
  }
}

// -------- global AFF branch ----------------------------------------------
__global__ __launch_bounds__(64) void k_glob(const float* __restrict__ mbd,
                                             const float* __restrict__ w1,
                                             const float* __restrict__ b1,
                                             const float* __restrict__ g1,
                                             const float* __restrict__ be1,
                                             const float* __restrict__ w2,
                                             const float* __restrict__ b2,
                                             const float* __restrict__ g2,
                                             const float* __restrict__ be2,
                                             float* __restrict__ xg) {
  __shared__ float ml[64];
  __shared__ float zg[16];
  int b = blockIdx.x, d = threadIdx.x;
  ml[d] = mbd[b * 64 + d] * (1.f / 3900.f);
  __syncthreads();
  float rb = rsqrtf(1.f + BN_EPS_);
  if (d < 16) {
    float a = b1[d];
    for (int i = 0; i < 64; ++i) a += w1[d * 64 + i] * ml[i];
    a = a * (g1[d] * rb) + be1[d];
    zg[d] = a > 0.f ? a : 0.f;
  }
  __syncthreads();
  float a = b2[d];
  for (int i = 0; i < 16; ++i) a += w2[d * 16 + i] * zg[i];
  xg[b * 64 + d] = a * (g2[d] * rb) + be2[d];
}

// -------- final: local AFF branch + sigmoid fuse (inline gather) ---------
__global__ __launch_bounds__(256) void k_final(const float* __restrict__ sem,
                                               const float* __restrict__ gcn,
                                               const float* __restrict__ xg,
                                               const float* __restrict__ w1,
                                               const float* __restrict__ b1,
                                               const float* __restrict__ g1,
                                               const float* __restrict__ be1,
                                               const float* __restrict__ w2,
                                               const float* __restrict__ b2,
                                               const float* __restrict__ g2,
                                               const float* __restrict__ be2,
                                               float* __restrict__ out) {
  __shared__ float w1l[16][65];
  __shared__ float w2l[64][17];
  __shared__ float xal[4][64];
  __shared__ float zll[4][16];
  int tid = threadIdx.x;
  for (int u = 0; u < 4; ++u) {
    int f = tid + 256 * u;
    w1l[f >> 6][f & 63] = w1[f];
    w2l[f >> 4][f & 15] = w2[f];
  }
  int lane = tid & 63, wv = tid >> 6;
  long row = (long)blockIdx.x * 4 + wv;        // 31,200 rows exact
  int bt = (int)(row / NN);
  int n = (int)(row - (long)bt * NN);
  int b = bt / TT;
  int f = (NN + n) * 64 + lane;
  int mm = f % MM, ii = f / MM;
  float a = sem[((long)bt * MM + mm) * 64 + ii];
  float r = gcn[row * DD + lane];
  float xa = a + r;
  xal[wv][lane] = xa;
  __syncthreads();
  float rb = rsqrtf(1.f + BN_EPS_);
  if (lane < 16) {
    float acc = b1[lane];
#pragma unroll 8
    for (int i = 0; i < 64; ++i) acc += w1l[lane][i] * xal[wv][i];
    acc = acc * (g1[lane] * rb) + be1[lane];
    zll[wv][lane] = acc > 0.f ? acc : 0.f;
  }
  __syncthreads();
  float acc = b2[lane];
#pragma unroll
  for (int i = 0; i < 16; ++i) acc += w2l[lane][i] * zll[wv][i];
  float xl = acc * (g2[lane] * rb) + be2[lane];
  float wei = 1.f / (1.f + __expf(-(xl + xg[b * 64 + lane])));
  out[row * DD + lane] = 2.f * a * wei + 2.f * r * (1.f - wei);
}

extern "C" void kernel_launch(void* const* d_in, const int* in_sizes, int n_in,
                              void* d_out, int out_size, void* d_ws, size_t ws_size,
                              hipStream_t stream) {
  const float* x    = (const float*)d_in[0];
  const float* gso  = (const float*)d_in[1];
  const unsigned char* mask_raw = (const unsigned char*)d_in[2];
  const float* Wq   = (const float*)d_in[3];
  const float* Wk   = (const float*)d_in[4];
  const float* Wv   = (const float*)d_in[5];
  const float* chw  = (const float*)d_in[6];
  const float* pt12 = (const float*)d_in[7];
  const float* pt21 = (const float*)d_in[8];
  const float* pt23 = (const float*)d_in[9];
  const float* pt32 = (const float*)d_in[10];
  const float* lng  = (const float*)d_in[11];
  const float* lnb  = (const float*)d_in[12];
  const float* l_w1 = (const float*)d_in[13];
  const float* l_b1 = (const float*)d_in[14];
  const float* l_g1 = (const float*)d_in[15];
  const float* l_be1= (const float*)d_in[16];
  const float* l_w2 = (const float*)d_in[17];
  const float* l_b2 = (const float*)d_in[18];
  const float* l_g2 = (const float*)d_in[19];
  const float* l_be2= (const float*)d_in[20];
  const float* g_w1 = (const float*)d_in[21];
  const float* g_b1 = (const float*)d_in[22];
  const float* g_g1 = (const float*)d_in[23];
  const float* g_be1= (const float*)d_in[24];
  const float* g_w2 = (const float*)d_in[25];
  const float* g_b2 = (const float*)d_in[26];
  const float* g_g2 = (const float*)d_in[27];
  const float* g_be2= (const float*)d_in[28];

  float* base = (float*)d_ws;
  unsigned char* nmask = (unsigned char*)d_ws;
  unsigned short* gsoB = (unsigned short*)(base + WS_GSOB);
  float* stX           = base + WS_STX;
  unsigned short* stXb = (unsigned short*)(base + WS_STXB);
  unsigned short* qb   = (unsigned short*)(base + WS_QB);
  unsigned short* kb   = (unsigned short*)(base + WS_KB);
  unsigned short* vb   = (unsigned short*)(base + WS_VB);
  float* sem           = base + WS_SEM;
  float* Gf            = base + WS_G;

  // aliases after attention (lifetimes disjoint):
  float* xs1f = (float*)qb;                    // spans qb+kb = SZ floats
  unsigned short* xs1b = vb;                   // SZ shorts
  float* t2o = (float*)stXb;                   // 1,996,800 f <= 2,995,200 f
  float* gcn = (float*)vb;                     // after t2 consumed xs1b
  float* mbd = Gf;
  float* xg  = Gf + 512;

  // attention chunk sizing
  long avail_f = (long)(ws_size / sizeof(float)) - WS_G;
  const int cands[9] = {24, 16, 12, 8, 6, 4, 3, 2, 1};
  int cbt = 1;
  for (int i = 0; i < 9; ++i) {
    if ((long)cands[i] * PERBT <= avail_f) { cbt = cands[i]; break; }
  }
  float* Sf = Gf;                                          // cbt*3*NN*SLD f
  unsigned short* Pb = (unsigned short*)(Sf + (long)cbt * 3 * NN * SLD);
  float* pda = (float*)(Pb + (long)cbt * MM * PSTR);       // cbt*MM f
  float* pdb = pda + (long)cbt * MM;

  k_maskprep<<<(NN * NN + 255) / 256, 256, 0, stream>>>(mask_raw, nmask);
  k_gsoprep<<<3575, 256, 0, stream>>>(gso, gsoB);
  k_stx<<<23400, 256, 0, stream>>>(x, stX, stXb);
  {
    dim3 g(732, 3);
    k_qkv_mfma<<<g, 256, 0, stream>>>(stXb, Wq, Wk, Wv, qb, kb, vb);
  }
  for (int bb = 0; bb < 96; bb += cbt) {
    dim3 gs(cbt * 3, 3, 3);
    k_scores_mfma<<<gs, 256, 0, stream>>>(qb, kb, Sf, bb);
    int nrows = cbt * MM;
    k_softmax<<<(nrows + 3) / 4, 256, 0, stream>>>(qb, kb, nmask, Sf, Pb, pda, pdb, bb, nrows);
    dim3 gp(cbt * 3, 3);
    k_pv_mfma<<<gp, 256, 0, stream>>>(Pb, pda, pdb, vb, sem, bb);
  }
  {
    dim3 g(288, 3);
    k_xs1_mfma<<<g, 256, 0, stream>>>(gsoB, stXb, stX, pt12, pt21, pt23, pt32, xs1f, xs1b);
  }
  {
    dim3 g(96, 3);
    k_t2_mfma<<<g, 256, 0, stream>>>(gsoB, xs1b, xs1f, stX, pt12, pt32, t2o);
  }
  k_cheb<<<488, 256, 0, stream>>>(stX, xs1f, t2o, chw, lng, lnb, gcn);
  hipMemsetAsync(mbd, 0, 1024 * sizeof(float), stream);
  k_mean<<<96, 256, 0, stream>>>(sem, gcn, mbd);
  k_glob<<<8, 64, 0, stream>>>(mbd, g_w1, g_b1, g_g1, g_be1, g_w2, g_b2, g_g2, g_be2, xg);
  k_final<<<7800, 256, 0, stream>>>(sem, gcn, xg,
                                    l_w1, l_b1, l_g1, l_be1,
                                    l_w2, l_b2, l_g2, l_be2,
                                    (float*)d_out);
}

// Round 6
// 468.584 us; speedup vs baseline: 3.8265x; 1.1605x over previous
//
#include <hip/hip_runtime.h>
#include <math.h>

constexpr int TT = 12;
constexpr int NN = 325;
constexpr int MM = 975;   // 3*NN
constexpr int DD = 64;
constexpr long SZ = 96L * MM * DD;       // 5,990,400 floats per big buffer
constexpr int PSTR = 352;                // P row stride (fp16 shorts), zero-padded
constexpr int GSTR = 352;                // gso row stride (fp16 shorts), zero-padded
constexpr int MSTR = 336;                // padded mask row stride (bytes)
constexpr float BN_EPS_ = 1e-5f;
constexpr float LN_EPS_ = 1e-5f;

// ---- workspace float offsets (running map; all sizes in floats) ----------
constexpr long WS_MASKP = 0;                          // 325*336 B -> 27,392 f
constexpr long WS_GSOB  = WS_MASKP + 27392;           // 915,200 shorts = 457,600 f
constexpr long WS_STX   = WS_GSOB + 457600;           // SZ f
constexpr long WS_STXB  = WS_STX + SZ;                // SZ/2 f
constexpr long WS_QB    = WS_STXB + SZ / 2;           // SZ/2 f
constexpr long WS_KB    = WS_QB + SZ / 2;             // SZ/2 f
constexpr long WS_VB    = WS_KB + SZ / 2;             // SZ/2 f
constexpr long WS_SEM   = WS_VB + SZ / 2;             // SZ f
constexpr long WS_T2B   = WS_SEM + SZ;                // 31200*64 shorts = 998,400 f
constexpr long WS_G     = WS_T2B + 998400;            // chunk region / mbd / xg
// per-bt chunk: Pb = MM*PSTR shorts = 171,600 f; pda+pdb = 2*MM f -> 1,950
constexpr long PERBT = 171600 + 1950;                 // 173,550 f

typedef _Float16 half8 __attribute__((ext_vector_type(8)));
typedef __attribute__((ext_vector_type(4))) float f32x4;

static __device__ inline unsigned short f2h(float f) {
  _Float16 h = (_Float16)f;
  return __builtin_bit_cast(unsigned short, h);
}
static __device__ inline float h2f(unsigned short s) {
  return (float)__builtin_bit_cast(_Float16, s);
}

// ------------- mask sniff + normalize to padded [NN][MSTR] u8 -------------
__global__ __launch_bounds__(256) void k_maskprep(const unsigned char* __restrict__ raw,
                                                  unsigned char* __restrict__ outm) {
  bool is_u8 = false;
  for (int i = 0; i < 256; ++i) {
    if (raw[4 * i + 1]) { is_u8 = true; break; }
  }
  int idx = blockIdx.x * 256 + threadIdx.x;     // 427 blocks covers NN*MSTR
  if (idx >= NN * MSTR) return;
  int n = idx / MSTR, j = idx - n * MSTR;
  unsigned char v = 1;                           // pad cols -> masked
  if (j < NN) {
    int f = n * NN + j;
    if (is_u8) v = (raw[f] != 0);
    else       v = (((const int*)raw)[f] != 0);
  }
  outm[idx] = v;
}

// ------------- gso -> fp16, padded rows [8][325][GSTR] --------------------
__global__ __launch_bounds__(256) void k_gsoprep(const float* __restrict__ gso,
                                                 unsigned short* __restrict__ gsoB) {
  int idx = blockIdx.x * 256 + threadIdx.x;   // 3575 blocks exact
  int b = idx / (NN * GSTR);
  int rem = idx - b * (NN * GSTR);
  int r = rem / GSTR, j = rem - r * GSTR;
  gsoB[idx] = (j < NN) ? f2h(gso[(long)b * NN * NN + r * NN + j]) : (unsigned short)0;
}

// ---------------- stX gather: [B,T,N,D] -> [BT, 3N, D] (f32 + fp16) ------
__global__ __launch_bounds__(256) void k_stx(const float* __restrict__ x,
                                             float* __restrict__ stX,
                                             unsigned short* __restrict__ stXb) {
  int idx = blockIdx.x * 256 + threadIdx.x;     // exact: 23,400 blocks
  int d = idx & 63;
  int m = (idx >> 6) % MM;
  int bt = idx / (MM * DD);
  int b = bt / TT, t = bt - b * TT;
  int w = m / NN, n = m - w * NN;
  int st = t + w - 1;
  st = st < 0 ? 0 : (st > TT - 1 ? TT - 1 : st);
  float val = x[(((b * TT + st) * NN + n) << 6) + d];
  stX[idx] = val;
  stXb[idx] = f2h(val);
}

// ---------------- QKV via MFMA: [93600x64] x [64x64] -> fp16 -------------
__global__ __launch_bounds__(256) void k_qkv_mfma(const unsigned short* __restrict__ stXb,
                                                  const float* __restrict__ Wq,
                                                  const float* __restrict__ Wk,
                                                  const float* __restrict__ Wv,
                                                  unsigned short* __restrict__ qb,
                                                  unsigned short* __restrict__ kb,
                                                  unsigned short* __restrict__ vb) {
  __shared__ alignas(16) unsigned short sX[128 * 72];
  __shared__ alignas(16) unsigned short sW[64 * 72];
  const float* W = blockIdx.y == 0 ? Wq : (blockIdx.y == 1 ? Wk : Wv);
  unsigned short* outb = blockIdx.y == 0 ? qb : (blockIdx.y == 1 ? kb : vb);
  int tid = threadIdx.x;
  long r0 = (long)blockIdx.x * 128;
  for (int u = 0; u < 4; ++u) {
    int idx = tid + 256 * u;
    int row = idx >> 3, c8 = idx & 7;
    long rg = r0 + row; if (rg > 93599) rg = 93599;
    *(uint4*)&sX[row * 72 + c8 * 8] = *(const uint4*)&stXb[rg * 64 + c8 * 8];
  }
  for (int u = 0; u < 16; ++u) {
    int f = tid + 256 * u;
    int o = f >> 6, d = f & 63;
    sW[o * 72 + d] = f2h(W[f]);
  }
  __syncthreads();
  int lane = tid & 63;
  int wv = __builtin_amdgcn_readfirstlane(tid >> 6);
  int lr = lane & 15, lg = lane >> 4;
  f32x4 zero4 = {0.f, 0.f, 0.f, 0.f};
  f32x4 acc[2][4];
#pragma unroll
  for (int rt = 0; rt < 2; ++rt)
#pragma unroll
    for (int c = 0; c < 4; ++c) acc[rt][c] = zero4;
#pragma unroll
  for (int kk = 0; kk < 2; ++kk) {
    half8 a0 = *(const half8*)&sX[(32 * wv + lr) * 72 + kk * 32 + lg * 8];
    half8 a1 = *(const half8*)&sX[(32 * wv + 16 + lr) * 72 + kk * 32 + lg * 8];
#pragma unroll
    for (int c = 0; c < 4; ++c) {
      half8 b = *(const half8*)&sW[(16 * c + lr) * 72 + kk * 32 + lg * 8];
      acc[0][c] = __builtin_amdgcn_mfma_f32_16x16x32_f16(a0, b, acc[0][c], 0, 0, 0);
      acc[1][c] = __builtin_amdgcn_mfma_f32_16x16x32_f16(a1, b, acc[1][c], 0, 0, 0);
    }
  }
  __syncthreads();
#pragma unroll
  for (int rt = 0; rt < 2; ++rt)
#pragma unroll
    for (int c = 0; c < 4; ++c)
#pragma unroll
      for (int e = 0; e < 4; ++e) {
        int row = 32 * wv + 16 * rt + lg * 4 + e;
        int col = 16 * c + lr;
        sX[row * 64 + col] = f2h(acc[rt][c][e]);
      }
  __syncthreads();
  for (int u = 0; u < 4; ++u) {
    int idx = tid + 256 * u;
    int row = idx >> 3, c8 = idx & 7;
    long rg = r0 + row;
    if (rg < 93600)
      *(uint4*)&outb[rg * 64 + c8 * 8] = *(const uint4*)&sX[row * 64 + c8 * 8];
  }
}

// ------- fused scores + masked softmax (+diag via MFMA) -> Pb/pda/pdb ----
// block: (bt,w) x 64-row tile; computes all 325 cols in registers.
__global__ __launch_bounds__(256) void k_ssm(const unsigned short* __restrict__ qb,
                                             const unsigned short* __restrict__ kb,
                                             const unsigned char* __restrict__ maskp,
                                             unsigned short* __restrict__ Pb,
                                             float* __restrict__ pda,
                                             float* __restrict__ pdb,
                                             int bt_base) {
  __shared__ alignas(16) unsigned short Kl[336 * 72];
  __shared__ alignas(16) unsigned short Ql[64 * 72];
  __shared__ alignas(16) unsigned char Ml[64 * MSTR];
  int btw = blockIdx.x;
  int btl = btw / 3, w = btw - btl * 3;
  long bt = bt_base + btl;
  int rt = blockIdx.y;                       // 0..5, 64 rows each
  long base = (bt * MM + (long)w * NN) * 64; // shorts
  int tid = threadIdx.x;
  // K: 336 clamped rows
  for (int u = 0; u < 11; ++u) {
    int idx = tid + 256 * u;
    if (idx < 2688) {
      int r = idx >> 3, c8 = idx & 7;
      int rr = r < NN ? r : NN - 1;
      *(uint4*)&Kl[r * 72 + c8 * 8] = *(const uint4*)&kb[base + (long)rr * 64 + c8 * 8];
    }
  }
  // Q: 64 rows
  for (int u = 0; u < 2; ++u) {
    int idx = tid + 256 * u;
    int r = idx >> 3, c8 = idx & 7;
    int rg = rt * 64 + r; if (rg > NN - 1) rg = NN - 1;
    *(uint4*)&Ql[r * 72 + c8 * 8] = *(const uint4*)&qb[base + (long)rg * 64 + c8 * 8];
  }
  // mask rows (padded, 16B aligned)
  for (int u = 0; u < 6; ++u) {
    int idx = tid + 256 * u;
    if (idx < 64 * (MSTR / 16)) {
      int r = idx / (MSTR / 16), c16 = idx - r * (MSTR / 16);
      int rg = rt * 64 + r; if (rg > NN - 1) rg = NN - 1;
      *(uint4*)&Ml[r * MSTR + c16 * 16] = *(const uint4*)&maskp[(long)rg * MSTR + c16 * 16];
    }
  }
  __syncthreads();
  int lane = tid & 63;
  int wv = __builtin_amdgcn_readfirstlane(tid >> 6);
  int lr = lane & 15, lg = lane >> 4;
  f32x4 zero4 = {0.f, 0.f, 0.f, 0.f};
  f32x4 acc[21];
#pragma unroll
  for (int ct = 0; ct < 21; ++ct) acc[ct] = zero4;
  f32x4 dA = zero4, dB = zero4;
  // partner global fragment addresses (B layout: col=lr -> partner of row nl)
  int nl_f = rt * 64 + 16 * wv + lr; if (nl_f > NN - 1) nl_f = NN - 1;
  long pAaddr = (bt * MM + ((w == 1) ? nl_f : NN + nl_f)) * 64;
  long pBaddr = (bt * MM + 2 * NN + nl_f) * 64;
#pragma unroll
  for (int kk = 0; kk < 2; ++kk) {
    half8 a = *(const half8*)&Ql[(16 * wv + lr) * 72 + kk * 32 + lg * 8];
#pragma unroll
    for (int ct = 0; ct < 21; ++ct) {
      half8 b = *(const half8*)&Kl[(16 * ct + lr) * 72 + kk * 32 + lg * 8];
      acc[ct] = __builtin_amdgcn_mfma_f32_16x16x32_f16(a, b, acc[ct], 0, 0, 0);
    }
    half8 bA = *(const half8*)&kb[pAaddr + kk * 32 + lg * 8];
    dA = __builtin_amdgcn_mfma_f32_16x16x32_f16(a, bA, dA, 0, 0, 0);
    if (w == 1) {
      half8 bB = *(const half8*)&kb[pBaddr + kk * 32 + lg * 8];
      dB = __builtin_amdgcn_mfma_f32_16x16x32_f16(a, bB, dB, 0, 0, 0);
    }
  }
  // extract diag: element (r,r) lives at lane (r>>2)*16 + r, reg r&3
  float da_[4], db_[4];
#pragma unroll
  for (int e = 0; e < 4; ++e) {
    int src = lg * 20 + e;                  // (r>>2)*16 + r with r = lg*4+e
    da_[e] = __shfl(dA[e], src);
    db_[e] = (w == 1) ? __shfl(dB[e], src) : -INFINITY;
  }
  // mask + row max
  float mx[4] = {-INFINITY, -INFINITY, -INFINITY, -INFINITY};
#pragma unroll
  for (int ct = 0; ct < 21; ++ct) {
    int col = 16 * ct + lr;
#pragma unroll
    for (int e = 0; e < 4; ++e) {
      int rl = 16 * wv + lg * 4 + e;
      bool masked = (col >= NN) || (Ml[rl * MSTR + col] != 0);
      float s = masked ? -INFINITY : acc[ct][e];
      acc[ct][e] = s;
      mx[e] = fmaxf(mx[e], s);
    }
  }
#pragma unroll
  for (int e = 0; e < 4; ++e)
    for (int m = 1; m < 16; m <<= 1) mx[e] = fmaxf(mx[e], __shfl_xor(mx[e], m));
  float gm[4], ea[4], eb[4], sum[4];
#pragma unroll
  for (int e = 0; e < 4; ++e) {
    gm[e] = fmaxf(mx[e], da_[e]);
    if (w == 1) gm[e] = fmaxf(gm[e], db_[e]);
    sum[e] = 0.f;
  }
#pragma unroll
  for (int ct = 0; ct < 21; ++ct)
#pragma unroll
    for (int e = 0; e < 4; ++e) {
      float s = acc[ct][e];
      float p = (s > -1e37f) ? __expf(s - gm[e]) : 0.f;
      acc[ct][e] = p;
      sum[e] += p;
    }
#pragma unroll
  for (int e = 0; e < 4; ++e) {
    for (int m = 1; m < 16; m <<= 1) sum[e] += __shfl_xor(sum[e], m);
    ea[e] = __expf(da_[e] - gm[e]);
    eb[e] = (w == 1) ? __expf(db_[e] - gm[e]) : 0.f;
    sum[e] += ea[e] + eb[e];
  }
  // write Pb rows + diag probs
  long prow0 = (long)(btl * 3 + w) * NN;
#pragma unroll
  for (int e = 0; e < 4; ++e) {
    int nl = rt * 64 + 16 * wv + lg * 4 + e;
    if (nl < NN) {
      float inv = 1.f / sum[e];
      unsigned short* prow = Pb + (prow0 + nl) * PSTR;
#pragma unroll
      for (int ct = 0; ct < 21; ++ct) prow[16 * ct + lr] = f2h(acc[ct][e] * inv);
      prow[336 + lr] = 0;
      if (lr == 0) { pda[prow0 + nl] = ea[e] * inv; pdb[prow0 + nl] = eb[e] * inv; }
    }
  }
}

// ---------------- PV via MFMA: [325x352]x[352x64] + diag epilogue --------
__global__ __launch_bounds__(256) void k_pv_mfma(const unsigned short* __restrict__ Pb,
                                                 const float* __restrict__ pda,
                                                 const float* __restrict__ pdb,
                                                 const unsigned short* __restrict__ vb,
                                                 float* __restrict__ sem,
                                                 int bt_base) {
  __shared__ alignas(16) unsigned short Al[128 * 40];
  __shared__ alignas(16) unsigned short Bt[64 * 40];
  int btw = blockIdx.x;
  int btl = btw / 3, w = btw - btl * 3;
  long bt = bt_base + btl;
  int rt_blk = blockIdx.y;
  long prow0 = (long)(btl * 3 + w) * NN;
  long vbase = bt * MM + (long)w * NN;
  int tid = threadIdx.x;
  int lane = tid & 63;
  int wv = __builtin_amdgcn_readfirstlane(tid >> 6);
  int lr = lane & 15, lg = lane >> 4;
  f32x4 zero4 = {0.f, 0.f, 0.f, 0.f};
  f32x4 acc[2][4];
#pragma unroll
  for (int rt = 0; rt < 2; ++rt)
#pragma unroll
    for (int c = 0; c < 4; ++c) acc[rt][c] = zero4;
  for (int kb_ = 0; kb_ < 352; kb_ += 32) {
    __syncthreads();
    for (int u = 0; u < 2; ++u) {
      int idx = tid + 256 * u;
      int row = idx >> 2, c8 = idx & 3;
      int rr = rt_blk * 128 + row; if (rr > NN - 1) rr = NN - 1;
      *(uint4*)&Al[row * 40 + c8 * 8] = *(const uint4*)&Pb[(prow0 + rr) * PSTR + kb_ + c8 * 8];
    }
    for (int u = 0; u < 2; ++u) {
      int idx = tid + 256 * u;
      int k = idx >> 4, c4 = idx & 15;
      int kg = kb_ + k;
      ushort4 vv;
      if (kg < NN) vv = *(const ushort4*)&vb[(vbase + kg) * 64 + c4 * 4];
      else { vv.x = 0; vv.y = 0; vv.z = 0; vv.w = 0; }
      Bt[(4 * c4 + 0) * 40 + k] = vv.x;
      Bt[(4 * c4 + 1) * 40 + k] = vv.y;
      Bt[(4 * c4 + 2) * 40 + k] = vv.z;
      Bt[(4 * c4 + 3) * 40 + k] = vv.w;
    }
    __syncthreads();
    half8 a0 = *(const half8*)&Al[(32 * wv + lr) * 40 + lg * 8];
    half8 a1 = *(const half8*)&Al[(32 * wv + 16 + lr) * 40 + lg * 8];
#pragma unroll
    for (int c = 0; c < 4; ++c) {
      half8 b = *(const half8*)&Bt[(16 * c + lr) * 40 + lg * 8];
      acc[0][c] = __builtin_amdgcn_mfma_f32_16x16x32_f16(a0, b, acc[0][c], 0, 0, 0);
      acc[1][c] = __builtin_amdgcn_mfma_f32_16x16x32_f16(a1, b, acc[1][c], 0, 0, 0);
    }
  }
#pragma unroll
  for (int rt = 0; rt < 2; ++rt)
#pragma unroll
    for (int c = 0; c < 4; ++c)
#pragma unroll
      for (int e = 0; e < 4; ++e) {
        int n = rt_blk * 128 + 32 * wv + 16 * rt + lg * 4 + e;
        int col = 16 * c + lr;
        if (n < NN) {
          float val = acc[rt][c][e];
          int partA = (w == 1) ? n : NN + n;
          val += pda[prow0 + n] * h2f(vb[(bt * MM + partA) * 64 + col]);
          if (w == 1)
            val += pdb[prow0 + n] * h2f(vb[(bt * MM + 2 * NN + n) * 64 + col]);
          sem[(bt * MM + (long)w * NN + n) * 64 + col] = val;
        }
      }
}

// ---------------- xs1 via MFMA: gso x stX(block) + diag epilogue ---------
__global__ __launch_bounds__(256) void k_xs1_mfma(const unsigned short* __restrict__ gsoB,
                                                  const unsigned short* __restrict__ stXb,
                                                  const float* __restrict__ stX,
                                                  const float* __restrict__ pt12,
                                                  const float* __restrict__ pt21,
                                                  const float* __restrict__ pt23,
                                                  const float* __restrict__ pt32,
                                                  float* __restrict__ xs1f,
                                                  unsigned short* __restrict__ xs1b) {
  __shared__ alignas(16) unsigned short Al[128 * 40];
  __shared__ alignas(16) unsigned short Bt[64 * 40];
  int btw = blockIdx.x;
  int bt = btw / 3, w = btw - bt * 3;
  int b = bt / TT;
  int rt_blk = blockIdx.y;
  const unsigned short* A = gsoB + (long)b * NN * GSTR;
  long vbase = (long)bt * MM + (long)w * NN;
  int tid = threadIdx.x;
  int lane = tid & 63;
  int wv = __builtin_amdgcn_readfirstlane(tid >> 6);
  int lr = lane & 15, lg = lane >> 4;
  f32x4 zero4 = {0.f, 0.f, 0.f, 0.f};
  f32x4 acc[2][4];
#pragma unroll
  for (int rt = 0; rt < 2; ++rt)
#pragma unroll
    for (int c = 0; c < 4; ++c) acc[rt][c] = zero4;
  for (int kb_ = 0; kb_ < 352; kb_ += 32) {
    __syncthreads();
    for (int u = 0; u < 2; ++u) {
      int idx = tid + 256 * u;
      int row = idx >> 2, c8 = idx & 3;
      int rr = rt_blk * 128 + row; if (rr > NN - 1) rr = NN - 1;
      *(uint4*)&Al[row * 40 + c8 * 8] = *(const uint4*)&A[(long)rr * GSTR + kb_ + c8 * 8];
    }
    for (int u = 0; u < 2; ++u) {
      int idx = tid + 256 * u;
      int k = idx >> 4, c4 = idx & 15;
      int kg = kb_ + k;
      ushort4 vv;
      if (kg < NN) vv = *(const ushort4*)&stXb[(vbase + kg) * 64 + c4 * 4];
      else { vv.x = 0; vv.y = 0; vv.z = 0; vv.w = 0; }
      Bt[(4 * c4 + 0) * 40 + k] = vv.x;
      Bt[(4 * c4 + 1) * 40 + k] = vv.y;
      Bt[(4 * c4 + 2) * 40 + k] = vv.z;
      Bt[(4 * c4 + 3) * 40 + k] = vv.w;
    }
    __syncthreads();
    half8 a0 = *(const half8*)&Al[(32 * wv + lr) * 40 + lg * 8];
    half8 a1 = *(const half8*)&Al[(32 * wv + 16 + lr) * 40 + lg * 8];
#pragma unroll
    for (int c = 0; c < 4; ++c) {
      half8 b_ = *(const half8*)&Bt[(16 * c + lr) * 40 + lg * 8];
      acc[0][c] = __builtin_amdgcn_mfma_f32_16x16x32_f16(a0, b_, acc[0][c], 0, 0, 0);
      acc[1][c] = __builtin_amdgcn_mfma_f32_16x16x32_f16(a1, b_, acc[1][c], 0, 0, 0);
    }
  }
  long btM = (long)bt * MM;
#pragma unroll
  for (int rt = 0; rt < 2; ++rt)
#pragma unroll
    for (int c = 0; c < 4; ++c)
#pragma unroll
      for (int e = 0; e < 4; ++e) {
        int n = rt_blk * 128 + 32 * wv + 16 * rt + lg * 4 + e;
        int col = 16 * c + lr;
        if (n < NN) {
          float val = acc[rt][c][e];
          if (w == 0) {
            val += pt21[n] * stX[(btM + NN + n) * 64 + col];
          } else if (w == 1) {
            val += pt12[n] * stX[(btM + n) * 64 + col]
                 + pt32[n] * stX[(btM + 2 * NN + n) * 64 + col];
          } else {
            val += pt23[n] * stX[(btM + NN + n) * 64 + col];
          }
          long o = (btM + (long)w * NN + n) * 64 + col;
          xs1f[o] = val;
          xs1b[o] = f2h(val);
        }
      }
}

// ------- t2 via MFMA: 2*(L*xs1)[mid] - stX[mid] -> fp16 ------------------
__global__ __launch_bounds__(256) void k_t2_mfma(const unsigned short* __restrict__ gsoB,
                                                 const unsigned short* __restrict__ xs1b,
                                                 const float* __restrict__ xs1f,
                                                 const float* __restrict__ stX,
                                                 const float* __restrict__ pt12,
                                                 const float* __restrict__ pt32,
                                                 unsigned short* __restrict__ t2b) {
  __shared__ alignas(16) unsigned short Al[128 * 40];
  __shared__ alignas(16) unsigned short Bt[64 * 40];
  int bt = blockIdx.x;
  int b = bt / TT;
  int rt_blk = blockIdx.y;
  const unsigned short* A = gsoB + (long)b * NN * GSTR;
  long vbase = (long)bt * MM + NN;
  int tid = threadIdx.x;
  int lane = tid & 63;
  int wv = __builtin_amdgcn_readfirstlane(tid >> 6);
  int lr = lane & 15, lg = lane >> 4;
  f32x4 zero4 = {0.f, 0.f, 0.f, 0.f};
  f32x4 acc[2][4];
#pragma unroll
  for (int rt = 0; rt < 2; ++rt)
#pragma unroll
    for (int c = 0; c < 4; ++c) acc[rt][c] = zero4;
  for (int kb_ = 0; kb_ < 352; kb_ += 32) {
    __syncthreads();
    for (int u = 0; u < 2; ++u) {
      int idx = tid + 256 * u;
      int row = idx >> 2, c8 = idx & 3;
      int rr = rt_blk * 128 + row; if (rr > NN - 1) rr = NN - 1;
      *(uint4*)&Al[row * 40 + c8 * 8] = *(const uint4*)&A[(long)rr * GSTR + kb_ + c8 * 8];
    }
    for (int u = 0; u < 2; ++u) {
      int idx = tid + 256 * u;
      int k = idx >> 4, c4 = idx & 15;
      int kg = kb_ + k;
      ushort4 vv;
      if (kg < NN) vv = *(const ushort4*)&xs1b[(vbase + kg) * 64 + c4 * 4];
      else { vv.x = 0; vv.y = 0; vv.z = 0; vv.w = 0; }
      Bt[(4 * c4 + 0) * 40 + k] = vv.x;
      Bt[(4 * c4 + 1) * 40 + k] = vv.y;
      Bt[(4 * c4 + 2) * 40 + k] = vv.z;
      Bt[(4 * c4 + 3) * 40 + k] = vv.w;
    }
    __syncthreads();
    half8 a0 = *(const half8*)&Al[(32 * wv + lr) * 40 + lg * 8];
    half8 a1 = *(const half8*)&Al[(32 * wv + 16 + lr) * 40 + lg * 8];
#pragma unroll
    for (int c = 0; c < 4; ++c) {
      half8 b_ = *(const half8*)&Bt[(16 * c + lr) * 40 + lg * 8];
      acc[0][c] = __builtin_amdgcn_mfma_f32_16x16x32_f16(a0, b_, acc[0][c], 0, 0, 0);
      acc[1][c] = __builtin_amdgcn_mfma_f32_16x16x32_f16(a1, b_, acc[1][c], 0, 0, 0);
    }
  }
  long btM = (long)bt * MM;
#pragma unroll
  for (int rt = 0; rt < 2; ++rt)
#pragma unroll
    for (int c = 0; c < 4; ++c)
#pragma unroll
      for (int e = 0; e < 4; ++e) {
        int n = rt_blk * 128 + 32 * wv + 16 * rt + lg * 4 + e;
        int col = 16 * c + lr;
        if (n < NN) {
          float val = 2.f * (pt12[n] * xs1f[(btM + n) * 64 + col]
                             + acc[rt][c][e]
                             + pt32[n] * xs1f[(btM + 2 * NN + n) * 64 + col])
                      - stX[(btM + NN + n) * 64 + col];
          t2b[((long)bt * NN + n) * 64 + col] = f2h(val);
        }
      }
}

// ------- cheb via MFMA: [31200x192]x[192x64] + LayerNorm epilogue --------
__global__ __launch_bounds__(256) void k_cheb_mfma(const unsigned short* __restrict__ stXb,
                                                   const unsigned short* __restrict__ xs1b,
                                                   const unsigned short* __restrict__ t2b,
                                                   const float* __restrict__ cw,
                                                   const float* __restrict__ lng,
                                                   const float* __restrict__ lnb,
                                                   float* __restrict__ gcn) {
  __shared__ alignas(16) unsigned short Bt[64 * 200];  // [j][K], K=192
  __shared__ alignas(16) unsigned short Al[128 * 40];
  int tid = threadIdx.x;
  for (int u = 0; u < 48; ++u) {
    int f = tid + 256 * u;                   // f = K*64 + j
    int K = f >> 6, j = f & 63;
    Bt[j * 200 + K] = f2h(cw[f]);
  }
  int lane = tid & 63;
  int wv = __builtin_amdgcn_readfirstlane(tid >> 6);
  int lr = lane & 15, lg = lane >> 4;
  long grow0 = (long)blockIdx.x * 128;
  f32x4 zero4 = {0.f, 0.f, 0.f, 0.f};
  f32x4 acc[2][4];
#pragma unroll
  for (int rt = 0; rt < 2; ++rt)
#pragma unroll
    for (int c = 0; c < 4; ++c) acc[rt][c] = zero4;
  for (int ch = 0; ch < 6; ++ch) {
    const unsigned short* src = ch < 2 ? stXb : (ch < 4 ? xs1b : t2b);
    int koff = (ch & 1) * 32;
    __syncthreads();
    for (int u = 0; u < 2; ++u) {
      int idx = tid + 256 * u;
      int row = idx >> 2, c8 = idx & 3;
      long gr = grow0 + row; if (gr > 31199) gr = 31199;
      int bt = (int)(gr / NN), n = (int)(gr - (long)bt * NN);
      long sbase = (ch < 4) ? ((long)bt * MM + NN + n) * 64 : gr * 64;
      *(uint4*)&Al[row * 40 + c8 * 8] = *(const uint4*)&src[sbase + koff + c8 * 8];
    }
    __syncthreads();
    half8 a0 = *(const half8*)&Al[(32 * wv + lr) * 40 + lg * 8];
    half8 a1 = *(const half8*)&Al[(32 * wv + 16 + lr) * 40 + lg * 8];
#pragma unroll
    for (int c = 0; c < 4; ++c) {
      half8 b = *(const half8*)&Bt[(16 * c + lr) * 200 + ch * 32 + lg * 8];
      acc[0][c] = __builtin_amdgcn_mfma_f32_16x16x32_f16(a0, b, acc[0][c], 0, 0, 0);
      acc[1][c] = __builtin_amdgcn_mfma_f32_16x16x32_f16(a1, b, acc[1][c], 0, 0, 0);
    }
  }
  float lngv[4], lnbv[4];
#pragma unroll
  for (int c = 0; c < 4; ++c) { lngv[c] = lng[16 * c + lr]; lnbv[c] = lnb[16 * c + lr]; }
#pragma unroll
  for (int rt = 0; rt < 2; ++rt)
#pragma unroll
    for (int e = 0; e < 4; ++e) {
      float s = acc[rt][0][e] + acc[rt][1][e] + acc[rt][2][e] + acc[rt][3][e];
      for (int m = 1; m < 16; m <<= 1) s += __shfl_xor(s, m);
      float mu = s * (1.f / 64.f);
      float q = 0.f;
#pragma unroll
      for (int c = 0; c < 4; ++c) { float d = acc[rt][c][e] - mu; q += d * d; }
      for (int m = 1; m < 16; m <<= 1) q += __shfl_xor(q, m);
      float rstd = rsqrtf(q * (1.f / 64.f) + LN_EPS_);
      long gr = grow0 + 32 * wv + 16 * rt + lg * 4 + e;
      if (gr < 31200) {
#pragma unroll
        for (int c = 0; c < 4; ++c)
          gcn[gr * 64 + 16 * c + lr] = (acc[rt][c][e] - mu) * rstd * lngv[c] + lnbv[c];
      }
    }
}

// -------- mean over (t,n) per (b,d), inline scramble-gather --------------
__global__ __launch_bounds__(256) void k_mean(const float* __restrict__ sem,
                                              const float* __restrict__ gcn,
                                              float* __restrict__ mbd) {
  __shared__ float red[4][64];
  int bt = blockIdx.x;
  int b = bt / TT;
  int d = threadIdx.x & 63, g = threadIdx.x >> 6;
  float s = 0.f;
  for (int n = g; n < NN; n += 4) {
    int f = (NN + n) * 64 + d;
    int mm = f % MM, ii = f / MM;
    float a = sem[((long)bt * MM + mm) * 64 + ii];
    float r = gcn[((long)bt * NN + n) * 64 + d];
    s += a + r;
  }
  red[g][d] = s;
  __syncthreads();
  if (threadIdx.x < 64) {
    float v = red[0][d] + red[1][d] + red[2][d] + red[3][d];
    atomicAdd(&mbd[b * 64 + d], v);
  }
}

// -------- global AFF branch ----------------------------------------------
__global__ __launch_bounds__(64) void k_glob(const float* __restrict__ mbd,
                                             const float* __restrict__ w1,
                                             const float* __restrict__ b1,
                                             const float* __restrict__ g1,
                                             const float* __restrict__ be1,
                                             const float* __restrict__ w2,
                                             const float* __restrict__ b2,
                                             const float* __restrict__ g2,
                                             const float* __restrict__ be2,
                                             float* __restrict__ xg) {
  __shared__ float ml[64];
  __shared__ float zg[16];
  int b = blockIdx.x, d = threadIdx.x;
  ml[d] = mbd[b * 64 + d] * (1.f / 3900.f);
  __syncthreads();
  float rb = rsqrtf(1.f + BN_EPS_);
  if (d < 16) {
    float a = b1[d];
    for (int i = 0; i < 64; ++i) a += w1[d * 64 + i] * ml[i];
    a = a * (g1[d] * rb) + be1[d];
    zg[d] = a > 0.f ? a : 0.f;
  }
  __syncthreads();
  float a = b2[d];
  for (int i = 0; i < 16; ++i) a += w2[d * 16 + i] * zg[i];
  xg[b * 64 + d] = a * (g2[d] * rb) + be2[d];
}

// -------- final: local AFF branch + sigmoid fuse (inline gather) ---------
__global__ __launch_bounds__(256) void k_final(const float* __restrict__ sem,
                                               const float* __restrict__ gcn,
                                               const float* __restrict__ xg,
                                               const float* __restrict__ w1,
                                               const float* __restrict__ b1,
                                               const float* __restrict__ g1,
                                               const float* __restrict__ be1,
                                               const float* __restrict__ w2,
                                               const float* __restrict__ b2,
                                               const float* __restrict__ g2,
                                               const float* __restrict__ be2,
                                               float* __restrict__ out) {
  __shared__ float w1l[16][65];
  __shared__ float w2l[64][17];
  __shared__ float xal[4][64];
  __shared__ float zll[4][16];
  int tid = threadIdx.x;
  for (int u = 0; u < 4; ++u) {
    int f = tid + 256 * u;
    w1l[f >> 6][f & 63] = w1[f];
    w2l[f >> 4][f & 15] = w2[f];
  }
  int lane = tid & 63, wv = tid >> 6;
  long row = (long)blockIdx.x * 4 + wv;        // 31,200 rows exact
  int bt = (int)(row / NN);
  int n = (int)(row - (long)bt * NN);
  int b = bt / TT;
  int f = (NN + n) * 64 + lane;
  int mm = f % MM, ii = f / MM;
  float a = sem[((long)bt * MM + mm) * 64 + ii];
  float r = gcn[row * DD + lane];
  float xa = a + r;
  xal[wv][lane] = xa;
  __syncthreads();
  float rb = rsqrtf(1.f + BN_EPS_);
  if (lane < 16) {
    float acc = b1[lane];
#pragma unroll 8
    for (int i = 0; i < 64; ++i) acc += w1l[lane][i] * xal[wv][i];
    acc = acc * (g1[lane] * rb) + be1[lane];
    zll[wv][lane] = acc > 0.f ? acc : 0.f;
  }
  __syncthreads();
  float acc = b2[lane];
#pragma unroll
  for (int i = 0; i < 16; ++i) acc += w2l[lane][i] * zll[wv][i];
  float xl = acc * (g2[lane] * rb) + be2[lane];
  float wei = 1.f / (1.f + __expf(-(xl + xg[b * 64 + lane])));
  out[row * DD + lane] = 2.f * a * wei + 2.f * r * (1.f - wei);
}

extern "C" void kernel_launch(void* const* d_in, const int* in_sizes, int n_in,
                              void* d_out, int out_size, void* d_ws, size_t ws_size,
                              hipStream_t stream) {
  const float* x    = (const float*)d_in[0];
  const float* gso  = (const float*)d_in[1];
  const unsigned char* mask_raw = (const unsigned char*)d_in[2];
  const float* Wq   = (const float*)d_in[3];
  const float* Wk   = (const float*)d_in[4];
  const float* Wv   = (const float*)d_in[5];
  const float* chw  = (const float*)d_in[6];
  const float* pt12 = (const float*)d_in[7];
  const float* pt21 = (const float*)d_in[8];
  const float* pt23 = (const float*)d_in[9];
  const float* pt32 = (const float*)d_in[10];
  const float* lng  = (const float*)d_in[11];
  const float* lnb  = (const float*)d_in[12];
  const float* l_w1 = (const float*)d_in[13];
  const float* l_b1 = (const float*)d_in[14];
  const float* l_g1 = (const float*)d_in[15];
  const float* l_be1= (const float*)d_in[16];
  const float* l_w2 = (const float*)d_in[17];
  const float* l_b2 = (const float*)d_in[18];
  const float* l_g2 = (const float*)d_in[19];
  const float* l_be2= (const float*)d_in[20];
  const float* g_w1 = (const float*)d_in[21];
  const float* g_b1 = (const float*)d_in[22];
  const float* g_g1 = (const float*)d_in[23];
  const float* g_be1= (const float*)d_in[24];
  const float* g_w2 = (const float*)d_in[25];
  const float* g_b2 = (const float*)d_in[26];
  const float* g_g2 = (const float*)d_in[27];
  const float* g_be2= (const float*)d_in[28];

  float* base = (float*)d_ws;
  unsigned char* maskp = (unsigned char*)d_ws;                // padded mask
  unsigned short* gsoB = (unsigned short*)(base + WS_GSOB);
  float* stX           = base + WS_STX;
  unsigned short* stXb = (unsigned short*)(base + WS_STXB);
  unsigned short* qb   = (unsigned short*)(base + WS_QB);
  unsigned short* kb   = (unsigned short*)(base + WS_KB);
  unsigned short* vb   = (unsigned short*)(base + WS_VB);
  float* sem           = base + WS_SEM;
  unsigned short* t2b  = (unsigned short*)(base + WS_T2B);
  float* Gf            = base + WS_G;

  // aliases (lifetimes disjoint):
  float* xs1f = (float*)qb;                    // spans qb+kb = SZ floats
  unsigned short* xs1b = vb;                   // SZ shorts (over vb)
  float* gcn = stX;                            // stX f32 dead after k_t2
  float* mbd = Gf;                             // chunk region dead after attn
  float* xg  = Gf + 512;

  // attention chunk sizing (Pb + pda + pdb only; S eliminated)
  long avail_f = (long)(ws_size / sizeof(float)) - WS_G;
  const int cands[9] = {24, 16, 12, 8, 6, 4, 3, 2, 1};
  int cbt = 1;
  for (int i = 0; i < 9; ++i) {
    if ((long)cands[i] * PERBT <= avail_f) { cbt = cands[i]; break; }
  }
  unsigned short* Pb = (unsigned short*)Gf;                // cbt*MM*PSTR shorts
  float* pda = (float*)(Pb + (long)cbt * MM * PSTR);       // cbt*MM f
  float* pdb = pda + (long)cbt * MM;

  k_maskprep<<<(NN * MSTR + 255) / 256, 256, 0, stream>>>(mask_raw, maskp);
  k_gsoprep<<<3575, 256, 0, stream>>>(gso, gsoB);
  k_stx<<<23400, 256, 0, stream>>>(x, stX, stXb);
  {
    dim3 g(732, 3);
    k_qkv_mfma<<<g, 256, 0, stream>>>(stXb, Wq, Wk, Wv, qb, kb, vb);
  }
  for (int bb = 0; bb < 96; bb += cbt) {
    dim3 gs(cbt * 3, 6);
    k_ssm<<<gs, 256, 0, stream>>>(qb, kb, maskp, Pb, pda, pdb, bb);
    dim3 gp(cbt * 3, 3);
    k_pv_mfma<<<gp, 256, 0, stream>>>(Pb, pda, pdb, vb, sem, bb);
  }
  {
    dim3 g(288, 3);
    k_xs1_mfma<<<g, 256, 0, stream>>>(gsoB, stXb, stX, pt12, pt21, pt23, pt32, xs1f, xs1b);
  }
  {
    dim3 g(96, 3);
    k_t2_mfma<<<g, 256, 0, stream>>>(gsoB, xs1b, xs1f, stX, pt12, pt32, t2b);
  }
  k_cheb_mfma<<<244, 256, 0, stream>>>(stXb, xs1b, t2b, chw, lng, lnb, gcn);
  hipMemsetAsync(mbd, 0, 1024 * sizeof(float), stream);
  k_mean<<<96, 256, 0, stream>>>(sem, gcn, mbd);
  k_glob<<<8, 64, 0, stream>>>(mbd, g_w1, g_b1, g_g1, g_be1, g_w2, g_b2, g_g2, g_be2, xg);
  k_final<<<7800, 256, 0, stream>>>(sem, gcn, xg,
                                    l_w1, l_b1, l_g1, l_be1,
                                    l_w2, l_b2, l_g2, l_be2,
                                    (float*)d_out);
}

// Round 7
// 413.131 us; speedup vs baseline: 4.3401x; 1.1342x over previous
//
#include <hip/hip_runtime.h>
#include <math.h>

constexpr int TT = 12;
constexpr int NN = 325;
constexpr int MM = 975;   // 3*NN
constexpr int DD = 64;
constexpr long SZ = 96L * MM * DD;       // 5,990,400 elements per big tensor
constexpr int GSTR = 352;                // gso row stride (fp16 shorts), zero-padded
constexpr int MBSTR = 48;                // mask bitrow stride (bytes), 384 bits
constexpr float BN_EPS_ = 1e-5f;
constexpr float LN_EPS_ = 1e-5f;

// ---- workspace float offsets (running map) -------------------------------
constexpr long WS_MASKB = 0;                          // 15,600 B -> 4,096 f
constexpr long WS_GSOB  = WS_MASKB + 4096;            // 915,200 shorts = 457,600 f
constexpr long WS_STXB  = WS_GSOB + 457600;           // SZ shorts = SZ/2 f
constexpr long WS_QB    = WS_STXB + SZ / 2;
constexpr long WS_KB    = WS_QB + SZ / 2;
constexpr long WS_VB    = WS_KB + SZ / 2;
constexpr long WS_SEM   = WS_VB + SZ / 2;             // SZ f (f32)
constexpr long WS_T2B   = WS_SEM + SZ;                // 998,400 f
constexpr long WS_MBD   = WS_T2B + 998400;            // mbd 512 + xg 512

typedef _Float16 half8 __attribute__((ext_vector_type(8)));
typedef __attribute__((ext_vector_type(4))) float f32x4;

static __device__ inline unsigned short f2h(float f) {
  _Float16 h = (_Float16)f;
  return __builtin_bit_cast(unsigned short, h);
}
static __device__ inline float h2f(unsigned short s) {
  return (float)__builtin_bit_cast(_Float16, s);
}

// ------------- mask sniff + pack to bitmask [NN][MBSTR] -------------------
__global__ __launch_bounds__(256) void k_maskprep(const unsigned char* __restrict__ raw,
                                                  unsigned char* __restrict__ outm) {
  bool is_u8 = false;
  for (int i = 0; i < 256; ++i) {
    if (raw[4 * i + 1]) { is_u8 = true; break; }
  }
  int idx = blockIdx.x * 256 + threadIdx.x;     // NN*MBSTR = 15,600 bytes
  if (idx >= NN * MBSTR) return;
  int n = idx / MBSTR, jb = idx - n * MBSTR;
  unsigned char v = 0;
  for (int k = 0; k < 8; ++k) {
    int col = jb * 8 + k;
    bool m = true;                               // pad cols -> masked
    if (col < NN) {
      int f = n * NN + col;
      m = is_u8 ? (raw[f] != 0) : (((const int*)raw)[f] != 0);
    }
    v |= (unsigned char)(m ? 1 : 0) << k;
  }
  outm[idx] = v;
}

// ------------- gso -> fp16, padded rows [8][325][GSTR] --------------------
__global__ __launch_bounds__(256) void k_gsoprep(const float* __restrict__ gso,
                                                 unsigned short* __restrict__ gsoB) {
  int idx = blockIdx.x * 256 + threadIdx.x;   // 3575 blocks exact
  int b = idx / (NN * GSTR);
  int rem = idx - b * (NN * GSTR);
  int r = rem / GSTR, j = rem - r * GSTR;
  gsoB[idx] = (j < NN) ? f2h(gso[(long)b * NN * NN + r * NN + j]) : (unsigned short)0;
}

// ---------------- stX gather: [B,T,N,D] -> [BT, 3N, D] fp16 ---------------
__global__ __launch_bounds__(256) void k_stx(const float* __restrict__ x,
                                             unsigned short* __restrict__ stXb) {
  int idx = blockIdx.x * 256 + threadIdx.x;     // exact: 23,400 blocks
  int d = idx & 63;
  int m = (idx >> 6) % MM;
  int bt = idx / (MM * DD);
  int b = bt / TT, t = bt - b * TT;
  int w = m / NN, n = m - w * NN;
  int st = t + w - 1;
  st = st < 0 ? 0 : (st > TT - 1 ? TT - 1 : st);
  stXb[idx] = f2h(x[(((b * TT + st) * NN + n) << 6) + d]);
}

// ---------------- QKV via MFMA: [93600x64] x [64x64] -> fp16 -------------
__global__ __launch_bounds__(256) void k_qkv_mfma(const unsigned short* __restrict__ stXb,
                                                  const float* __restrict__ Wq,
                                                  const float* __restrict__ Wk,
                                                  const float* __restrict__ Wv,
                                                  unsigned short* __restrict__ qb,
                                                  unsigned short* __restrict__ kb,
                                                  unsigned short* __restrict__ vb) {
  __shared__ alignas(16) unsigned short sX[128 * 72];
  __shared__ alignas(16) unsigned short sW[64 * 72];
  const float* W = blockIdx.y == 0 ? Wq : (blockIdx.y == 1 ? Wk : Wv);
  unsigned short* outb = blockIdx.y == 0 ? qb : (blockIdx.y == 1 ? kb : vb);
  int tid = threadIdx.x;
  long r0 = (long)blockIdx.x * 128;
  for (int u = 0; u < 4; ++u) {
    int idx = tid + 256 * u;
    int row = idx >> 3, c8 = idx & 7;
    long rg = r0 + row; if (rg > 93599) rg = 93599;
    *(uint4*)&sX[row * 72 + c8 * 8] = *(const uint4*)&stXb[rg * 64 + c8 * 8];
  }
  for (int u = 0; u < 16; ++u) {
    int f = tid + 256 * u;
    int o = f >> 6, d = f & 63;
    sW[o * 72 + d] = f2h(W[f]);
  }
  __syncthreads();
  int lane = tid & 63;
  int wv = __builtin_amdgcn_readfirstlane(tid >> 6);
  int lr = lane & 15, lg = lane >> 4;
  f32x4 zero4 = {0.f, 0.f, 0.f, 0.f};
  f32x4 acc[2][4];
#pragma unroll
  for (int rt = 0; rt < 2; ++rt)
#pragma unroll
    for (int c = 0; c < 4; ++c) acc[rt][c] = zero4;
#pragma unroll
  for (int kk = 0; kk < 2; ++kk) {
    half8 a0 = *(const half8*)&sX[(32 * wv + lr) * 72 + kk * 32 + lg * 8];
    half8 a1 = *(const half8*)&sX[(32 * wv + 16 + lr) * 72 + kk * 32 + lg * 8];
#pragma unroll
    for (int c = 0; c < 4; ++c) {
      half8 b = *(const half8*)&sW[(16 * c + lr) * 72 + kk * 32 + lg * 8];
      acc[0][c] = __builtin_amdgcn_mfma_f32_16x16x32_f16(a0, b, acc[0][c], 0, 0, 0);
      acc[1][c] = __builtin_amdgcn_mfma_f32_16x16x32_f16(a1, b, acc[1][c], 0, 0, 0);
    }
  }
  __syncthreads();
#pragma unroll
  for (int rt = 0; rt < 2; ++rt)
#pragma unroll
    for (int c = 0; c < 4; ++c)
#pragma unroll
      for (int e = 0; e < 4; ++e) {
        int row = 32 * wv + 16 * rt + lg * 4 + e;
        int col = 16 * c + lr;
        sX[row * 64 + col] = f2h(acc[rt][c][e]);
      }
  __syncthreads();
  for (int u = 0; u < 4; ++u) {
    int idx = tid + 256 * u;
    int row = idx >> 3, c8 = idx & 7;
    long rg = r0 + row;
    if (rg < 93600)
      *(uint4*)&outb[rg * 64 + c8 * 8] = *(const uint4*)&sX[row * 64 + c8 * 8];
  }
}

// ------- fully fused attention: QK^T + mask/softmax + PV -> sem ----------
// block: (bt,w) x 64-row tile. P never leaves the block.
__global__ __launch_bounds__(256) void k_attn(const unsigned short* __restrict__ qb,
                                              const unsigned short* __restrict__ kb,
                                              const unsigned short* __restrict__ vb,
                                              const unsigned char* __restrict__ maskb,
                                              float* __restrict__ sem) {
  __shared__ alignas(16) unsigned short Kl[336 * 72];   // K; reused for V (Bt [64][352])
  __shared__ alignas(16) unsigned short Ql[64 * 72];    // Q; reused for per-wave P scratch
  __shared__ unsigned char Mb[64 * MBSTR];              // bit-packed mask rows
  int btw = blockIdx.x;
  int bt = btw / 3, w = btw - bt * 3;
  int rt = blockIdx.y;                         // 0..5
  long base = ((long)bt * MM + (long)w * NN) * 64;
  int tid = threadIdx.x;
  // K: 336 clamped rows
  for (int u = 0; u < 11; ++u) {
    int idx = tid + 256 * u;
    if (idx < 2688) {
      int r = idx >> 3, c8 = idx & 7;
      int rr = r < NN ? r : NN - 1;
      *(uint4*)&Kl[r * 72 + c8 * 8] = *(const uint4*)&kb[base + (long)rr * 64 + c8 * 8];
    }
  }
  // Q: 64 rows
  for (int u = 0; u < 2; ++u) {
    int idx = tid + 256 * u;
    int r = idx >> 3, c8 = idx & 7;
    int rg = rt * 64 + r; if (rg > NN - 1) rg = NN - 1;
    *(uint4*)&Ql[r * 72 + c8 * 8] = *(const uint4*)&qb[base + (long)rg * 64 + c8 * 8];
  }
  // mask bits: 64 rows x 48 B
  if (tid < 192) {
    int r = tid / 3, c16 = tid - (tid / 3) * 3;
    int rg = rt * 64 + r; if (rg > NN - 1) rg = NN - 1;
    *(uint4*)&Mb[r * MBSTR + c16 * 16] = *(const uint4*)&maskb[(long)rg * MBSTR + c16 * 16];
  }
  __syncthreads();
  int lane = tid & 63;
  int wv = __builtin_amdgcn_readfirstlane(tid >> 6);
  int lr = lane & 15, lg = lane >> 4;
  f32x4 zero4 = {0.f, 0.f, 0.f, 0.f};
  f32x4 acc[22];
#pragma unroll
  for (int ct = 0; ct < 22; ++ct) acc[ct] = zero4;
  f32x4 dA = zero4, dB = zero4;
  int nl_f = rt * 64 + 16 * wv + lr; if (nl_f > NN - 1) nl_f = NN - 1;
  long pAaddr = ((long)bt * MM + ((w == 1) ? nl_f : NN + nl_f)) * 64;
  long pBaddr = ((long)bt * MM + 2 * NN + nl_f) * 64;
#pragma unroll
  for (int kk = 0; kk < 2; ++kk) {
    half8 a = *(const half8*)&Ql[(16 * wv + lr) * 72 + kk * 32 + lg * 8];
#pragma unroll
    for (int ct = 0; ct < 21; ++ct) {
      half8 b = *(const half8*)&Kl[(16 * ct + lr) * 72 + kk * 32 + lg * 8];
      acc[ct] = __builtin_amdgcn_mfma_f32_16x16x32_f16(a, b, acc[ct], 0, 0, 0);
    }
    half8 bA = *(const half8*)&kb[pAaddr + kk * 32 + lg * 8];
    dA = __builtin_amdgcn_mfma_f32_16x16x32_f16(a, bA, dA, 0, 0, 0);
    if (w == 1) {
      half8 bB = *(const half8*)&kb[pBaddr + kk * 32 + lg * 8];
      dB = __builtin_amdgcn_mfma_f32_16x16x32_f16(a, bB, dB, 0, 0, 0);
    }
  }
  // diag extraction: element (r,r) at lane 20*lg+e for r = lg*4+e
  float da_[4], db_[4];
#pragma unroll
  for (int e = 0; e < 4; ++e) {
    int src = lg * 20 + e;
    da_[e] = __shfl(dA[e], src);
    db_[e] = (w == 1) ? __shfl(dB[e], src) : -INFINITY;
  }
  // mask + row max (mask from LDS bitrows; row rl = 16wv + lg*4+e)
  float mx[4] = {-INFINITY, -INFINITY, -INFINITY, -INFINITY};
#pragma unroll
  for (int ct = 0; ct < 22; ++ct) {
    int col = 16 * ct + lr;
#pragma unroll
    for (int e = 0; e < 4; ++e) {
      int rl = 16 * wv + lg * 4 + e;
      bool masked = (col >= NN) ||
                    ((Mb[rl * MBSTR + (col >> 3)] >> (col & 7)) & 1);
      float s = masked ? -INFINITY : acc[ct][e];
      acc[ct][e] = s;
      mx[e] = fmaxf(mx[e], s);
    }
  }
#pragma unroll
  for (int e = 0; e < 4; ++e)
    for (int m = 1; m < 16; m <<= 1) mx[e] = fmaxf(mx[e], __shfl_xor(mx[e], m));
  float gm[4], ea[4], eb[4], sum[4], inv[4];
#pragma unroll
  for (int e = 0; e < 4; ++e) {
    gm[e] = fmaxf(mx[e], da_[e]);
    if (w == 1) gm[e] = fmaxf(gm[e], db_[e]);
    sum[e] = 0.f;
  }
#pragma unroll
  for (int ct = 0; ct < 22; ++ct)
#pragma unroll
    for (int e = 0; e < 4; ++e) {
      float s = acc[ct][e];
      float p = (s > -1e37f) ? __expf(s - gm[e]) : 0.f;
      acc[ct][e] = p;
      sum[e] += p;
    }
#pragma unroll
  for (int e = 0; e < 4; ++e) {
    for (int m = 1; m < 16; m <<= 1) sum[e] += __shfl_xor(sum[e], m);
    ea[e] = __expf(da_[e] - gm[e]);
    eb[e] = (w == 1) ? __expf(db_[e] - gm[e]) : 0.f;
    sum[e] += ea[e] + eb[e];
    inv[e] = 1.f / sum[e];
  }
  // stage V into Kl region, Bt layout [col][352]
  __syncthreads();
  unsigned short* Bt = Kl;
  for (int u = 0; u < 22; ++u) {
    int idx = tid + 256 * u;
    if (idx < 5632) {
      int k = idx >> 4, c4 = idx & 15;
      ushort4 vvv;
      if (k < NN) vvv = *(const ushort4*)&vb[base + (long)k * 64 + c4 * 4];
      else { vvv.x = 0; vvv.y = 0; vvv.z = 0; vvv.w = 0; }
      Bt[(4 * c4 + 0) * 352 + k] = vvv.x;
      Bt[(4 * c4 + 1) * 352 + k] = vvv.y;
      Bt[(4 * c4 + 2) * 352 + k] = vvv.z;
      Bt[(4 * c4 + 3) * 352 + k] = vvv.w;
    }
  }
  __syncthreads();
  // PV: per-wave P transpose through private LDS scratch (in Ql region)
  unsigned short* Ptr = (unsigned short*)Ql + wv * 640;   // [16][40]
  f32x4 oacc[4];
#pragma unroll
  for (int c = 0; c < 4; ++c) oacc[c] = zero4;
  for (int ck = 0; ck < 11; ++ck) {
#pragma unroll
    for (int t = 0; t < 2; ++t) {
      int ct = 2 * ck + t;
#pragma unroll
      for (int e = 0; e < 4; ++e)
        Ptr[(lg * 4 + e) * 40 + t * 16 + lr] = f2h(acc[ct][e] * inv[e]);
    }
    half8 a = *(const half8*)&Ptr[lr * 40 + lg * 8];
#pragma unroll
    for (int c = 0; c < 4; ++c) {
      half8 b = *(const half8*)&Bt[(16 * c + lr) * 352 + ck * 32 + lg * 8];
      oacc[c] = __builtin_amdgcn_mfma_f32_16x16x32_f16(a, b, oacc[c], 0, 0, 0);
    }
  }
  // epilogue: diag-partner contributions + write sem
#pragma unroll
  for (int c = 0; c < 4; ++c)
#pragma unroll
    for (int e = 0; e < 4; ++e) {
      int n = rt * 64 + 16 * wv + lg * 4 + e;
      int col = 16 * c + lr;
      if (n < NN) {
        float val = oacc[c][e];
        int partA = (w == 1) ? n : NN + n;
        val += ea[e] * inv[e] * h2f(vb[((long)bt * MM + partA) * 64 + col]);
        if (w == 1)
          val += eb[e] * inv[e] * h2f(vb[((long)bt * MM + 2 * NN + n) * 64 + col]);
        sem[((long)bt * MM + (long)w * NN + n) * 64 + col] = val;
      }
    }
}

// ---------------- xs1 via MFMA: gso x stX(block) + diag epilogue ---------
__global__ __launch_bounds__(256) void k_xs1_mfma(const unsigned short* __restrict__ gsoB,
                                                  const unsigned short* __restrict__ stXb,
                                                  const float* __restrict__ pt12,
                                                  const float* __restrict__ pt21,
                                                  const float* __restrict__ pt23,
                                                  const float* __restrict__ pt32,
                                                  unsigned short* __restrict__ xs1b) {
  __shared__ alignas(16) unsigned short Al[128 * 40];
  __shared__ alignas(16) unsigned short Bt[64 * 40];
  int btw = blockIdx.x;
  int bt = btw / 3, w = btw - bt * 3;
  int b = bt / TT;
  int rt_blk = blockIdx.y;
  const unsigned short* A = gsoB + (long)b * NN * GSTR;
  long vbase = (long)bt * MM + (long)w * NN;
  int tid = threadIdx.x;
  int lane = tid & 63;
  int wv = __builtin_amdgcn_readfirstlane(tid >> 6);
  int lr = lane & 15, lg = lane >> 4;
  f32x4 zero4 = {0.f, 0.f, 0.f, 0.f};
  f32x4 acc[2][4];
#pragma unroll
  for (int rt = 0; rt < 2; ++rt)
#pragma unroll
    for (int c = 0; c < 4; ++c) acc[rt][c] = zero4;
  for (int kb_ = 0; kb_ < 352; kb_ += 32) {
    __syncthreads();
    for (int u = 0; u < 2; ++u) {
      int idx = tid + 256 * u;
      int row = idx >> 2, c8 = idx & 3;
      int rr = rt_blk * 128 + row; if (rr > NN - 1) rr = NN - 1;
      *(uint4*)&Al[row * 40 + c8 * 8] = *(const uint4*)&A[(long)rr * GSTR + kb_ + c8 * 8];
    }
    for (int u = 0; u < 2; ++u) {
      int idx = tid + 256 * u;
      int k = idx >> 4, c4 = idx & 15;
      int kg = kb_ + k;
      ushort4 vv;
      if (kg < NN) vv = *(const ushort4*)&stXb[(vbase + kg) * 64 + c4 * 4];
      else { vv.x = 0; vv.y = 0; vv.z = 0; vv.w = 0; }
      Bt[(4 * c4 + 0) * 40 + k] = vv.x;
      Bt[(4 * c4 + 1) * 40 + k] = vv.y;
      Bt[(4 * c4 + 2) * 40 + k] = vv.z;
      Bt[(4 * c4 + 3) * 40 + k] = vv.w;
    }
    __syncthreads();
    half8 a0 = *(const half8*)&Al[(32 * wv + lr) * 40 + lg * 8];
    half8 a1 = *(const half8*)&Al[(32 * wv + 16 + lr) * 40 + lg * 8];
#pragma unroll
    for (int c = 0; c < 4; ++c) {
      half8 b_ = *(const half8*)&Bt[(16 * c + lr) * 40 + lg * 8];
      acc[0][c] = __builtin_amdgcn_mfma_f32_16x16x32_f16(a0, b_, acc[0][c], 0, 0, 0);
      acc[1][c] = __builtin_amdgcn_mfma_f32_16x16x32_f16(a1, b_, acc[1][c], 0, 0, 0);
    }
  }
  long btM = (long)bt * MM;
#pragma unroll
  for (int rt = 0; rt < 2; ++rt)
#pragma unroll
    for (int c = 0; c < 4; ++c)
#pragma unroll
      for (int e = 0; e < 4; ++e) {
        int n = rt_blk * 128 + 32 * wv + 16 * rt + lg * 4 + e;
        int col = 16 * c + lr;
        if (n < NN) {
          float val = acc[rt][c][e];
          if (w == 0) {
            val += pt21[n] * h2f(stXb[(btM + NN + n) * 64 + col]);
          } else if (w == 1) {
            val += pt12[n] * h2f(stXb[(btM + n) * 64 + col])
                 + pt32[n] * h2f(stXb[(btM + 2 * NN + n) * 64 + col]);
          } else {
            val += pt23[n] * h2f(stXb[(btM + NN + n) * 64 + col]);
          }
          xs1b[(btM + (long)w * NN + n) * 64 + col] = f2h(val);
        }
      }
}

// ------- t2 via MFMA: 2*(L*xs1)[mid] - stX[mid] -> fp16 ------------------
__global__ __launch_bounds__(256) void k_t2_mfma(const unsigned short* __restrict__ gsoB,
                                                 const unsigned short* __restrict__ xs1b,
                                                 const unsigned short* __restrict__ stXb,
                                                 const float* __restrict__ pt12,
                                                 const float* __restrict__ pt32,
                                                 unsigned short* __restrict__ t2b) {
  __shared__ alignas(16) unsigned short Al[128 * 40];
  __shared__ alignas(16) unsigned short Bt[64 * 40];
  int bt = blockIdx.x;
  int b = bt / TT;
  int rt_blk = blockIdx.y;
  const unsigned short* A = gsoB + (long)b * NN * GSTR;
  long vbase = (long)bt * MM + NN;
  int tid = threadIdx.x;
  int lane = tid & 63;
  int wv = __builtin_amdgcn_readfirstlane(tid >> 6);
  int lr = lane & 15, lg = lane >> 4;
  f32x4 zero4 = {0.f, 0.f, 0.f, 0.f};
  f32x4 acc[2][4];
#pragma unroll
  for (int rt = 0; rt < 2; ++rt)
#pragma unroll
    for (int c = 0; c < 4; ++c) acc[rt][c] = zero4;
  for (int kb_ = 0; kb_ < 352; kb_ += 32) {
    __syncthreads();
    for (int u = 0; u < 2; ++u) {
      int idx = tid + 256 * u;
      int row = idx >> 2, c8 = idx & 3;
      int rr = rt_blk * 128 + row; if (rr > NN - 1) rr = NN - 1;
      *(uint4*)&Al[row * 40 + c8 * 8] = *(const uint4*)&A[(long)rr * GSTR + kb_ + c8 * 8];
    }
    for (int u = 0; u < 2; ++u) {
      int idx = tid + 256 * u;
      int k = idx >> 4, c4 = idx & 15;
      int kg = kb_ + k;
      ushort4 vv;
      if (kg < NN) vv = *(const ushort4*)&xs1b[(vbase + kg) * 64 + c4 * 4];
      else { vv.x = 0; vv.y = 0; vv.z = 0; vv.w = 0; }
      Bt[(4 * c4 + 0) * 40 + k] = vv.x;
      Bt[(4 * c4 + 1) * 40 + k] = vv.y;
      Bt[(4 * c4 + 2) * 40 + k] = vv.z;
      Bt[(4 * c4 + 3) * 40 + k] = vv.w;
    }
    __syncthreads();
    half8 a0 = *(const half8*)&Al[(32 * wv + lr) * 40 + lg * 8];
    half8 a1 = *(const half8*)&Al[(32 * wv + 16 + lr) * 40 + lg * 8];
#pragma unroll
    for (int c = 0; c < 4; ++c) {
      half8 b_ = *(const half8*)&Bt[(16 * c + lr) * 40 + lg * 8];
      acc[0][c] = __builtin_amdgcn_mfma_f32_16x16x32_f16(a0, b_, acc[0][c], 0, 0, 0);
      acc[1][c] = __builtin_amdgcn_mfma_f32_16x16x32_f16(a1, b_, acc[1][c], 0, 0, 0);
    }
  }
  long btM = (long)bt * MM;
#pragma unroll
  for (int rt = 0; rt < 2; ++rt)
#pragma unroll
    for (int c = 0; c < 4; ++c)
#pragma unroll
      for (int e = 0; e < 4; ++e) {
        int n = rt_blk * 128 + 32 * wv + 16 * rt + lg * 4 + e;
        int col = 16 * c + lr;
        if (n < NN) {
          float val = 2.f * (pt12[n] * h2f(xs1b[(btM + n) * 64 + col])
                             + acc[rt][c][e]
                             + pt32[n] * h2f(xs1b[(btM + 2 * NN + n) * 64 + col]))
                      - h2f(stXb[(btM + NN + n) * 64 + col]);
          t2b[((long)bt * NN + n) * 64 + col] = f2h(val);
        }
      }
}

// ------- cheb via MFMA: [31200x192]x[192x64] + LayerNorm epilogue --------
__global__ __launch_bounds__(256) void k_cheb_mfma(const unsigned short* __restrict__ stXb,
                                                   const unsigned short* __restrict__ xs1b,
                                                   const unsigned short* __restrict__ t2b,
                                                   const float* __restrict__ cw,
                                                   const float* __restrict__ lng,
                                                   const float* __restrict__ lnb,
                                                   float* __restrict__ gcn) {
  __shared__ alignas(16) unsigned short Bt[64 * 200];  // [j][K], K=192
  __shared__ alignas(16) unsigned short Al[128 * 40];
  int tid = threadIdx.x;
  for (int u = 0; u < 48; ++u) {
    int f = tid + 256 * u;                   // f = K*64 + j
    int K = f >> 6, j = f & 63;
    Bt[j * 200 + K] = f2h(cw[f]);
  }
  int lane = tid & 63;
  int wv = __builtin_amdgcn_readfirstlane(tid >> 6);
  int lr = lane & 15, lg = lane >> 4;
  long grow0 = (long)blockIdx.x * 128;
  f32x4 zero4 = {0.f, 0.f, 0.f, 0.f};
  f32x4 acc[2][4];
#pragma unroll
  for (int rt = 0; rt < 2; ++rt)
#pragma unroll
    for (int c = 0; c < 4; ++c) acc[rt][c] = zero4;
  for (int ch = 0; ch < 6; ++ch) {
    const unsigned short* src = ch < 2 ? stXb : (ch < 4 ? xs1b : t2b);
    int koff = (ch & 1) * 32;
    __syncthreads();
    for (int u = 0; u < 2; ++u) {
      int idx = tid + 256 * u;
      int row = idx >> 2, c8 = idx & 3;
      long gr = grow0 + row; if (gr > 31199) gr = 31199;
      int bt = (int)(gr / NN), n = (int)(gr - (long)bt * NN);
      long sbase = (ch < 4) ? ((long)bt * MM + NN + n) * 64 : gr * 64;
      *(uint4*)&Al[row * 40 + c8 * 8] = *(const uint4*)&src[sbase + koff + c8 * 8];
    }
    __syncthreads();
    half8 a0 = *(const half8*)&Al[(32 * wv + lr) * 40 + lg * 8];
    half8 a1 = *(const half8*)&Al[(32 * wv + 16 + lr) * 40 + lg * 8];
#pragma unroll
    for (int c = 0; c < 4; ++c) {
      half8 b = *(const half8*)&Bt[(16 * c + lr) * 200 + ch * 32 + lg * 8];
      acc[0][c] = __builtin_amdgcn_mfma_f32_16x16x32_f16(a0, b, acc[0][c], 0, 0, 0);
      acc[1][c] = __builtin_amdgcn_mfma_f32_16x16x32_f16(a1, b, acc[1][c], 0, 0, 0);
    }
  }
  float lngv[4], lnbv[4];
#pragma unroll
  for (int c = 0; c < 4; ++c) { lngv[c] = lng[16 * c + lr]; lnbv[c] = lnb[16 * c + lr]; }
#pragma unroll
  for (int rt = 0; rt < 2; ++rt)
#pragma unroll
    for (int e = 0; e < 4; ++e) {
      float s = acc[rt][0][e] + acc[rt][1][e] + acc[rt][2][e] + acc[rt][3][e];
      for (int m = 1; m < 16; m <<= 1) s += __shfl_xor(s, m);
      float mu = s * (1.f / 64.f);
      float q = 0.f;
#pragma unroll
      for (int c = 0; c < 4; ++c) { float d = acc[rt][c][e] - mu; q += d * d; }
      for (int m = 1; m < 16; m <<= 1) q += __shfl_xor(q, m);
      float rstd = rsqrtf(q * (1.f / 64.f) + LN_EPS_);
      long gr = grow0 + 32 * wv + 16 * rt + lg * 4 + e;
      if (gr < 31200) {
#pragma unroll
        for (int c = 0; c < 4; ++c)
          gcn[gr * 64 + 16 * c + lr] = (acc[rt][c][e] - mu) * rstd * lngv[c] + lnbv[c];
      }
    }
}

// -------- mean over (t,n) per (b,d), inline scramble-gather --------------
__global__ __launch_bounds__(256) void k_mean(const float* __restrict__ sem,
                                              const float* __restrict__ gcn,
                                              float* __restrict__ mbd) {
  __shared__ float red[4][64];
  int bt = blockIdx.x;
  int b = bt / TT;
  int d = threadIdx.x & 63, g = threadIdx.x >> 6;
  float s = 0.f;
  for (int n = g; n < NN; n += 4) {
    int f = (NN + n) * 64 + d;
    int mm = f % MM, ii = f / MM;
    float a = sem[((long)bt * MM + mm) * 64 + ii];
    float r = gcn[((long)bt * NN + n) * 64 + d];
    s += a + r;
  }
  red[g][d] = s;
  __syncthreads();
  if (threadIdx.x < 64) {
    float v = red[0][d] + red[1][d] + red[2][d] + red[3][d];
    atomicAdd(&mbd[b * 64 + d], v);
  }
}

// -------- global AFF branch ----------------------------------------------
__global__ __launch_bounds__(64) void k_glob(const float* __restrict__ mbd,
                                             const float* __restrict__ w1,
                                             const float* __restrict__ b1,
                                             const float* __restrict__ g1,
                                             const float* __restrict__ be1,
                                             const float* __restrict__ w2,
                                             const float* __restrict__ b2,
                                             const float* __restrict__ g2,
                                             const float* __restrict__ be2,
                                             float* __restrict__ xg) {
  __shared__ float ml[64];
  __shared__ float zg[16];
  int b = blockIdx.x, d = threadIdx.x;
  ml[d] = mbd[b * 64 + d] * (1.f / 3900.f);
  __syncthreads();
  float rb = rsqrtf(1.f + BN_EPS_);
  if (d < 16) {
    float a = b1[d];
    for (int i = 0; i < 64; ++i) a += w1[d * 64 + i] * ml[i];
    a = a * (g1[d] * rb) + be1[d];
    zg[d] = a > 0.f ? a : 0.f;
  }
  __syncthreads();
  float a = b2[d];
  for (int i = 0; i < 16; ++i) a += w2[d * 16 + i] * zg[i];
  xg[b * 64 + d] = a * (g2[d] * rb) + be2[d];
}

// -------- final: local AFF branch + sigmoid fuse (inline gather) ---------
__global__ __launch_bounds__(256) void k_final(const float* __restrict__ sem,
                                               const float* __restrict__ gcn,
                                               const float* __restrict__ xg,
                                               const float* __restrict__ w1,
                                               const float* __restrict__ b1,
                                               const float* __restrict__ g1,
                                               const float* __restrict__ be1,
                                               const float* __restrict__ w2,
                                               const float* __restrict__ b2,
                                               const float* __restrict__ g2,
                                               const float* __restrict__ be2,
                                               float* __restrict__ out) {
  __shared__ float w1l[16][65];
  __shared__ float w2l[64][17];
  __shared__ float xal[4][64];
  __shared__ float zll[4][16];
  int tid = threadIdx.x;
  for (int u = 0; u < 4; ++u) {
    int f = tid + 256 * u;
    w1l[f >> 6][f & 63] = w1[f];
    w2l[f >> 4][f & 15] = w2[f];
  }
  int lane = tid & 63, wv = tid >> 6;
  long row = (long)blockIdx.x * 4 + wv;        // 31,200 rows exact
  int bt = (int)(row / NN);
  int n = (int)(row - (long)bt * NN);
  int b = bt / TT;
  int f = (NN + n) * 64 + lane;
  int mm = f % MM, ii = f / MM;
  float a = sem[((long)bt * MM + mm) * 64 + ii];
  float r = gcn[row * DD + lane];
  float xa = a + r;
  xal[wv][lane] = xa;
  __syncthreads();
  float rb = rsqrtf(1.f + BN_EPS_);
  if (lane < 16) {
    float acc = b1[lane];
#pragma unroll 8
    for (int i = 0; i < 64; ++i) acc += w1l[lane][i] * xal[wv][i];
    acc = acc * (g1[lane] * rb) + be1[lane];
    zll[wv][lane] = acc > 0.f ? acc : 0.f;
  }
  __syncthreads();
  float acc = b2[lane];
#pragma unroll
  for (int i = 0; i < 16; ++i) acc += w2l[lane][i] * zll[wv][i];
  float xl = acc * (g2[lane] * rb) + be2[lane];
  float wei = 1.f / (1.f + __expf(-(xl + xg[b * 64 + lane])));
  out[row * DD + lane] = 2.f * a * wei + 2.f * r * (1.f - wei);
}

extern "C" void kernel_launch(void* const* d_in, const int* in_sizes, int n_in,
                              void* d_out, int out_size, void* d_ws, size_t ws_size,
                              hipStream_t stream) {
  const float* x    = (const float*)d_in[0];
  const float* gso  = (const float*)d_in[1];
  const unsigned char* mask_raw = (const unsigned char*)d_in[2];
  const float* Wq   = (const float*)d_in[3];
  const float* Wk   = (const float*)d_in[4];
  const float* Wv   = (const float*)d_in[5];
  const float* chw  = (const float*)d_in[6];
  const float* pt12 = (const float*)d_in[7];
  const float* pt21 = (const float*)d_in[8];
  const float* pt23 = (const float*)d_in[9];
  const float* pt32 = (const float*)d_in[10];
  const float* lng  = (const float*)d_in[11];
  const float* lnb  = (const float*)d_in[12];
  const float* l_w1 = (const float*)d_in[13];
  const float* l_b1 = (const float*)d_in[14];
  const float* l_g1 = (const float*)d_in[15];
  const float* l_be1= (const float*)d_in[16];
  const float* l_w2 = (const float*)d_in[17];
  const float* l_b2 = (const float*)d_in[18];
  const float* l_g2 = (const float*)d_in[19];
  const float* l_be2= (const float*)d_in[20];
  const float* g_w1 = (const float*)d_in[21];
  const float* g_b1 = (const float*)d_in[22];
  const float* g_g1 = (const float*)d_in[23];
  const float* g_be1= (const float*)d_in[24];
  const float* g_w2 = (const float*)d_in[25];
  const float* g_b2 = (const float*)d_in[26];
  const float* g_g2 = (const float*)d_in[27];
  const float* g_be2= (const float*)d_in[28];

  float* base = (float*)d_ws;
  unsigned char* maskb = (unsigned char*)d_ws;
  unsigned short* gsoB = (unsigned short*)(base + WS_GSOB);
  unsigned short* stXb = (unsigned short*)(base + WS_STXB);
  unsigned short* qb   = (unsigned short*)(base + WS_QB);
  unsigned short* kb   = (unsigned short*)(base + WS_KB);
  unsigned short* vb   = (unsigned short*)(base + WS_VB);
  float* sem           = base + WS_SEM;
  unsigned short* t2b  = (unsigned short*)(base + WS_T2B);

  // aliases (lifetimes disjoint):
  unsigned short* xs1b = vb;            // vb dead after k_attn
  float* gcn = (float*)qb;              // qb dead after k_attn; 1.99M f <= 2.99M f
  float* mbd = base + WS_MBD;
  float* xg  = mbd + 512;

  k_maskprep<<<(NN * MBSTR + 255) / 256, 256, 0, stream>>>(mask_raw, maskb);
  k_gsoprep<<<3575, 256, 0, stream>>>(gso, gsoB);
  k_stx<<<23400, 256, 0, stream>>>(x, stXb);
  {
    dim3 g(732, 3);
    k_qkv_mfma<<<g, 256, 0, stream>>>(stXb, Wq, Wk, Wv, qb, kb, vb);
  }
  {
    dim3 ga(288, 6);
    k_attn<<<ga, 256, 0, stream>>>(qb, kb, vb, maskb, sem);
  }
  {
    dim3 g(288, 3);
    k_xs1_mfma<<<g, 256, 0, stream>>>(gsoB, stXb, pt12, pt21, pt23, pt32, xs1b);
  }
  {
    dim3 g(96, 3);
    k_t2_mfma<<<g, 256, 0, stream>>>(gsoB, xs1b, stXb, pt12, pt32, t2b);
  }
  k_cheb_mfma<<<244, 256, 0, stream>>>(stXb, xs1b, t2b, chw, lng, lnb, gcn);
  hipMemsetAsync(mbd, 0, 1024 * sizeof(float), stream);
  k_mean<<<96, 256, 0, stream>>>(sem, gcn, mbd);
  k_glob<<<8, 64, 0, stream>>>(mbd, g_w1, g_b1, g_g1, g_be1, g_w2, g_b2, g_g2, g_be2, xg);
  k_final<<<7800, 256, 0, stream>>>(sem, gcn, xg,
                                    l_w1, l_b1, l_g1, l_be1,
                                    l_w2, l_b2, l_g2, l_be2,
                                    (float*)d_out);
}

// Round 8
// 370.052 us; speedup vs baseline: 4.8453x; 1.1164x over previous
//
#include <hip/hip_runtime.h>
#include <math.h>

constexpr int TT = 12;
constexpr int NN = 325;
constexpr int MM = 975;   // 3*NN
constexpr int DD = 64;
constexpr long SZ = 96L * MM * DD;       // 5,990,400 elements per big tensor
constexpr int GSTR = 352;                // gso row stride (fp16 shorts), zero-padded
constexpr int MBSTR = 48;                // mask bitrow stride (bytes), 384 bits
constexpr int VTS = 22528;               // vbT per-seg elements (64*352)
constexpr float BN_EPS_ = 1e-5f;
constexpr float LN_EPS_ = 1e-5f;

// ---- workspace float offsets (running map) -------------------------------
constexpr long WS_MASKB = 0;                          // 15,600 B -> 4,096 f
constexpr long WS_GSOB  = WS_MASKB + 4096;            // 457,600 f
constexpr long WS_STXB  = WS_GSOB + 457600;           // SZ/2 f
constexpr long WS_QB    = WS_STXB + SZ / 2;
constexpr long WS_KB    = WS_QB + SZ / 2;
constexpr long WS_VB    = WS_KB + SZ / 2;
constexpr long WS_VT    = WS_VB + SZ / 2;             // 288*22528 shorts = 3,244,032 f
constexpr long WS_SEMH  = WS_VT + 3244032;            // SZ shorts = SZ/2 f
constexpr long WS_T2B   = WS_SEMH + SZ / 2;           // 998,400 f
constexpr long WS_MBD   = WS_T2B + 998400;            // mbd 512 + xg 512

typedef _Float16 half8 __attribute__((ext_vector_type(8)));
typedef __attribute__((ext_vector_type(4))) float f32x4;

static __device__ inline unsigned short f2h(float f) {
  _Float16 h = (_Float16)f;
  return __builtin_bit_cast(unsigned short, h);
}
static __device__ inline float h2f(unsigned short s) {
  return (float)__builtin_bit_cast(_Float16, s);
}

// ------------- mask sniff + pack to bitmask [NN][MBSTR] -------------------
__global__ __launch_bounds__(256) void k_maskprep(const unsigned char* __restrict__ raw,
                                                  unsigned char* __restrict__ outm) {
  bool is_u8 = false;
  for (int i = 0; i < 256; ++i) {
    if (raw[4 * i + 1]) { is_u8 = true; break; }
  }
  int idx = blockIdx.x * 256 + threadIdx.x;     // NN*MBSTR = 15,600 bytes
  if (idx >= NN * MBSTR) return;
  int n = idx / MBSTR, jb = idx - n * MBSTR;
  unsigned char v = 0;
  for (int k = 0; k < 8; ++k) {
    int col = jb * 8 + k;
    bool m = true;                               // pad cols -> masked
    if (col < NN) {
      int f = n * NN + col;
      m = is_u8 ? (raw[f] != 0) : (((const int*)raw)[f] != 0);
    }
    v |= (unsigned char)(m ? 1 : 0) << k;
  }
  outm[idx] = v;
}

// ------------- gso -> fp16, padded rows [8][325][GSTR] --------------------
__global__ __launch_bounds__(256) void k_gsoprep(const float* __restrict__ gso,
                                                 unsigned short* __restrict__ gsoB) {
  int idx = blockIdx.x * 256 + threadIdx.x;   // 3575 blocks exact
  int b = idx / (NN * GSTR);
  int rem = idx - b * (NN * GSTR);
  int r = rem / GSTR, j = rem - r * GSTR;
  gsoB[idx] = (j < NN) ? f2h(gso[(long)b * NN * NN + r * NN + j]) : (unsigned short)0;
}

// ---------------- stX gather: [B,T,N,D] -> [BT, 3N, D] fp16 ---------------
__global__ __launch_bounds__(256) void k_stx(const float* __restrict__ x,
                                             unsigned short* __restrict__ stXb) {
  int idx = blockIdx.x * 256 + threadIdx.x;     // exact: 23,400 blocks
  int d = idx & 63;
  int m = (idx >> 6) % MM;
  int bt = idx / (MM * DD);
  int b = bt / TT, t = bt - b * TT;
  int w = m / NN, n = m - w * NN;
  int st = t + w - 1;
  st = st < 0 ? 0 : (st > TT - 1 ? TT - 1 : st);
  stXb[idx] = f2h(x[(((b * TT + st) * NN + n) << 6) + d]);
}

// ---------------- QKV via MFMA: [93600x64] x [64x64] -> fp16 -------------
__global__ __launch_bounds__(256) void k_qkv_mfma(const unsigned short* __restrict__ stXb,
                                                  const float* __restrict__ Wq,
                                                  const float* __restrict__ Wk,
                                                  const float* __restrict__ Wv,
                                                  unsigned short* __restrict__ qb,
                                                  unsigned short* __restrict__ kb,
                                                  unsigned short* __restrict__ vb) {
  __shared__ alignas(16) unsigned short sX[128 * 72];
  __shared__ alignas(16) unsigned short sW[64 * 72];
  const float* W = blockIdx.y == 0 ? Wq : (blockIdx.y == 1 ? Wk : Wv);
  unsigned short* outb = blockIdx.y == 0 ? qb : (blockIdx.y == 1 ? kb : vb);
  int tid = threadIdx.x;
  long r0 = (long)blockIdx.x * 128;
  for (int u = 0; u < 4; ++u) {
    int idx = tid + 256 * u;
    int row = idx >> 3, c8 = idx & 7;
    long rg = r0 + row; if (rg > 93599) rg = 93599;
    *(uint4*)&sX[row * 72 + c8 * 8] = *(const uint4*)&stXb[rg * 64 + c8 * 8];
  }
  for (int u = 0; u < 16; ++u) {
    int f = tid + 256 * u;
    int o = f >> 6, d = f & 63;
    sW[o * 72 + d] = f2h(W[f]);
  }
  __syncthreads();
  int lane = tid & 63;
  int wv = __builtin_amdgcn_readfirstlane(tid >> 6);
  int lr = lane & 15, lg = lane >> 4;
  f32x4 zero4 = {0.f, 0.f, 0.f, 0.f};
  f32x4 acc[2][4];
#pragma unroll
  for (int rt = 0; rt < 2; ++rt)
#pragma unroll
    for (int c = 0; c < 4; ++c) acc[rt][c] = zero4;
#pragma unroll
  for (int kk = 0; kk < 2; ++kk) {
    half8 a0 = *(const half8*)&sX[(32 * wv + lr) * 72 + kk * 32 + lg * 8];
    half8 a1 = *(const half8*)&sX[(32 * wv + 16 + lr) * 72 + kk * 32 + lg * 8];
#pragma unroll
    for (int c = 0; c < 4; ++c) {
      half8 b = *(const half8*)&sW[(16 * c + lr) * 72 + kk * 32 + lg * 8];
      acc[0][c] = __builtin_amdgcn_mfma_f32_16x16x32_f16(a0, b, acc[0][c], 0, 0, 0);
      acc[1][c] = __builtin_amdgcn_mfma_f32_16x16x32_f16(a1, b, acc[1][c], 0, 0, 0);
    }
  }
  __syncthreads();
#pragma unroll
  for (int rt = 0; rt < 2; ++rt)
#pragma unroll
    for (int c = 0; c < 4; ++c)
#pragma unroll
      for (int e = 0; e < 4; ++e) {
        int row = 32 * wv + 16 * rt + lg * 4 + e;
        int col = 16 * c + lr;
        sX[row * 64 + col] = f2h(acc[rt][c][e]);
      }
  __syncthreads();
  for (int u = 0; u < 4; ++u) {
    int idx = tid + 256 * u;
    int row = idx >> 3, c8 = idx & 7;
    long rg = r0 + row;
    if (rg < 93600)
      *(uint4*)&outb[rg * 64 + c8 * 8] = *(const uint4*)&sX[row * 64 + c8 * 8];
  }
}

// ------- V transpose: vb [seg*NN+k][64] -> vbT [seg][64][352] ------------
__global__ __launch_bounds__(256) void k_vT(const unsigned short* __restrict__ vb,
                                            unsigned short* __restrict__ vbT) {
  __shared__ alignas(16) unsigned short T[128 * 72];
  int seg = blockIdx.x;                  // 0..287
  int ck = blockIdx.y;                   // 0..2 (k chunks of 128)
  int tid = threadIdx.x;
  long base = (long)seg * NN * 64;
  int k0 = ck * 128;
  for (int u = 0; u < 4; ++u) {
    int idx = tid + 256 * u;
    int row = idx >> 3, c8 = idx & 7;
    int kg = k0 + row;
    uint4 v;
    if (kg < NN) v = *(const uint4*)&vb[base + (long)kg * 64 + c8 * 8];
    else { v.x = 0; v.y = 0; v.z = 0; v.w = 0; }
    *(uint4*)&T[row * 72 + c8 * 8] = v;
  }
  __syncthreads();
  int d = tid & 63, k8 = tid >> 6;
  for (int it = 0; it < 4; ++it) {
    int klocal = (it * 4 + k8) * 8;
    if (k0 + klocal < 352) {
      unsigned short tmp[8];
#pragma unroll
      for (int j = 0; j < 8; ++j) tmp[j] = T[(klocal + j) * 72 + d];
      *(uint4*)&vbT[(long)seg * VTS + (long)d * 352 + k0 + klocal] = *(const uint4*)tmp;
    }
  }
}

// ------- fully fused attention, no big LDS: QK^T + softmax + PV ----------
__global__ __launch_bounds__(256, 3) void k_attn(const unsigned short* __restrict__ qb,
                                                 const unsigned short* __restrict__ kb,
                                                 const unsigned short* __restrict__ vb,
                                                 const unsigned short* __restrict__ vbT,
                                                 const unsigned char* __restrict__ maskb,
                                                 unsigned short* __restrict__ semh) {
  __shared__ unsigned char Mb[64 * MBSTR];              // 3 KB mask bits
  __shared__ alignas(16) unsigned short Ptr4[4 * 16 * 40];  // per-wave P scratch
  int seg = blockIdx.x;                  // bt*3+w
  int bt = seg / 3, w = seg - bt * 3;
  int rt = blockIdx.y;                   // 0..5
  long segbase = (long)seg * NN * 64;
  int tid = threadIdx.x;
  // stage mask bits
  if (tid < 192) {
    int r = tid / 3, c16 = tid - (tid / 3) * 3;
    int rg = rt * 64 + r; if (rg > NN - 1) rg = NN - 1;
    *(uint4*)&Mb[r * MBSTR + c16 * 16] = *(const uint4*)&maskb[(long)rg * MBSTR + c16 * 16];
  }
  __syncthreads();
  int lane = tid & 63;
  int wv = __builtin_amdgcn_readfirstlane(tid >> 6);
  int lr = lane & 15, lg = lane >> 4;
  f32x4 zero4 = {0.f, 0.f, 0.f, 0.f};
  f32x4 acc[21];
#pragma unroll
  for (int ct = 0; ct < 21; ++ct) acc[ct] = zero4;
  f32x4 dA = zero4, dB = zero4;
  int arow = rt * 64 + 16 * wv + lr; if (arow > NN - 1) arow = NN - 1;
  long abase = segbase + (long)arow * 64;
  int nl_f = arow;
  long pAaddr = ((long)bt * MM + ((w == 1) ? nl_f : NN + nl_f)) * 64;
  long pBaddr = ((long)bt * MM + 2 * NN + nl_f) * 64;
#pragma unroll
  for (int kk = 0; kk < 2; ++kk) {
    half8 a = *(const half8*)&qb[abase + kk * 32 + lg * 8];
#pragma unroll
    for (int ct = 0; ct < 21; ++ct) {
      int brow = 16 * ct + lr; if (brow > NN - 1) brow = NN - 1;
      half8 b = *(const half8*)&kb[segbase + (long)brow * 64 + kk * 32 + lg * 8];
      acc[ct] = __builtin_amdgcn_mfma_f32_16x16x32_f16(a, b, acc[ct], 0, 0, 0);
    }
    half8 bA = *(const half8*)&kb[pAaddr + kk * 32 + lg * 8];
    dA = __builtin_amdgcn_mfma_f32_16x16x32_f16(a, bA, dA, 0, 0, 0);
    if (w == 1) {
      half8 bB = *(const half8*)&kb[pBaddr + kk * 32 + lg * 8];
      dB = __builtin_amdgcn_mfma_f32_16x16x32_f16(a, bB, dB, 0, 0, 0);
    }
  }
  // diag extraction: element (r,r) at lane 20*lg+e for r = lg*4+e
  float da_[4], db_[4];
#pragma unroll
  for (int e = 0; e < 4; ++e) {
    int src = lg * 20 + e;
    da_[e] = __shfl(dA[e], src);
    db_[e] = (w == 1) ? __shfl(dB[e], src) : -INFINITY;
  }
  // mask (register bit tests) + row max
  float mx[4] = {-INFINITY, -INFINITY, -INFINITY, -INFINITY};
  unsigned mw[4];
#pragma unroll
  for (int ct = 0; ct < 21; ++ct) {
    if ((ct & 1) == 0) {
#pragma unroll
      for (int e = 0; e < 4; ++e) {
        int rl = 16 * wv + lg * 4 + e;
        mw[e] = *(const unsigned*)&Mb[rl * MBSTR + (ct >> 1) * 4];
      }
    }
    int sh = 16 * (ct & 1) + lr;
#pragma unroll
    for (int e = 0; e < 4; ++e) {
      bool masked = (mw[e] >> sh) & 1;
      float s = masked ? -INFINITY : acc[ct][e];
      acc[ct][e] = s;
      mx[e] = fmaxf(mx[e], s);
    }
  }
#pragma unroll
  for (int e = 0; e < 4; ++e)
    for (int m = 1; m < 16; m <<= 1) mx[e] = fmaxf(mx[e], __shfl_xor(mx[e], m));
  float gm[4], ea[4], eb[4], sum[4], inv[4];
#pragma unroll
  for (int e = 0; e < 4; ++e) {
    gm[e] = fmaxf(mx[e], da_[e]);
    if (w == 1) gm[e] = fmaxf(gm[e], db_[e]);
    sum[e] = 0.f;
  }
#pragma unroll
  for (int ct = 0; ct < 21; ++ct)
#pragma unroll
    for (int e = 0; e < 4; ++e) {
      float s = acc[ct][e];
      float p = (s > -1e37f) ? __expf(s - gm[e]) : 0.f;
      acc[ct][e] = p;
      sum[e] += p;
    }
#pragma unroll
  for (int e = 0; e < 4; ++e) {
    for (int m = 1; m < 16; m <<= 1) sum[e] += __shfl_xor(sum[e], m);
    ea[e] = __expf(da_[e] - gm[e]);
    eb[e] = (w == 1) ? __expf(db_[e] - gm[e]) : 0.f;
    sum[e] += ea[e] + eb[e];
    inv[e] = 1.f / sum[e];
  }
  // PV: per-wave P transpose scratch; B-fragments direct from global vbT
  unsigned short* Ptr = Ptr4 + wv * 640;   // [16][40]
  long vtbase = (long)seg * VTS;
  f32x4 oacc[4];
#pragma unroll
  for (int c = 0; c < 4; ++c) oacc[c] = zero4;
#pragma unroll
  for (int ck = 0; ck < 11; ++ck) {
#pragma unroll
    for (int t = 0; t < 2; ++t) {
      int ct = 2 * ck + t;
#pragma unroll
      for (int e = 0; e < 4; ++e) {
        float pv = (ct < 21) ? acc[ct][e] * inv[e] : 0.f;
        Ptr[(lg * 4 + e) * 40 + t * 16 + lr] = f2h(pv);
      }
    }
    half8 a = *(const half8*)&Ptr[lr * 40 + lg * 8];
#pragma unroll
    for (int c = 0; c < 4; ++c) {
      half8 b = *(const half8*)&vbT[vtbase + (long)(16 * c + lr) * 352 + ck * 32 + lg * 8];
      oacc[c] = __builtin_amdgcn_mfma_f32_16x16x32_f16(a, b, oacc[c], 0, 0, 0);
    }
  }
  // epilogue: diag-partner contributions + write semh
#pragma unroll
  for (int c = 0; c < 4; ++c)
#pragma unroll
    for (int e = 0; e < 4; ++e) {
      int n = rt * 64 + 16 * wv + lg * 4 + e;
      int col = 16 * c + lr;
      if (n < NN) {
        float val = oacc[c][e];
        int partA = (w == 1) ? n : NN + n;
        val += ea[e] * inv[e] * h2f(vb[((long)bt * MM + partA) * 64 + col]);
        if (w == 1)
          val += eb[e] * inv[e] * h2f(vb[((long)bt * MM + 2 * NN + n) * 64 + col]);
        semh[((long)bt * MM + (long)w * NN + n) * 64 + col] = f2h(val);
      }
    }
}

// ---------------- xs1 via MFMA: gso x stX(block) + diag epilogue ---------
__global__ __launch_bounds__(256) void k_xs1_mfma(const unsigned short* __restrict__ gsoB,
                                                  const unsigned short* __restrict__ stXb,
                                                  const float* __restrict__ pt12,
                                                  const float* __restrict__ pt21,
                                                  const float* __restrict__ pt23,
                                                  const float* __restrict__ pt32,
                                                  unsigned short* __restrict__ xs1b) {
  __shared__ alignas(16) unsigned short Al[128 * 40];
  __shared__ alignas(16) unsigned short Bt[64 * 40];
  int btw = blockIdx.x;
  int bt = btw / 3, w = btw - bt * 3;
  int b = bt / TT;
  int rt_blk = blockIdx.y;
  const unsigned short* A = gsoB + (long)b * NN * GSTR;
  long vbase = (long)bt * MM + (long)w * NN;
  int tid = threadIdx.x;
  int lane = tid & 63;
  int wv = __builtin_amdgcn_readfirstlane(tid >> 6);
  int lr = lane & 15, lg = lane >> 4;
  f32x4 zero4 = {0.f, 0.f, 0.f, 0.f};
  f32x4 acc[2][4];
#pragma unroll
  for (int rt = 0; rt < 2; ++rt)
#pragma unroll
    for (int c = 0; c < 4; ++c) acc[rt][c] = zero4;
  for (int kb_ = 0; kb_ < 352; kb_ += 32) {
    __syncthreads();
    for (int u = 0; u < 2; ++u) {
      int idx = tid + 256 * u;
      int row = idx >> 2, c8 = idx & 3;
      int rr = rt_blk * 128 + row; if (rr > NN - 1) rr = NN - 1;
      *(uint4*)&Al[row * 40 + c8 * 8] = *(const uint4*)&A[(long)rr * GSTR + kb_ + c8 * 8];
    }
    for (int u = 0; u < 2; ++u) {
      int idx = tid + 256 * u;
      int k = idx >> 4, c4 = idx & 15;
      int kg = kb_ + k;
#pragma unroll
      for (int j = 0; j < 4; ++j) {
        int d = c4 + 16 * j;
        unsigned short val = (kg < NN) ? stXb[(vbase + kg) * 64 + d] : (unsigned short)0;
        Bt[d * 40 + k] = val;
      }
    }
    __syncthreads();
    half8 a0 = *(const half8*)&Al[(32 * wv + lr) * 40 + lg * 8];
    half8 a1 = *(const half8*)&Al[(32 * wv + 16 + lr) * 40 + lg * 8];
#pragma unroll
    for (int c = 0; c < 4; ++c) {
      half8 b_ = *(const half8*)&Bt[(16 * c + lr) * 40 + lg * 8];
      acc[0][c] = __builtin_amdgcn_mfma_f32_16x16x32_f16(a0, b_, acc[0][c], 0, 0, 0);
      acc[1][c] = __builtin_amdgcn_mfma_f32_16x16x32_f16(a1, b_, acc[1][c], 0, 0, 0);
    }
  }
  long btM = (long)bt * MM;
#pragma unroll
  for (int rt = 0; rt < 2; ++rt)
#pragma unroll
    for (int c = 0; c < 4; ++c)
#pragma unroll
      for (int e = 0; e < 4; ++e) {
        int n = rt_blk * 128 + 32 * wv + 16 * rt + lg * 4 + e;
        int col = 16 * c + lr;
        if (n < NN) {
          float val = acc[rt][c][e];
          if (w == 0) {
            val += pt21[n] * h2f(stXb[(btM + NN + n) * 64 + col]);
          } else if (w == 1) {
            val += pt12[n] * h2f(stXb[(btM + n) * 64 + col])
                 + pt32[n] * h2f(stXb[(btM + 2 * NN + n) * 64 + col]);
          } else {
            val += pt23[n] * h2f(stXb[(btM + NN + n) * 64 + col]);
          }
          xs1b[(btM + (long)w * NN + n) * 64 + col] = f2h(val);
        }
      }
}

// ------- t2 via MFMA: 2*(L*xs1)[mid] - stX[mid] -> fp16 ------------------
__global__ __launch_bounds__(256) void k_t2_mfma(const unsigned short* __restrict__ gsoB,
                                                 const unsigned short* __restrict__ xs1b,
                                                 const unsigned short* __restrict__ stXb,
                                                 const float* __restrict__ pt12,
                                                 const float* __restrict__ pt32,
                                                 unsigned short* __restrict__ t2b) {
  __shared__ alignas(16) unsigned short Al[128 * 40];
  __shared__ alignas(16) unsigned short Bt[64 * 40];
  int bt = blockIdx.x;
  int b = bt / TT;
  int rt_blk = blockIdx.y;
  const unsigned short* A = gsoB + (long)b * NN * GSTR;
  long vbase = (long)bt * MM + NN;
  int tid = threadIdx.x;
  int lane = tid & 63;
  int wv = __builtin_amdgcn_readfirstlane(tid >> 6);
  int lr = lane & 15, lg = lane >> 4;
  f32x4 zero4 = {0.f, 0.f, 0.f, 0.f};
  f32x4 acc[2][4];
#pragma unroll
  for (int rt = 0; rt < 2; ++rt)
#pragma unroll
    for (int c = 0; c < 4; ++c) acc[rt][c] = zero4;
  for (int kb_ = 0; kb_ < 352; kb_ += 32) {
    __syncthreads();
    for (int u = 0; u < 2; ++u) {
      int idx = tid + 256 * u;
      int row = idx >> 2, c8 = idx & 3;
      int rr = rt_blk * 128 + row; if (rr > NN - 1) rr = NN - 1;
      *(uint4*)&Al[row * 40 + c8 * 8] = *(const uint4*)&A[(long)rr * GSTR + kb_ + c8 * 8];
    }
    for (int u = 0; u < 2; ++u) {
      int idx = tid + 256 * u;
      int k = idx >> 4, c4 = idx & 15;
      int kg = kb_ + k;
#pragma unroll
      for (int j = 0; j < 4; ++j) {
        int d = c4 + 16 * j;
        unsigned short val = (kg < NN) ? xs1b[(vbase + kg) * 64 + d] : (unsigned short)0;
        Bt[d * 40 + k] = val;
      }
    }
    __syncthreads();
    half8 a0 = *(const half8*)&Al[(32 * wv + lr) * 40 + lg * 8];
    half8 a1 = *(const half8*)&Al[(32 * wv + 16 + lr) * 40 + lg * 8];
#pragma unroll
    for (int c = 0; c < 4; ++c) {
      half8 b_ = *(const half8*)&Bt[(16 * c + lr) * 40 + lg * 8];
      acc[0][c] = __builtin_amdgcn_mfma_f32_16x16x32_f16(a0, b_, acc[0][c], 0, 0, 0);
      acc[1][c] = __builtin_amdgcn_mfma_f32_16x16x32_f16(a1, b_, acc[1][c], 0, 0, 0);
    }
  }
  long btM = (long)bt * MM;
#pragma unroll
  for (int rt = 0; rt < 2; ++rt)
#pragma unroll
    for (int c = 0; c < 4; ++c)
#pragma unroll
      for (int e = 0; e < 4; ++e) {
        int n = rt_blk * 128 + 32 * wv + 16 * rt + lg * 4 + e;
        int col = 16 * c + lr;
        if (n < NN) {
          float val = 2.f * (pt12[n] * h2f(xs1b[(btM + n) * 64 + col])
                             + acc[rt][c][e]
                             + pt32[n] * h2f(xs1b[(btM + 2 * NN + n) * 64 + col]))
                      - h2f(stXb[(btM + NN + n) * 64 + col]);
          t2b[((long)bt * NN + n) * 64 + col] = f2h(val);
        }
      }
}

// ------- cheb via MFMA: [31200x192]x[192x64] + LayerNorm epilogue --------
__global__ __launch_bounds__(256) void k_cheb_mfma(const unsigned short* __restrict__ stXb,
                                                   const unsigned short* __restrict__ xs1b,
                                                   const unsigned short* __restrict__ t2b,
                                                   const float* __restrict__ cw,
                                                   const float* __restrict__ lng,
                                                   const float* __restrict__ lnb,
                                                   float* __restrict__ gcn) {
  __shared__ alignas(16) unsigned short Bt[64 * 200];  // [j][K], K=192
  __shared__ alignas(16) unsigned short Al[128 * 40];
  int tid = threadIdx.x;
  for (int u = 0; u < 48; ++u) {
    int f = tid + 256 * u;                   // f = K*64 + j
    int K = f >> 6, j = f & 63;
    Bt[j * 200 + K] = f2h(cw[f]);
  }
  int lane = tid & 63;
  int wv = __builtin_amdgcn_readfirstlane(tid >> 6);
  int lr = lane & 15, lg = lane >> 4;
  long grow0 = (long)blockIdx.x * 128;
  f32x4 zero4 = {0.f, 0.f, 0.f, 0.f};
  f32x4 acc[2][4];
#pragma unroll
  for (int rt = 0; rt < 2; ++rt)
#pragma unroll
    for (int c = 0; c < 4; ++c) acc[rt][c] = zero4;
  for (int ch = 0; ch < 6; ++ch) {
    const unsigned short* src = ch < 2 ? stXb : (ch < 4 ? xs1b : t2b);
    int koff = (ch & 1) * 32;
    __syncthreads();
    for (int u = 0; u < 2; ++u) {
      int idx = tid + 256 * u;
      int row = idx >> 2, c8 = idx & 3;
      long gr = grow0 + row; if (gr > 31199) gr = 31199;
      int bt = (int)(gr / NN), n = (int)(gr - (long)bt * NN);
      long sbase = (ch < 4) ? ((long)bt * MM + NN + n) * 64 : gr * 64;
      *(uint4*)&Al[row * 40 + c8 * 8] = *(const uint4*)&src[sbase + koff + c8 * 8];
    }
    __syncthreads();
    half8 a0 = *(const half8*)&Al[(32 * wv + lr) * 40 + lg * 8];
    half8 a1 = *(const half8*)&Al[(32 * wv + 16 + lr) * 40 + lg * 8];
#pragma unroll
    for (int c = 0; c < 4; ++c) {
      half8 b = *(const half8*)&Bt[(16 * c + lr) * 200 + ch * 32 + lg * 8];
      acc[0][c] = __builtin_amdgcn_mfma_f32_16x16x32_f16(a0, b, acc[0][c], 0, 0, 0);
      acc[1][c] = __builtin_amdgcn_mfma_f32_16x16x32_f16(a1, b, acc[1][c], 0, 0, 0);
    }
  }
  float lngv[4], lnbv[4];
#pragma unroll
  for (int c = 0; c < 4; ++c) { lngv[c] = lng[16 * c + lr]; lnbv[c] = lnb[16 * c + lr]; }
#pragma unroll
  for (int rt = 0; rt < 2; ++rt)
#pragma unroll
    for (int e = 0; e < 4; ++e) {
      float s = acc[rt][0][e] + acc[rt][1][e] + acc[rt][2][e] + acc[rt][3][e];
      for (int m = 1; m < 16; m <<= 1) s += __shfl_xor(s, m);
      float mu = s * (1.f / 64.f);
      float q = 0.f;
#pragma unroll
      for (int c = 0; c < 4; ++c) { float d = acc[rt][c][e] - mu; q += d * d; }
      for (int m = 1; m < 16; m <<= 1) q += __shfl_xor(q, m);
      float rstd = rsqrtf(q * (1.f / 64.f) + LN_EPS_);
      long gr = grow0 + 32 * wv + 16 * rt + lg * 4 + e;
      if (gr < 31200) {
#pragma unroll
        for (int c = 0; c < 4; ++c)
          gcn[gr * 64 + 16 * c + lr] = (acc[rt][c][e] - mu) * rstd * lngv[c] + lnbv[c];
      }
    }
}

// -------- mean over (t,n) per (b,d), inline scramble-gather --------------
__global__ __launch_bounds__(256) void k_mean(const unsigned short* __restrict__ semh,
                                              const float* __restrict__ gcn,
                                              float* __restrict__ mbd) {
  __shared__ float red[4][64];
  int bt = blockIdx.x;
  int b = bt / TT;
  int d = threadIdx.x & 63, g = threadIdx.x >> 6;
  float s = 0.f;
  for (int n = g; n < NN; n += 4) {
    int f = (NN + n) * 64 + d;
    int mm = f % MM, ii = f / MM;
    float a = h2f(semh[((long)bt * MM + mm) * 64 + ii]);
    float r = gcn[((long)bt * NN + n) * 64 + d];
    s += a + r;
  }
  red[g][d] = s;
  __syncthreads();
  if (threadIdx.x < 64) {
    float v = red[0][d] + red[1][d] + red[2][d] + red[3][d];
    atomicAdd(&mbd[b * 64 + d], v);
  }
}

// -------- global AFF branch ----------------------------------------------
__global__ __launch_bounds__(64) void k_glob(const float* __restrict__ mbd,
                                             const float* __restrict__ w1,
                                             const float* __restrict__ b1,
                                             const float* __restrict__ g1,
                                             const float* __restrict__ be1,
                                             const float* __restrict__ w2,
                                             const float* __restrict__ b2,
                                             const float* __restrict__ g2,
                                             const float* __restrict__ be2,
                                             float* __restrict__ xg) {
  __shared__ float ml[64];
  __shared__ float zg[16];
  int b = blockIdx.x, d = threadIdx.x;
  ml[d] = mbd[b * 64 + d] * (1.f / 3900.f);
  __syncthreads();
  float rb = rsqrtf(1.f + BN_EPS_);
  if (d < 16) {
    float a = b1[d];
    for (int i = 0; i < 64; ++i) a += w1[d * 64 + i] * ml[i];
    a = a * (g1[d] * rb) + be1[d];
    zg[d] = a > 0.f ? a : 0.f;
  }
  __syncthreads();
  float a = b2[d];
  for (int i = 0; i < 16; ++i) a += w2[d * 16 + i] * zg[i];
  xg[b * 64 + d] = a * (g2[d] * rb) + be2[d];
}

// -------- final: local AFF branch + sigmoid fuse (inline gather) ---------
__global__ __launch_bounds__(256) void k_final(const unsigned short* __restrict__ semh,
                                               const float* __restrict__ gcn,
                                               const float* __restrict__ xg,
                                               const float* __restrict__ w1,
                                               const float* __restrict__ b1,
                                               const float* __restrict__ g1,
                                               const float* __restrict__ be1,
                                               const float* __restrict__ w2,
                                               const float* __restrict__ b2,
                                               const float* __restrict__ g2,
                                               const float* __restrict__ be2,
                                               float* __restrict__ out) {
  __shared__ float w1l[16][65];
  __shared__ float w2l[64][17];
  __shared__ float xal[4][64];
  __shared__ float zll[4][16];
  int tid = threadIdx.x;
  for (int u = 0; u < 4; ++u) {
    int f = tid + 256 * u;
    w1l[f >> 6][f & 63] = w1[f];
    w2l[f >> 4][f & 15] = w2[f];
  }
  int lane = tid & 63, wv = tid >> 6;
  long row = (long)blockIdx.x * 4 + wv;        // 31,200 rows exact
  int bt = (int)(row / NN);
  int n = (int)(row - (long)bt * NN);
  int b = bt / TT;
  int f = (NN + n) * 64 + lane;
  int mm = f % MM, ii = f / MM;
  float a = h2f(semh[((long)bt * MM + mm) * 64 + ii]);
  float r = gcn[row * DD + lane];
  float xa = a + r;
  xal[wv][lane] = xa;
  __syncthreads();
  float rb = rsqrtf(1.f + BN_EPS_);
  if (lane < 16) {
    float acc = b1[lane];
#pragma unroll 8
    for (int i = 0; i < 64; ++i) acc += w1l[lane][i] * xal[wv][i];
    acc = acc * (g1[lane] * rb) + be1[lane];
    zll[wv][lane] = acc > 0.f ? acc : 0.f;
  }
  __syncthreads();
  float acc = b2[lane];
#pragma unroll
  for (int i = 0; i < 16; ++i) acc += w2l[lane][i] * zll[wv][i];
  float xl = acc * (g2[lane] * rb) + be2[lane];
  float wei = 1.f / (1.f + __expf(-(xl + xg[b * 64 + lane])));
  out[row * DD + lane] = 2.f * a * wei + 2.f * r * (1.f - wei);
}

extern "C" void kernel_launch(void* const* d_in, const int* in_sizes, int n_in,
                              void* d_out, int out_size, void* d_ws, size_t ws_size,
                              hipStream_t stream) {
  const float* x    = (const float*)d_in[0];
  const float* gso  = (const float*)d_in[1];
  const unsigned char* mask_raw = (const unsigned char*)d_in[2];
  const float* Wq   = (const float*)d_in[3];
  const float* Wk   = (const float*)d_in[4];
  const float* Wv   = (const float*)d_in[5];
  const float* chw  = (const float*)d_in[6];
  const float* pt12 = (const float*)d_in[7];
  const float* pt21 = (const float*)d_in[8];
  const float* pt23 = (const float*)d_in[9];
  const float* pt32 = (const float*)d_in[10];
  const float* lng  = (const float*)d_in[11];
  const float* lnb  = (const float*)d_in[12];
  const float* l_w1 = (const float*)d_in[13];
  const float* l_b1 = (const float*)d_in[14];
  const float* l_g1 = (const float*)d_in[15];
  const float* l_be1= (const float*)d_in[16];
  const float* l_w2 = (const float*)d_in[17];
  const float* l_b2 = (const float*)d_in[18];
  const float* l_g2 = (const float*)d_in[19];
  const float* l_be2= (const float*)d_in[20];
  const float* g_w1 = (const float*)d_in[21];
  const float* g_b1 = (const float*)d_in[22];
  const float* g_g1 = (const float*)d_in[23];
  const float* g_be1= (const float*)d_in[24];
  const float* g_w2 = (const float*)d_in[25];
  const float* g_b2 = (const float*)d_in[26];
  const float* g_g2 = (const float*)d_in[27];
  const float* g_be2= (const float*)d_in[28];

  float* base = (float*)d_ws;
  unsigned char* maskb = (unsigned char*)d_ws;
  unsigned short* gsoB = (unsigned short*)(base + WS_GSOB);
  unsigned short* stXb = (unsigned short*)(base + WS_STXB);
  unsigned short* qb   = (unsigned short*)(base + WS_QB);
  unsigned short* kb   = (unsigned short*)(base + WS_KB);
  unsigned short* vb   = (unsigned short*)(base + WS_VB);
  unsigned short* vbT  = (unsigned short*)(base + WS_VT);
  unsigned short* semh = (unsigned short*)(base + WS_SEMH);
  unsigned short* t2b  = (unsigned short*)(base + WS_T2B);

  // aliases (lifetimes disjoint):
  unsigned short* xs1b = vb;            // vb dead after k_attn
  float* gcn = (float*)qb;              // qb dead after k_attn; 1.99M f <= 2.99M f
  float* mbd = base + WS_MBD;
  float* xg  = mbd + 512;

  k_maskprep<<<(NN * MBSTR + 255) / 256, 256, 0, stream>>>(mask_raw, maskb);
  k_gsoprep<<<3575, 256, 0, stream>>>(gso, gsoB);
  k_stx<<<23400, 256, 0, stream>>>(x, stXb);
  {
    dim3 g(732, 3);
    k_qkv_mfma<<<g, 256, 0, stream>>>(stXb, Wq, Wk, Wv, qb, kb, vb);
  }
  {
    dim3 gv(288, 3);
    k_vT<<<gv, 256, 0, stream>>>(vb, vbT);
  }
  {
    dim3 ga(288, 6);
    k_attn<<<ga, 256, 0, stream>>>(qb, kb, vb, vbT, maskb, semh);
  }
  {
    dim3 g(288, 3);
    k_xs1_mfma<<<g, 256, 0, stream>>>(gsoB, stXb, pt12, pt21, pt23, pt32, xs1b);
  }
  {
    dim3 g(96, 3);
    k_t2_mfma<<<g, 256, 0, stream>>>(gsoB, xs1b, stXb, pt12, pt32, t2b);
  }
  k_cheb_mfma<<<244, 256, 0, stream>>>(stXb, xs1b, t2b, chw, lng, lnb, gcn);
  hipMemsetAsync(mbd, 0, 1024 * sizeof(float), stream);
  k_mean<<<96, 256, 0, stream>>>(semh, gcn, mbd);
  k_glob<<<8, 64, 0, stream>>>(mbd, g_w1, g_b1, g_g1, g_be1, g_w2, g_b2, g_g2, g_be2, xg);
  k_final<<<7800, 256, 0, stream>>>(semh, gcn, xg,
                                    l_w1, l_b1, l_g1, l_be1,
                                    l_w2, l_b2, l_g2, l_be2,
                                    (float*)d_out);
}

// Round 9
// 359.227 us; speedup vs baseline: 4.9913x; 1.0301x over previous
//
#include <hip/hip_runtime.h>
#include <math.h>

constexpr int TT = 12;
constexpr int NN = 325;
constexpr int MM = 975;   // 3*NN
constexpr int DD = 64;
constexpr long SZ = 96L * MM * DD;       // 5,990,400 elements per big tensor
constexpr int GSTR = 352;                // gso row stride (fp16 shorts), zero-padded
constexpr int MBSTR = 48;                // mask bitrow stride (bytes), 384 bits
constexpr int VTS = 22528;               // vbT per-seg elements (64*352)
constexpr float BN_EPS_ = 1e-5f;
constexpr float LN_EPS_ = 1e-5f;

// ---- workspace float offsets (running map) -------------------------------
constexpr long WS_MASKB = 0;                          // 15,600 B -> 4,096 f
constexpr long WS_GSOB  = WS_MASKB + 4096;            // 457,600 f
constexpr long WS_STXB  = WS_GSOB + 457600;           // SZ/2 f
constexpr long WS_QB    = WS_STXB + SZ / 2;
constexpr long WS_KB    = WS_QB + SZ / 2;
constexpr long WS_VB    = WS_KB + SZ / 2;
constexpr long WS_VT    = WS_VB + SZ / 2;             // 3,244,032 f
constexpr long WS_SEMH  = WS_VT + 3244032;            // SZ/2 f
constexpr long WS_T2B   = WS_SEMH + SZ / 2;           // 998,400 f
constexpr long WS_MBD   = WS_T2B + 998400;            // mbd 512 + xg 512

typedef _Float16 half8 __attribute__((ext_vector_type(8)));
typedef __attribute__((ext_vector_type(4))) float f32x4;

static __device__ inline unsigned short f2h(float f) {
  _Float16 h = (_Float16)f;
  return __builtin_bit_cast(unsigned short, h);
}
static __device__ inline float h2f(unsigned short s) {
  return (float)__builtin_bit_cast(_Float16, s);
}

// ------------- mask sniff + pack to bitmask [NN][MBSTR] -------------------
__global__ __launch_bounds__(256) void k_maskprep(const unsigned char* __restrict__ raw,
                                                  unsigned char* __restrict__ outm) {
  bool is_u8 = false;
  for (int i = 0; i < 256; ++i) {
    if (raw[4 * i + 1]) { is_u8 = true; break; }
  }
  int idx = blockIdx.x * 256 + threadIdx.x;     // NN*MBSTR = 15,600 bytes
  if (idx >= NN * MBSTR) return;
  int n = idx / MBSTR, jb = idx - n * MBSTR;
  unsigned char v = 0;
  for (int k = 0; k < 8; ++k) {
    int col = jb * 8 + k;
    bool m = true;                               // pad cols -> masked
    if (col < NN) {
      int f = n * NN + col;
      m = is_u8 ? (raw[f] != 0) : (((const int*)raw)[f] != 0);
    }
    v |= (unsigned char)(m ? 1 : 0) << k;
  }
  outm[idx] = v;
}

// ------------- gso -> fp16, padded rows [8][325][GSTR] --------------------
__global__ __launch_bounds__(256) void k_gsoprep(const float* __restrict__ gso,
                                                 unsigned short* __restrict__ gsoB) {
  int idx = blockIdx.x * 256 + threadIdx.x;   // 3575 blocks exact
  int b = idx / (NN * GSTR);
  int rem = idx - b * (NN * GSTR);
  int r = rem / GSTR, j = rem - r * GSTR;
  gsoB[idx] = (j < NN) ? f2h(gso[(long)b * NN * NN + r * NN + j]) : (unsigned short)0;
}

// ---------------- stX gather: [B,T,N,D] -> [BT, 3N, D] fp16 ---------------
__global__ __launch_bounds__(256) void k_stx(const float* __restrict__ x,
                                             unsigned short* __restrict__ stXb) {
  int idx = blockIdx.x * 256 + threadIdx.x;     // exact: 23,400 blocks
  int d = idx & 63;
  int m = (idx >> 6) % MM;
  int bt = idx / (MM * DD);
  int b = bt / TT, t = bt - b * TT;
  int w = m / NN, n = m - w * NN;
  int st = t + w - 1;
  st = st < 0 ? 0 : (st > TT - 1 ? TT - 1 : st);
  stXb[idx] = f2h(x[(((b * TT + st) * NN + n) << 6) + d]);
}

// ---------------- QKV via MFMA: [93600x64] x [64x64] -> fp16 -------------
__global__ __launch_bounds__(256) void k_qkv_mfma(const unsigned short* __restrict__ stXb,
                                                  const float* __restrict__ Wq,
                                                  const float* __restrict__ Wk,
                                                  const float* __restrict__ Wv,
                                                  unsigned short* __restrict__ qb,
                                                  unsigned short* __restrict__ kb,
                                                  unsigned short* __restrict__ vb) {
  __shared__ alignas(16) unsigned short sX[128 * 72];
  __shared__ alignas(16) unsigned short sW[64 * 72];
  const float* W = blockIdx.y == 0 ? Wq : (blockIdx.y == 1 ? Wk : Wv);
  unsigned short* outb = blockIdx.y == 0 ? qb : (blockIdx.y == 1 ? kb : vb);
  int tid = threadIdx.x;
  long r0 = (long)blockIdx.x * 128;
  for (int u = 0; u < 4; ++u) {
    int idx = tid + 256 * u;
    int row = idx >> 3, c8 = idx & 7;
    long rg = r0 + row; if (rg > 93599) rg = 93599;
    *(uint4*)&sX[row * 72 + c8 * 8] = *(const uint4*)&stXb[rg * 64 + c8 * 8];
  }
  for (int u = 0; u < 16; ++u) {
    int f = tid + 256 * u;
    int o = f >> 6, d = f & 63;
    sW[o * 72 + d] = f2h(W[f]);
  }
  __syncthreads();
  int lane = tid & 63;
  int wv = __builtin_amdgcn_readfirstlane(tid >> 6);
  int lr = lane & 15, lg = lane >> 4;
  f32x4 zero4 = {0.f, 0.f, 0.f, 0.f};
  f32x4 acc[2][4];
#pragma unroll
  for (int rt = 0; rt < 2; ++rt)
#pragma unroll
    for (int c = 0; c < 4; ++c) acc[rt][c] = zero4;
#pragma unroll
  for (int kk = 0; kk < 2; ++kk) {
    half8 a0 = *(const half8*)&sX[(32 * wv + lr) * 72 + kk * 32 + lg * 8];
    half8 a1 = *(const half8*)&sX[(32 * wv + 16 + lr) * 72 + kk * 32 + lg * 8];
#pragma unroll
    for (int c = 0; c < 4; ++c) {
      half8 b = *(const half8*)&sW[(16 * c + lr) * 72 + kk * 32 + lg * 8];
      acc[0][c] = __builtin_amdgcn_mfma_f32_16x16x32_f16(a0, b, acc[0][c], 0, 0, 0);
      acc[1][c] = __builtin_amdgcn_mfma_f32_16x16x32_f16(a1, b, acc[1][c], 0, 0, 0);
    }
  }
  __syncthreads();
#pragma unroll
  for (int rt = 0; rt < 2; ++rt)
#pragma unroll
    for (int c = 0; c < 4; ++c)
#pragma unroll
      for (int e = 0; e < 4; ++e) {
        int row = 32 * wv + 16 * rt + lg * 4 + e;
        int col = 16 * c + lr;
        sX[row * 64 + col] = f2h(acc[rt][c][e]);
      }
  __syncthreads();
  for (int u = 0; u < 4; ++u) {
    int idx = tid + 256 * u;
    int row = idx >> 3, c8 = idx & 7;
    long rg = r0 + row;
    if (rg < 93600)
      *(uint4*)&outb[rg * 64 + c8 * 8] = *(const uint4*)&sX[row * 64 + c8 * 8];
  }
}

// ------- V transpose: vb [seg*NN+k][64] -> vbT [seg][64][352] ------------
__global__ __launch_bounds__(256) void k_vT(const unsigned short* __restrict__ vb,
                                            unsigned short* __restrict__ vbT) {
  __shared__ alignas(16) unsigned short T[128 * 72];
  int seg = blockIdx.x;                  // 0..287
  int ck = blockIdx.y;                   // 0..2 (k chunks of 128)
  int tid = threadIdx.x;
  long base = (long)seg * NN * 64;
  int k0 = ck * 128;
  for (int u = 0; u < 4; ++u) {
    int idx = tid + 256 * u;
    int row = idx >> 3, c8 = idx & 7;
    int kg = k0 + row;
    uint4 v;
    if (kg < NN) v = *(const uint4*)&vb[base + (long)kg * 64 + c8 * 8];
    else { v.x = 0; v.y = 0; v.z = 0; v.w = 0; }
    *(uint4*)&T[row * 72 + c8 * 8] = v;
  }
  __syncthreads();
  int d = tid & 63, k8 = tid >> 6;
  for (int it = 0; it < 4; ++it) {
    int klocal = (it * 4 + k8) * 8;
    if (k0 + klocal < 352) {
      unsigned short tmp[8];
#pragma unroll
      for (int j = 0; j < 8; ++j) tmp[j] = T[(klocal + j) * 72 + d];
      *(uint4*)&vbT[(long)seg * VTS + (long)d * 352 + k0 + klocal] = *(const uint4*)tmp;
    }
  }
}

// ------- fully fused attention: 1 wave = 16 rows x 325 cols --------------
// grid 6048 (288 segs x 21 row-tiles), XCD-swizzled so a seg's 21 tiles
// share one XCD's L2 (K panel fetched once per XCD).
__global__ __launch_bounds__(64, 3) void k_attn(const unsigned short* __restrict__ qb,
                                                const unsigned short* __restrict__ kb,
                                                const unsigned short* __restrict__ vb,
                                                const unsigned short* __restrict__ vbT,
                                                const unsigned char* __restrict__ maskb,
                                                unsigned short* __restrict__ semh) {
  __shared__ alignas(16) unsigned short Ptr[16 * 40];   // per-block (1-wave) P scratch
  int bid = blockIdx.x;
  int swz = (bid & 7) * 756 + (bid >> 3);   // 6048 = 8 * 756 exact
  int seg = swz / 21, rti = swz - seg * 21;
  int bt = seg / 3, w = seg - bt * 3;
  int n0 = rti * 16;
  long segbase = (long)seg * NN * 64;
  int lane = threadIdx.x;
  int lr = lane & 15, lg = lane >> 4;
  f32x4 zero4 = {0.f, 0.f, 0.f, 0.f};
  f32x4 acc[21];
#pragma unroll
  for (int ct = 0; ct < 21; ++ct) acc[ct] = zero4;
  f32x4 dA = zero4, dB = zero4;
  int arow = n0 + lr; if (arow > NN - 1) arow = NN - 1;
  long abase = segbase + (long)arow * 64;
  long pAaddr = ((long)bt * MM + ((w == 1) ? arow : NN + arow)) * 64;
  long pBaddr = ((long)bt * MM + 2 * NN + arow) * 64;
#pragma unroll
  for (int kk = 0; kk < 2; ++kk) {
    half8 a = *(const half8*)&qb[abase + kk * 32 + lg * 8];
#pragma unroll
    for (int ct = 0; ct < 21; ++ct) {
      int brow = 16 * ct + lr; if (brow > NN - 1) brow = NN - 1;
      half8 b = *(const half8*)&kb[segbase + (long)brow * 64 + kk * 32 + lg * 8];
      acc[ct] = __builtin_amdgcn_mfma_f32_16x16x32_f16(a, b, acc[ct], 0, 0, 0);
    }
    half8 bA = *(const half8*)&kb[pAaddr + kk * 32 + lg * 8];
    dA = __builtin_amdgcn_mfma_f32_16x16x32_f16(a, bA, dA, 0, 0, 0);
    if (w == 1) {
      half8 bB = *(const half8*)&kb[pBaddr + kk * 32 + lg * 8];
      dB = __builtin_amdgcn_mfma_f32_16x16x32_f16(a, bB, dB, 0, 0, 0);
    }
  }
  // diag extraction: element (r,r) at lane 20*lg+e for r = lg*4+e
  float da_[4], db_[4];
#pragma unroll
  for (int e = 0; e < 4; ++e) {
    int src = lg * 20 + e;
    da_[e] = __shfl(dA[e], src);
    db_[e] = (w == 1) ? __shfl(dB[e], src) : -INFINITY;
  }
  // mask (global dword bit tests; 16 lr-lanes share address -> broadcast)
  int rl[4];
#pragma unroll
  for (int e = 0; e < 4; ++e) {
    int r = n0 + lg * 4 + e; if (r > NN - 1) r = NN - 1;
    rl[e] = r;
  }
  float mx[4] = {-INFINITY, -INFINITY, -INFINITY, -INFINITY};
  unsigned mw[4];
#pragma unroll
  for (int ct = 0; ct < 21; ++ct) {
    if ((ct & 1) == 0) {
#pragma unroll
      for (int e = 0; e < 4; ++e)
        mw[e] = *(const unsigned*)&maskb[(long)rl[e] * MBSTR + (ct >> 1) * 4];
    }
    int sh = 16 * (ct & 1) + lr;
#pragma unroll
    for (int e = 0; e < 4; ++e) {
      bool masked = (mw[e] >> sh) & 1;
      float s = masked ? -INFINITY : acc[ct][e];
      acc[ct][e] = s;
      mx[e] = fmaxf(mx[e], s);
    }
  }
#pragma unroll
  for (int e = 0; e < 4; ++e)
    for (int m = 1; m < 16; m <<= 1) mx[e] = fmaxf(mx[e], __shfl_xor(mx[e], m));
  float gm[4], ea[4], eb[4], sum[4], inv[4];
#pragma unroll
  for (int e = 0; e < 4; ++e) {
    gm[e] = fmaxf(mx[e], da_[e]);
    if (w == 1) gm[e] = fmaxf(gm[e], db_[e]);
    sum[e] = 0.f;
  }
#pragma unroll
  for (int ct = 0; ct < 21; ++ct)
#pragma unroll
    for (int e = 0; e < 4; ++e) {
      float s = acc[ct][e];
      float p = (s > -1e37f) ? __expf(s - gm[e]) : 0.f;
      acc[ct][e] = p;
      sum[e] += p;
    }
#pragma unroll
  for (int e = 0; e < 4; ++e) {
    for (int m = 1; m < 16; m <<= 1) sum[e] += __shfl_xor(sum[e], m);
    ea[e] = __expf(da_[e] - gm[e]);
    eb[e] = (w == 1) ? __expf(db_[e] - gm[e]) : 0.f;
    sum[e] += ea[e] + eb[e];
    inv[e] = 1.f / sum[e];
  }
  // PV: P transpose through private LDS scratch; B-frags from global vbT
  long vtbase = (long)seg * VTS;
  f32x4 oacc[4];
#pragma unroll
  for (int c = 0; c < 4; ++c) oacc[c] = zero4;
#pragma unroll
  for (int ck = 0; ck < 11; ++ck) {
#pragma unroll
    for (int t = 0; t < 2; ++t) {
      int ct = 2 * ck + t;
#pragma unroll
      for (int e = 0; e < 4; ++e) {
        float pv = (ct < 21) ? acc[ct][e] * inv[e] : 0.f;
        Ptr[(lg * 4 + e) * 40 + t * 16 + lr] = f2h(pv);
      }
    }
    half8 a = *(const half8*)&Ptr[lr * 40 + lg * 8];
#pragma unroll
    for (int c = 0; c < 4; ++c) {
      half8 b = *(const half8*)&vbT[vtbase + (long)(16 * c + lr) * 352 + ck * 32 + lg * 8];
      oacc[c] = __builtin_amdgcn_mfma_f32_16x16x32_f16(a, b, oacc[c], 0, 0, 0);
    }
  }
  // epilogue: diag-partner contributions + write semh
#pragma unroll
  for (int c = 0; c < 4; ++c)
#pragma unroll
    for (int e = 0; e < 4; ++e) {
      int n = n0 + lg * 4 + e;
      int col = 16 * c + lr;
      if (n < NN) {
        float val = oacc[c][e];
        int partA = (w == 1) ? n : NN + n;
        val += ea[e] * inv[e] * h2f(vb[((long)bt * MM + partA) * 64 + col]);
        if (w == 1)
          val += eb[e] * inv[e] * h2f(vb[((long)bt * MM + 2 * NN + n) * 64 + col]);
        semh[((long)bt * MM + (long)w * NN + n) * 64 + col] = f2h(val);
      }
    }
}

// ---------------- xs1 via MFMA: gso x stX(block) + diag epilogue ---------
__global__ __launch_bounds__(256) void k_xs1_mfma(const unsigned short* __restrict__ gsoB,
                                                  const unsigned short* __restrict__ stXb,
                                                  const float* __restrict__ pt12,
                                                  const float* __restrict__ pt21,
                                                  const float* __restrict__ pt23,
                                                  const float* __restrict__ pt32,
                                                  unsigned short* __restrict__ xs1b) {
  __shared__ alignas(16) unsigned short Al[128 * 40];
  __shared__ alignas(16) unsigned short Bt[64 * 40];
  int btw = blockIdx.x;
  int bt = btw / 3, w = btw - bt * 3;
  int b = bt / TT;
  int rt_blk = blockIdx.y;
  const unsigned short* A = gsoB + (long)b * NN * GSTR;
  long vbase = (long)bt * MM + (long)w * NN;
  int tid = threadIdx.x;
  int lane = tid & 63;
  int wv = __builtin_amdgcn_readfirstlane(tid >> 6);
  int lr = lane & 15, lg = lane >> 4;
  f32x4 zero4 = {0.f, 0.f, 0.f, 0.f};
  f32x4 acc[2][4];
#pragma unroll
  for (int rt = 0; rt < 2; ++rt)
#pragma unroll
    for (int c = 0; c < 4; ++c) acc[rt][c] = zero4;
  for (int kb_ = 0; kb_ < 352; kb_ += 32) {
    __syncthreads();
    for (int u = 0; u < 2; ++u) {
      int idx = tid + 256 * u;
      int row = idx >> 2, c8 = idx & 3;
      int rr = rt_blk * 128 + row; if (rr > NN - 1) rr = NN - 1;
      *(uint4*)&Al[row * 40 + c8 * 8] = *(const uint4*)&A[(long)rr * GSTR + kb_ + c8 * 8];
    }
    for (int u = 0; u < 2; ++u) {
      int idx = tid + 256 * u;
      int k = idx >> 4, c4 = idx & 15;
      int kg = kb_ + k;
#pragma unroll
      for (int j = 0; j < 4; ++j) {
        int d = c4 + 16 * j;
        unsigned short val = (kg < NN) ? stXb[(vbase + kg) * 64 + d] : (unsigned short)0;
        Bt[d * 40 + k] = val;
      }
    }
    __syncthreads();
    half8 a0 = *(const half8*)&Al[(32 * wv + lr) * 40 + lg * 8];
    half8 a1 = *(const half8*)&Al[(32 * wv + 16 + lr) * 40 + lg * 8];
#pragma unroll
    for (int c = 0; c < 4; ++c) {
      half8 b_ = *(const half8*)&Bt[(16 * c + lr) * 40 + lg * 8];
      acc[0][c] = __builtin_amdgcn_mfma_f32_16x16x32_f16(a0, b_, acc[0][c], 0, 0, 0);
      acc[1][c] = __builtin_amdgcn_mfma_f32_16x16x32_f16(a1, b_, acc[1][c], 0, 0, 0);
    }
  }
  long btM = (long)bt * MM;
#pragma unroll
  for (int rt = 0; rt < 2; ++rt)
#pragma unroll
    for (int c = 0; c < 4; ++c)
#pragma unroll
      for (int e = 0; e < 4; ++e) {
        int n = rt_blk * 128 + 32 * wv + 16 * rt + lg * 4 + e;
        int col = 16 * c + lr;
        if (n < NN) {
          float val = acc[rt][c][e];
          if (w == 0) {
            val += pt21[n] * h2f(stXb[(btM + NN + n) * 64 + col]);
          } else if (w == 1) {
            val += pt12[n] * h2f(stXb[(btM + n) * 64 + col])
                 + pt32[n] * h2f(stXb[(btM + 2 * NN + n) * 64 + col]);
          } else {
            val += pt23[n] * h2f(stXb[(btM + NN + n) * 64 + col]);
          }
          xs1b[(btM + (long)w * NN + n) * 64 + col] = f2h(val);
        }
      }
}

// ------- t2 via MFMA: 2*(L*xs1)[mid] - stX[mid] -> fp16 ------------------
__global__ __launch_bounds__(256) void k_t2_mfma(const unsigned short* __restrict__ gsoB,
                                                 const unsigned short* __restrict__ xs1b,
                                                 const unsigned short* __restrict__ stXb,
                                                 const float* __restrict__ pt12,
                                                 const float* __restrict__ pt32,
                                                 unsigned short* __restrict__ t2b) {
  __shared__ alignas(16) unsigned short Al[128 * 40];
  __shared__ alignas(16) unsigned short Bt[64 * 40];
  int bt = blockIdx.x;
  int b = bt / TT;
  int rt_blk = blockIdx.y;
  const unsigned short* A = gsoB + (long)b * NN * GSTR;
  long vbase = (long)bt * MM + NN;
  int tid = threadIdx.x;
  int lane = tid & 63;
  int wv = __builtin_amdgcn_readfirstlane(tid >> 6);
  int lr = lane & 15, lg = lane >> 4;
  f32x4 zero4 = {0.f, 0.f, 0.f, 0.f};
  f32x4 acc[2][4];
#pragma unroll
  for (int rt = 0; rt < 2; ++rt)
#pragma unroll
    for (int c = 0; c < 4; ++c) acc[rt][c] = zero4;
  for (int kb_ = 0; kb_ < 352; kb_ += 32) {
    __syncthreads();
    for (int u = 0; u < 2; ++u) {
      int idx = tid + 256 * u;
      int row = idx >> 2, c8 = idx & 3;
      int rr = rt_blk * 128 + row; if (rr > NN - 1) rr = NN - 1;
      *(uint4*)&Al[row * 40 + c8 * 8] = *(const uint4*)&A[(long)rr * GSTR + kb_ + c8 * 8];
    }
    for (int u = 0; u < 2; ++u) {
      int idx = tid + 256 * u;
      int k = idx >> 4, c4 = idx & 15;
      int kg = kb_ + k;
#pragma unroll
      for (int j = 0; j < 4; ++j) {
        int d = c4 + 16 * j;
        unsigned short val = (kg < NN) ? xs1b[(vbase + kg) * 64 + d] : (unsigned short)0;
        Bt[d * 40 + k] = val;
      }
    }
    __syncthreads();
    half8 a0 = *(const half8*)&Al[(32 * wv + lr) * 40 + lg * 8];
    half8 a1 = *(const half8*)&Al[(32 * wv + 16 + lr) * 40 + lg * 8];
#pragma unroll
    for (int c = 0; c < 4; ++c) {
      half8 b_ = *(const half8*)&Bt[(16 * c + lr) * 40 + lg * 8];
      acc[0][c] = __builtin_amdgcn_mfma_f32_16x16x32_f16(a0, b_, acc[0][c], 0, 0, 0);
      acc[1][c] = __builtin_amdgcn_mfma_f32_16x16x32_f16(a1, b_, acc[1][c], 0, 0, 0);
    }
  }
  long btM = (long)bt * MM;
#pragma unroll
  for (int rt = 0; rt < 2; ++rt)
#pragma unroll
    for (int c = 0; c < 4; ++c)
#pragma unroll
      for (int e = 0; e < 4; ++e) {
        int n = rt_blk * 128 + 32 * wv + 16 * rt + lg * 4 + e;
        int col = 16 * c + lr;
        if (n < NN) {
          float val = 2.f * (pt12[n] * h2f(xs1b[(btM + n) * 64 + col])
                             + acc[rt][c][e]
                             + pt32[n] * h2f(xs1b[(btM + 2 * NN + n) * 64 + col]))
                      - h2f(stXb[(btM + NN + n) * 64 + col]);
          t2b[((long)bt * NN + n) * 64 + col] = f2h(val);
        }
      }
}

// ------- cheb via MFMA: [31200x192]x[192x64] + LayerNorm epilogue --------
__global__ __launch_bounds__(256) void k_cheb_mfma(const unsigned short* __restrict__ stXb,
                                                   const unsigned short* __restrict__ xs1b,
                                                   const unsigned short* __restrict__ t2b,
                                                   const float* __restrict__ cw,
                                                   const float* __restrict__ lng,
                                                   const float* __restrict__ lnb,
                                                   float* __restrict__ gcn) {
  __shared__ alignas(16) unsigned short Bt[64 * 200];  // [j][K], K=192
  __shared__ alignas(16) unsigned short Al[128 * 40];
  int tid = threadIdx.x;
  for (int u = 0; u < 48; ++u) {
    int f = tid + 256 * u;                   // f = K*64 + j
    int K = f >> 6, j = f & 63;
    Bt[j * 200 + K] = f2h(cw[f]);
  }
  int lane = tid & 63;
  int wv = __builtin_amdgcn_readfirstlane(tid >> 6);
  int lr = lane & 15, lg = lane >> 4;
  long grow0 = (long)blockIdx.x * 128;
  f32x4 zero4 = {0.f, 0.f, 0.f, 0.f};
  f32x4 acc[2][4];
#pragma unroll
  for (int rt = 0; rt < 2; ++rt)
#pragma unroll
    for (int c = 0; c < 4; ++c) acc[rt][c] = zero4;
  for (int ch = 0; ch < 6; ++ch) {
    const unsigned short* src = ch < 2 ? stXb : (ch < 4 ? xs1b : t2b);
    int koff = (ch & 1) * 32;
    __syncthreads();
    for (int u = 0; u < 2; ++u) {
      int idx = tid + 256 * u;
      int row = idx >> 2, c8 = idx & 3;
      long gr = grow0 + row; if (gr > 31199) gr = 31199;
      int bt = (int)(gr / NN), n = (int)(gr - (long)bt * NN);
      long sbase = (ch < 4) ? ((long)bt * MM + NN + n) * 64 : gr * 64;
      *(uint4*)&Al[row * 40 + c8 * 8] = *(const uint4*)&src[sbase + koff + c8 * 8];
    }
    __syncthreads();
    half8 a0 = *(const half8*)&Al[(32 * wv + lr) * 40 + lg * 8];
    half8 a1 = *(const half8*)&Al[(32 * wv + 16 + lr) * 40 + lg * 8];
#pragma unroll
    for (int c = 0; c < 4; ++c) {
      half8 b = *(const half8*)&Bt[(16 * c + lr) * 200 + ch * 32 + lg * 8];
      acc[0][c] = __builtin_amdgcn_mfma_f32_16x16x32_f16(a0, b, acc[0][c], 0, 0, 0);
      acc[1][c] = __builtin_amdgcn_mfma_f32_16x16x32_f16(a1, b, acc[1][c], 0, 0, 0);
    }
  }
  float lngv[4], lnbv[4];
#pragma unroll
  for (int c = 0; c < 4; ++c) { lngv[c] = lng[16 * c + lr]; lnbv[c] = lnb[16 * c + lr]; }
#pragma unroll
  for (int rt = 0; rt < 2; ++rt)
#pragma unroll
    for (int e = 0; e < 4; ++e) {
      float s = acc[rt][0][e] + acc[rt][1][e] + acc[rt][2][e] + acc[rt][3][e];
      for (int m = 1; m < 16; m <<= 1) s += __shfl_xor(s, m);
      float mu = s * (1.f / 64.f);
      float q = 0.f;
#pragma unroll
      for (int c = 0; c < 4; ++c) { float d = acc[rt][c][e] - mu; q += d * d; }
      for (int m = 1; m < 16; m <<= 1) q += __shfl_xor(q, m);
      float rstd = rsqrtf(q * (1.f / 64.f) + LN_EPS_);
      long gr = grow0 + 32 * wv + 16 * rt + lg * 4 + e;
      if (gr < 31200) {
#pragma unroll
        for (int c = 0; c < 4; ++c)
          gcn[gr * 64 + 16 * c + lr] = (acc[rt][c][e] - mu) * rstd * lngv[c] + lnbv[c];
      }
    }
}

// -------- mean over (t,n) per (b,d), inline scramble-gather --------------
__global__ __launch_bounds__(256) void k_mean(const unsigned short* __restrict__ semh,
                                              const float* __restrict__ gcn,
                                              float* __restrict__ mbd) {
  __shared__ float red[4][64];
  int bt = blockIdx.x;
  int b = bt / TT;
  int d = threadIdx.x & 63, g = threadIdx.x >> 6;
  float s = 0.f;
  for (int n = g; n < NN; n += 4) {
    int f = (NN + n) * 64 + d;
    int mm = f % MM, ii = f / MM;
    float a = h2f(semh[((long)bt * MM + mm) * 64 + ii]);
    float r = gcn[((long)bt * NN + n) * 64 + d];
    s += a + r;
  }
  red[g][d] = s;
  __syncthreads();
  if (threadIdx.x < 64) {
    float v = red[0][d] + red[1][d] + red[2][d] + red[3][d];
    atomicAdd(&mbd[b * 64 + d], v);
  }
}

// -------- global AFF branch ----------------------------------------------
__global__ __launch_bounds__(64) void k_glob(const float* __restrict__ mbd,
                                             const float* __restrict__ w1,
                                             const float* __restrict__ b1,
                                             const float* __restrict__ g1,
                                             const float* __restrict__ be1,
                                             const float* __restrict__ w2,
                                             const float* __restrict__ b2,
                                             const float* __restrict__ g2,
                                             const float* __restrict__ be2,
                                             float* __restrict__ xg) {
  __shared__ float ml[64];
  __shared__ float zg[16];
  int b = blockIdx.x, d = threadIdx.x;
  ml[d] = mbd[b * 64 + d] * (1.f / 3900.f);
  __syncthreads();
  float rb = rsqrtf(1.f + BN_EPS_);
  if (d < 16) {
    float a = b1[d];
    for (int i = 0; i < 64; ++i) a += w1[d * 64 + i] * ml[i];
    a = a * (g1[d] * rb) + be1[d];
    zg[d] = a > 0.f ? a : 0.f;
  }
  __syncthreads();
  float a = b2[d];
  for (int i = 0; i < 16; ++i) a += w2[d * 16 + i] * zg[i];
  xg[b * 64 + d] = a * (g2[d] * rb) + be2[d];
}

// -------- final: local AFF branch + sigmoid fuse (inline gather) ---------
__global__ __launch_bounds__(256) void k_final(const unsigned short* __restrict__ semh,
                                               const float* __restrict__ gcn,
                                               const float* __restrict__ xg,
                                               const float* __restrict__ w1,
                                               const float* __restrict__ b1,
                                               const float* __restrict__ g1,
                                               const float* __restrict__ be1,
                                               const float* __restrict__ w2,
                                               const float* __restrict__ b2,
                                               const float* __restrict__ g2,
                                               const float* __restrict__ be2,
                                               float* __restrict__ out) {
  __shared__ float w1l[16][65];
  __shared__ float w2l[64][17];
  __shared__ float xal[4][64];
  __shared__ float zll[4][16];
  int tid = threadIdx.x;
  for (int u = 0; u < 4; ++u) {
    int f = tid + 256 * u;
    w1l[f >> 6][f & 63] = w1[f];
    w2l[f >> 4][f & 15] = w2[f];
  }
  int lane = tid & 63, wv = tid >> 6;
  long row = (long)blockIdx.x * 4 + wv;        // 31,200 rows exact
  int bt = (int)(row / NN);
  int n = (int)(row - (long)bt * NN);
  int b = bt / TT;
  int f = (NN + n) * 64 + lane;
  int mm = f % MM, ii = f / MM;
  float a = h2f(semh[((long)bt * MM + mm) * 64 + ii]);
  float r = gcn[row * DD + lane];
  float xa = a + r;
  xal[wv][lane] = xa;
  __syncthreads();
  float rb = rsqrtf(1.f + BN_EPS_);
  if (lane < 16) {
    float acc = b1[lane];
#pragma unroll 8
    for (int i = 0; i < 64; ++i) acc += w1l[lane][i] * xal[wv][i];
    acc = acc * (g1[lane] * rb) + be1[lane];
    zll[wv][lane] = acc > 0.f ? acc : 0.f;
  }
  __syncthreads();
  float acc = b2[lane];
#pragma unroll
  for (int i = 0; i < 16; ++i) acc += w2l[lane][i] * zll[wv][i];
  float xl = acc * (g2[lane] * rb) + be2[lane];
  float wei = 1.f / (1.f + __expf(-(xl + xg[b * 64 + lane])));
  out[row * DD + lane] = 2.f * a * wei + 2.f * r * (1.f - wei);
}

extern "C" void kernel_launch(void* const* d_in, const int* in_sizes, int n_in,
                              void* d_out, int out_size, void* d_ws, size_t ws_size,
                              hipStream_t stream) {
  const float* x    = (const float*)d_in[0];
  const float* gso  = (const float*)d_in[1];
  const unsigned char* mask_raw = (const unsigned char*)d_in[2];
  const float* Wq   = (const float*)d_in[3];
  const float* Wk   = (const float*)d_in[4];
  const float* Wv   = (const float*)d_in[5];
  const float* chw  = (const float*)d_in[6];
  const float* pt12 = (const float*)d_in[7];
  const float* pt21 = (const float*)d_in[8];
  const float* pt23 = (const float*)d_in[9];
  const float* pt32 = (const float*)d_in[10];
  const float* lng  = (const float*)d_in[11];
  const float* lnb  = (const float*)d_in[12];
  const float* l_w1 = (const float*)d_in[13];
  const float* l_b1 = (const float*)d_in[14];
  const float* l_g1 = (const float*)d_in[15];
  const float* l_be1= (const float*)d_in[16];
  const float* l_w2 = (const float*)d_in[17];
  const float* l_b2 = (const float*)d_in[18];
  const float* l_g2 = (const float*)d_in[19];
  const float* l_be2= (const float*)d_in[20];
  const float* g_w1 = (const float*)d_in[21];
  const float* g_b1 = (const float*)d_in[22];
  const float* g_g1 = (const float*)d_in[23];
  const float* g_be1= (const float*)d_in[24];
  const float* g_w2 = (const float*)d_in[25];
  const float* g_b2 = (const float*)d_in[26];
  const float* g_g2 = (const float*)d_in[27];
  const float* g_be2= (const float*)d_in[28];

  float* base = (float*)d_ws;
  unsigned char* maskb = (unsigned char*)d_ws;
  unsigned short* gsoB = (unsigned short*)(base + WS_GSOB);
  unsigned short* stXb = (unsigned short*)(base + WS_STXB);
  unsigned short* qb   = (unsigned short*)(base + WS_QB);
  unsigned short* kb   = (unsigned short*)(base + WS_KB);
  unsigned short* vb   = (unsigned short*)(base + WS_VB);
  unsigned short* vbT  = (unsigned short*)(base + WS_VT);
  unsigned short* semh = (unsigned short*)(base + WS_SEMH);
  unsigned short* t2b  = (unsigned short*)(base + WS_T2B);

  // aliases (lifetimes disjoint):
  unsigned short* xs1b = vb;            // vb dead after k_attn
  float* gcn = (float*)qb;              // qb dead after k_attn
  float* mbd = base + WS_MBD;
  float* xg  = mbd + 512;

  k_maskprep<<<(NN * MBSTR + 255) / 256, 256, 0, stream>>>(mask_raw, maskb);
  k_gsoprep<<<3575, 256, 0, stream>>>(gso, gsoB);
  k_stx<<<23400, 256, 0, stream>>>(x, stXb);
  {
    dim3 g(732, 3);
    k_qkv_mfma<<<g, 256, 0, stream>>>(stXb, Wq, Wk, Wv, qb, kb, vb);
  }
  {
    dim3 gv(288, 3);
    k_vT<<<gv, 256, 0, stream>>>(vb, vbT);
  }
  k_attn<<<6048, 64, 0, stream>>>(qb, kb, vb, vbT, maskb, semh);
  {
    dim3 g(288, 3);
    k_xs1_mfma<<<g, 256, 0, stream>>>(gsoB, stXb, pt12, pt21, pt23, pt32, xs1b);
  }
  {
    dim3 g(96, 3);
    k_t2_mfma<<<g, 256, 0, stream>>>(gsoB, xs1b, stXb, pt12, pt32, t2b);
  }
  k_cheb_mfma<<<244, 256, 0, stream>>>(stXb, xs1b, t2b, chw, lng, lnb, gcn);
  hipMemsetAsync(mbd, 0, 1024 * sizeof(float), stream);
  k_mean<<<96, 256, 0, stream>>>(semh, gcn, mbd);
  k_glob<<<8, 64, 0, stream>>>(mbd, g_w1, g_b1, g_g1, g_be1, g_w2, g_b2, g_g2, g_be2, xg);
  k_final<<<7800, 256, 0, stream>>>(semh, gcn, xg,
                                    l_w1, l_b1, l_g1, l_be1,
                                    l_w2, l_b2, l_g2, l_be2,
                                    (float*)d_out);
}